// Round 9
// baseline (328.077 us; speedup 1.0000x reference)
//
#include <hip/hip_runtime.h>
#include <hip/hip_bf16.h>

#define NTOT 2048
#define DD 256
#define BSZ 4

typedef _Float16 half_t;
typedef __attribute__((ext_vector_type(8))) _Float16 halfx8;
typedef __attribute__((ext_vector_type(4))) _Float16 halfx4;
typedef __attribute__((ext_vector_type(4))) float f32x4;

// ---------------- block reduce (256 threads) ----------------
__device__ __forceinline__ float blockReduceSum256(float v) {
    __shared__ float red[4];
    for (int off = 32; off > 0; off >>= 1) v += __shfl_down(v, off);
    int lane = threadIdx.x & 63, w = threadIdx.x >> 6;
    __syncthreads();
    if (lane == 0) red[w] = v;
    __syncthreads();
    return red[0] + red[1] + red[2] + red[3];
}

// ---------------- mega setup: wprep | stats | adj->lcol0 | maps ----------------
#define SB_WPREP 4352
#define SB_STAT  4356
#define SB_A2L   4868
#define SB_MAPS  4900
__global__ void __launch_bounds__(256) setup_kernel(
    const float* __restrict__ bw1, const float* __restrict__ bw2,
    const float* __restrict__ pw2, half_t* __restrict__ Wt,
    const float* __restrict__ pos, float* __restrict__ pstats,
    const float* __restrict__ poolp, float* __restrict__ pinv,
    const float* __restrict__ adj, int* __restrict__ ldeg0, int* __restrict__ lcol0,
    int* __restrict__ orig, int* __restrict__ inv) {
    int bid = blockIdx.x, tid = threadIdx.x;
    if (bid < SB_WPREP) {
        int m = bid >> 8, rem = bid & 255;
        int nb = (rem >> 4) * 16, kb = (rem & 15) * 16;
        const float* W = (m < 8) ? (bw1 + (size_t)m * DD * DD)
                      : (m < 16) ? (bw2 + (size_t)(m - 8) * DD * DD)
                                 : pw2;
        __shared__ float s[16][17];
        int i = tid >> 4, j = tid & 15;
        s[i][j] = W[(size_t)(kb + i) * DD + nb + j];
        __syncthreads();
        Wt[(size_t)m * DD * DD + (size_t)(nb + i) * DD + kb + j] = (half_t)s[j][i];
    } else if (bid < SB_STAT) {
        int which = bid - SB_WPREP;
        if (which == 0) {
            float s[3] = {0.f, 0.f, 0.f};
            for (int i = tid; i < NTOT; i += 256)
                for (int c = 0; c < 3; ++c) s[c] += pos[i * 3 + c];
            float m[3];
            for (int c = 0; c < 3; ++c) m[c] = blockReduceSum256(s[c]) / (float)NTOT;
            float q[3] = {0.f, 0.f, 0.f};
            for (int i = tid; i < NTOT; i += 256)
                for (int c = 0; c < 3; ++c) { float d = pos[i * 3 + c] - m[c]; q[c] += d * d; }
            for (int c = 0; c < 3; ++c) {
                float t = blockReduceSum256(q[c]);
                if (tid == 0) {
                    float var = ((float)BSZ * t) / ((float)BSZ * NTOT - 1.0f);
                    pstats[c] = m[c];
                    pstats[3 + c] = 1.0f / (sqrtf(var) + 1e-8f);
                }
            }
        } else {
            int dep = which - 1;
            float v = poolp[dep * DD + tid];
            float ss = blockReduceSum256(v * v);
            if (tid == 0) pinv[dep] = rsqrtf(ss);
        }
    } else if (bid < SB_A2L) {
        int row = (bid - SB_STAT) * 4 + (tid >> 6);
        int lane = tid & 63;
        int run = 0;
        for (int j0 = 0; j0 < NTOT; j0 += 64) {
            int j = j0 + lane;
            bool pred = adj[(size_t)row * NTOT + j] != 0.f;
            unsigned long long mask = __ballot(pred);
            if (pred) {
                int pos2 = run + __popcll(mask & ((1ull << lane) - 1ull));
                if (pos2 < 64) lcol0[row * 64 + pos2] = j;
            }
            run += __popcll(mask);
        }
        if (lane == 0) ldeg0[row] = run < 64 ? run : 64;
    } else {
        int t = (bid - SB_A2L) * 256 + tid;  // B*NTOT
        int i = t & (NTOT - 1);
        orig[t] = i; inv[t] = i;  // tag 0
    }
}

// ---------------- fused pe + input projection + h/z init ----------------
__global__ void __launch_bounds__(256) pe_h_kernel(
    const float* __restrict__ pos, const float* __restrict__ pstats,
    const float* __restrict__ pw1, const float* __restrict__ pb1,
    const half_t* __restrict__ Wt16, const float* __restrict__ pb2,
    const float* __restrict__ x, const float* __restrict__ in_w,
    const float* __restrict__ in_b, float* __restrict__ h, float* __restrict__ z) {
    __shared__ half_t tb[16][264];
    __shared__ float iw[16][DD];
    __shared__ float xs[16][16];
    __shared__ float part[4][16][2];
    __shared__ float mrs[16][2];
    int tid = threadIdx.x;
    int i0 = blockIdx.x * 16;
    {
        int rl = tid >> 4, cb = (tid & 15) * 16;
        float pn[3];
#pragma unroll
        for (int c = 0; c < 3; ++c)
            pn[c] = (pos[(i0 + rl) * 3 + c] - pstats[c]) * pstats[3 + c];
#pragma unroll
        for (int u = 0; u < 16; ++u) {
            int d = cb + u;
            float a = pb1[d];
            a += pn[0] * pw1[d];
            a += pn[1] * pw1[DD + d];
            a += pn[2] * pw1[2 * DD + d];
            a = a / (1.0f + expf(-a));
            tb[rl][d] = (half_t)a;
        }
        int k = tid >> 4;
#pragma unroll
        for (int u = 0; u < 16; ++u) iw[k][cb + u] = in_w[k * DD + cb + u];
    }
    __syncthreads();
    int w = tid >> 6, l = tid & 63;
    int lo = l & 15, hi = l >> 4;
    int kb = hi * 8;
    float pe_r[4][4];
    {
        f32x4 acc[4] = {};
#pragma unroll
        for (int k0 = 0; k0 < DD; k0 += 32) {
            halfx8 a0 = *(const halfx8*)&tb[lo][kb + k0];
#pragma unroll
            for (int j = 0; j < 4; ++j) {
                halfx8 bj = *(const halfx8*)(Wt16 + (size_t)(w * 64 + j * 16 + lo) * DD + kb + k0);
                acc[j] = __builtin_amdgcn_mfma_f32_16x16x32_f16(a0, bj, acc[j], 0, 0, 0);
            }
        }
#pragma unroll
        for (int j = 0; j < 4; ++j) {
            float bs = pb2[w * 64 + j * 16 + lo];
#pragma unroll
            for (int q = 0; q < 4; ++q) pe_r[j][q] = acc[j][q] + bs;
        }
    }
    float xb[4];
#pragma unroll
    for (int j = 0; j < 4; ++j) xb[j] = in_b[w * 64 + j * 16 + lo];
    for (int b = 0; b < BSZ; ++b) {
        __syncthreads();
        xs[tid >> 4][tid & 15] = x[(size_t)(b * NTOT + i0 + (tid >> 4)) * 16 + (tid & 15)];
        __syncthreads();
        float vh[4][4];
#pragma unroll
        for (int q = 0; q < 4; ++q) {
            int rl = hi * 4 + q;
            float s = 0.f, ss = 0.f;
#pragma unroll
            for (int j = 0; j < 4; ++j) {
                int c = w * 64 + j * 16 + lo;
                float acc = xb[j];
#pragma unroll
                for (int k = 0; k < 16; ++k) acc += xs[rl][k] * iw[k][c];
                float v = acc + pe_r[j][q];
                vh[j][q] = v;
                s += v; ss += v * v;
            }
#pragma unroll
            for (int m = 1; m < 16; m <<= 1) { s += __shfl_xor(s, m); ss += __shfl_xor(ss, m); }
            if (lo == 0) { part[w][rl][0] = s; part[w][rl][1] = ss; }
        }
        __syncthreads();
        if (tid < 16) {
            float s = 0.f, ss = 0.f;
#pragma unroll
            for (int w2 = 0; w2 < 4; ++w2) { s += part[w2][tid][0]; ss += part[w2][tid][1]; }
            float mean = s * (1.0f / DD);
            float var = ss * (1.0f / DD) - mean * mean;
            mrs[tid][0] = mean;
            mrs[tid][1] = rsqrtf(var + 1e-5f);
        }
        __syncthreads();
#pragma unroll
        for (int q = 0; q < 4; ++q) {
            int rl = hi * 4 + q;
            size_t r = (size_t)(b * NTOT + i0 + rl);
            float mean = mrs[rl][0], rs = mrs[rl][1];
#pragma unroll
            for (int j = 0; j < 4; ++j) {
                int c = w * 64 + j * 16 + lo;
                float v = vh[j][q];
                h[r * DD + c] = v;
                z[r * DD + c] = (v - mean) * rs;
            }
        }
    }
}

// ---------------- fused layer, ROWS rows/block ----------------
// ROWS in {4,8,16}; 256 thr (4 waves x 64 cols). MFMA M-rows >= ROWS are garbage,
// never stored. Phase A has exactly ROWS real rows (TPR=256/ROWS threads each).
template <int ROWS, int SCORE>
__global__ void __launch_bounds__(256) layer_kernel(
    float* __restrict__ h, const float* __restrict__ zin, float* __restrict__ zout,
    const half_t* __restrict__ Wt1, const half_t* __restrict__ Wt2,
    const float* __restrict__ b1v, const float* __restrict__ b2v,
    const float* __restrict__ gv, const float* __restrict__ bbv,
    const float* __restrict__ beps, int blk,
    const int* __restrict__ ldeg0, const int* __restrict__ lcol0,
    const int* __restrict__ orig, const int* __restrict__ inv,
    const float* __restrict__ poolp, const float* __restrict__ pinv_all,
    float* __restrict__ scores, int dep, int n, int tag) {
    constexpr int TPR = 256 / ROWS;
    constexpr int CH = 64 / TPR;
    __shared__ half_t tb[16][264];
    __shared__ half_t ub[16][264];
    __shared__ float part[4][16][3];
    __shared__ float mrs[16][2];
    int tid = threadIdx.x;
    int rowBase = blockIdx.x * ROWS;
    float eps1 = 1.0f + beps[blk];

    // ---- phase A: aggregation -> LDS tb (f16) ----
    {
        int rl = tid / TPR, cg = tid % TPR;
        int r = rowBase + rl;
        int b = r / n, i = r - b * n;
        const f32x4* zb = (const f32x4*)zin + (size_t)b * n * 64;
        f32x4 acc[CH];
#pragma unroll
        for (int u = 0; u < CH; ++u) acc[u] = zb[(size_t)i * 64 + cg + TPR * u] * eps1;
        int cnt = 0;
        if (tag == 0) {
            int deg = ldeg0[i];
            const int* lc = lcol0 + i * 64;
            int p = 0;
            for (; p + 4 <= deg; p += 4) {
                int j0 = lc[p], j1 = lc[p + 1], j2 = lc[p + 2], j3 = lc[p + 3];
#pragma unroll
                for (int u = 0; u < CH; ++u) {
                    f32x4 v0 = zb[(size_t)j0 * 64 + cg + TPR * u];
                    f32x4 v1 = zb[(size_t)j1 * 64 + cg + TPR * u];
                    f32x4 v2 = zb[(size_t)j2 * 64 + cg + TPR * u];
                    f32x4 v3 = zb[(size_t)j3 * 64 + cg + TPR * u];
                    acc[u] += (v0 + v1) + (v2 + v3);
                }
            }
            for (; p < deg; ++p) {
                int j = lc[p];
#pragma unroll
                for (int u = 0; u < CH; ++u) acc[u] += zb[(size_t)j * 64 + cg + TPR * u];
            }
            cnt = deg;
        } else {
            int o = orig[b * NTOT + i];
            int deg = ldeg0[o];
            const int* lc = lcol0 + o * 64;
            const int* invb = inv + b * NTOT;
            int p = 0;
            for (; p + 4 <= deg; p += 4) {
                int c0 = lc[p], c1 = lc[p + 1], c2 = lc[p + 2], c3 = lc[p + 3];
                int v0 = invb[c0], v1 = invb[c1], v2 = invb[c2], v3 = invb[c3];
                if ((v0 >> 12) == tag) {
                    int j = v0 & 4095; ++cnt;
#pragma unroll
                    for (int u = 0; u < CH; ++u) acc[u] += zb[(size_t)j * 64 + cg + TPR * u];
                }
                if ((v1 >> 12) == tag) {
                    int j = v1 & 4095; ++cnt;
#pragma unroll
                    for (int u = 0; u < CH; ++u) acc[u] += zb[(size_t)j * 64 + cg + TPR * u];
                }
                if ((v2 >> 12) == tag) {
                    int j = v2 & 4095; ++cnt;
#pragma unroll
                    for (int u = 0; u < CH; ++u) acc[u] += zb[(size_t)j * 64 + cg + TPR * u];
                }
                if ((v3 >> 12) == tag) {
                    int j = v3 & 4095; ++cnt;
#pragma unroll
                    for (int u = 0; u < CH; ++u) acc[u] += zb[(size_t)j * 64 + cg + TPR * u];
                }
            }
            for (; p < deg; ++p) {
                int v = invb[lc[p]];
                if ((v >> 12) == tag) {
                    int j = v & 4095; ++cnt;
#pragma unroll
                    for (int u = 0; u < CH; ++u) acc[u] += zb[(size_t)j * 64 + cg + TPR * u];
                }
            }
        }
        float coefb = eps1 + (float)cnt;
#pragma unroll
        for (int u = 0; u < CH; ++u) {
            int c4 = cg + TPR * u;
            f32x4 gvv = ((const f32x4*)gv)[c4];
            f32x4 bvv = ((const f32x4*)bbv)[c4];
            f32x4 tv = gvv * acc[u] + bvv * coefb;
            halfx4 th;
#pragma unroll
            for (int e = 0; e < 4; ++e) th[e] = (half_t)tv[e];
            *(halfx4*)&tb[rl][c4 * 4] = th;
        }
    }
    __syncthreads();

    int w = tid >> 6, l = tid & 63;
    int lo = l & 15, hi = l >> 4;
    int kb = hi * 8;

    // ---- phase B: mm1 + silu -> ub ----
    {
        f32x4 acc[4] = {};
#pragma unroll
        for (int k0 = 0; k0 < DD; k0 += 32) {
            halfx8 a0 = *(const halfx8*)&tb[lo][kb + k0];
#pragma unroll
            for (int j = 0; j < 4; ++j) {
                halfx8 bj = *(const halfx8*)(Wt1 + (size_t)(w * 64 + j * 16 + lo) * DD + kb + k0);
                acc[j] = __builtin_amdgcn_mfma_f32_16x16x32_f16(a0, bj, acc[j], 0, 0, 0);
            }
        }
        float bs[4];
#pragma unroll
        for (int j = 0; j < 4; ++j) bs[j] = b1v[w * 64 + j * 16 + lo];
#pragma unroll
        for (int q = 0; q < 4; ++q)
#pragma unroll
            for (int j = 0; j < 4; ++j) {
                float v = acc[j][q] + bs[j];
                v = v / (1.0f + expf(-v));
                ub[hi * 4 + q][w * 64 + j * 16 + lo] = (half_t)v;
            }
    }
    __syncthreads();

    // ---- phase C: mm2 + residual + stats (+score) + z ----
    {
        f32x4 acc[4] = {};
#pragma unroll
        for (int k0 = 0; k0 < DD; k0 += 32) {
            halfx8 a0 = *(const halfx8*)&ub[lo][kb + k0];
#pragma unroll
            for (int j = 0; j < 4; ++j) {
                halfx8 bj = *(const halfx8*)(Wt2 + (size_t)(w * 64 + j * 16 + lo) * DD + kb + k0);
                acc[j] = __builtin_amdgcn_mfma_f32_16x16x32_f16(a0, bj, acc[j], 0, 0, 0);
            }
        }
        float bs[4], pv[4] = {};
#pragma unroll
        for (int j = 0; j < 4; ++j) bs[j] = b2v[w * 64 + j * 16 + lo];
        if (SCORE) {
#pragma unroll
            for (int j = 0; j < 4; ++j) pv[j] = poolp[dep * DD + w * 64 + j * 16 + lo];
        }
        float vh[4][4];
#pragma unroll
        for (int q = 0; q < 4; ++q) {
            int rl = hi * 4 + q;
            int r = rowBase + rl;
            float s = 0.f, ss = 0.f, sp = 0.f;
            if (rl < ROWS) {
#pragma unroll
                for (int j = 0; j < 4; ++j) {
                    int c = w * 64 + j * 16 + lo;
                    float v = h[(size_t)r * DD + c] + acc[j][q] + bs[j];
                    vh[j][q] = v;
                    s += v; ss += v * v;
                    if (SCORE) sp += v * pv[j];
                }
            }
#pragma unroll
            for (int m = 1; m < 16; m <<= 1) {
                s += __shfl_xor(s, m); ss += __shfl_xor(ss, m);
                if (SCORE) sp += __shfl_xor(sp, m);
            }
            if (lo == 0 && rl < ROWS) {
                part[w][rl][0] = s; part[w][rl][1] = ss;
                if (SCORE) part[w][rl][2] = sp;
            }
        }
        __syncthreads();
        if (tid < ROWS) {
            float s = 0.f, ss = 0.f, sp = 0.f;
#pragma unroll
            for (int w2 = 0; w2 < 4; ++w2) {
                s += part[w2][tid][0]; ss += part[w2][tid][1];
                if (SCORE) sp += part[w2][tid][2];
            }
            float mean = s * (1.0f / DD);
            float var = ss * (1.0f / DD) - mean * mean;
            mrs[tid][0] = mean;
            mrs[tid][1] = rsqrtf(var + 1e-5f);
            if (SCORE) {
                int r = rowBase + tid;
                int b2 = r / n, ii = r - b2 * n;
                scores[b2 * NTOT + ii] = sp * pinv_all[dep];
            }
        }
        __syncthreads();
#pragma unroll
        for (int q = 0; q < 4; ++q) {
            int rl = hi * 4 + q;
            if (rl < ROWS) {
                int r = rowBase + rl;
                float mean = mrs[rl][0], rs = mrs[rl][1];
#pragma unroll
                for (int j = 0; j < 4; ++j) {
                    int c = w * 64 + j * 16 + lo;
                    float v = vh[j][q];
                    h[(size_t)r * DD + c] = v;
                    zout[(size_t)r * DD + c] = (v - mean) * rs;
                }
            }
        }
    }
}

// ---------------- pooling: 1-pass radix + candidate rank (fallback: full radix) ----------------
__global__ void topk_kernel(const float* __restrict__ scores, const int* __restrict__ orig_cur,
                            int* __restrict__ orig_next, int* __restrict__ idx_local,
                            float* __restrict__ gate, int n, int k) {
    __shared__ unsigned keys[2048];
    __shared__ int hist[256];
    __shared__ int sg[256], se[256];
    __shared__ int sh_bucket, sh_r, sh_cnt;
    __shared__ unsigned cand[256];
    __shared__ unsigned sh_thr;
    int b = blockIdx.x;
    const float* sc = scores + b * NTOT;
    int tid = threadIdx.x;
    for (int i = tid; i < n; i += 256) {
        unsigned u = __float_as_uint(sc[i]);
        keys[i] = (u & 0x80000000u) ? ~u : (u | 0x80000000u);
    }
    hist[tid] = 0;
    if (tid == 0) sh_cnt = 0;
    __syncthreads();
    for (int i = tid; i < n; i += 256) atomicAdd(&hist[keys[i] >> 24], 1);
    __syncthreads();
    int cnt = hist[tid];
    sg[tid] = cnt;
    __syncthreads();
    for (int off = 1; off < 256; off <<= 1) {
        int v = (tid >= off) ? sg[tid - off] : 0;
        __syncthreads();
        sg[tid] += v;
        __syncthreads();
    }
    int r = n - k;  // 0-indexed rank ascending
    int incl = sg[tid], excl = incl - cnt;
    if (excl <= r && r < incl) { sh_bucket = tid; sh_r = r - excl; }
    __syncthreads();
    int b1 = sh_bucket, r1 = sh_r;
    int c = hist[b1];
    unsigned thrkey;
    if (c <= 256) {
        for (int i = tid; i < n; i += 256) {
            unsigned key = keys[i];
            if ((key >> 24) == (unsigned)b1) {
                int pos = atomicAdd(&sh_cnt, 1);
                cand[pos] = key;
            }
        }
        __syncthreads();
        if (tid < c) {
            unsigned mine = cand[tid];
            int less = 0, eq = 0;
            for (int j = 0; j < c; ++j) {
                unsigned oth = cand[j];
                less += (oth < mine); eq += (oth == mine);
            }
            if (less <= r1 && r1 < less + eq) sh_thr = mine;
        }
        __syncthreads();
        thrkey = sh_thr;
    } else {
        unsigned prefix = ((unsigned)b1) << 24;
        int rr = r1;
        for (int shift = 16; shift >= 0; shift -= 8) {
            __syncthreads();
            hist[tid] = 0;
            __syncthreads();
            unsigned mask = 0xFFFFFFFFu << (shift + 8);
            for (int i = tid; i < n; i += 256) {
                unsigned key = keys[i];
                if ((key & mask) == (prefix & mask)) atomicAdd(&hist[(key >> shift) & 255], 1);
            }
            __syncthreads();
            int cnt2 = hist[tid];
            sg[tid] = cnt2;
            __syncthreads();
            for (int off = 1; off < 256; off <<= 1) {
                int v = (tid >= off) ? sg[tid - off] : 0;
                __syncthreads();
                sg[tid] += v;
                __syncthreads();
            }
            int incl2 = sg[tid], excl2 = incl2 - cnt2;
            if (excl2 <= rr && rr < incl2) { sh_bucket = tid; sh_r = rr - excl2; }
            __syncthreads();
            prefix |= ((unsigned)sh_bucket) << shift;
            rr = sh_r;
            __syncthreads();
        }
        thrkey = prefix;
    }
    unsigned uthr = (thrkey & 0x80000000u) ? (thrkey ^ 0x80000000u) : ~thrkey;
    float thr = __uint_as_float(uthr);  // exact k-th largest value
    int chunk = n / 256;
    int base = tid * chunk;
    int cgt = 0, ceq = 0;
    for (int u = 0; u < chunk; ++u) {
        float s = sc[base + u];
        cgt += (s > thr); ceq += (s == thr);
    }
    sg[tid] = cgt; se[tid] = ceq; __syncthreads();
    for (int off = 1; off < 256; off <<= 1) {
        int vg = (tid >= off) ? sg[tid - off] : 0;
        int ve = (tid >= off) ? se[tid - off] : 0;
        __syncthreads();
        sg[tid] += vg; se[tid] += ve;
        __syncthreads();
    }
    int total_gt = sg[255];
    int ties = k - total_gt;
    int gtb = sg[tid] - cgt, eqb = se[tid] - ceq;
    for (int u = 0; u < chunk; ++u) {
        int i = base + u;
        float s = sc[i];
        bool isgt = (s > thr), iseq = (s == thr);
        bool keep = isgt || (iseq && eqb < ties);
        if (keep) {
            int pos = gtb + (eqb < ties ? eqb : ties);
            idx_local[b * NTOT + pos] = i;
            gate[b * NTOT + pos] = tanhf(s);
            orig_next[b * NTOT + pos] = orig_cur[b * NTOT + i];
        }
        gtb += isgt; eqb += iseq;
    }
}

// gather gated rows, recompute stats, write z, and set inverse map
__global__ void __launch_bounds__(64) gather_kernel(
    const float* __restrict__ h, const int* __restrict__ idx_local,
    const float* __restrict__ gate, const int* __restrict__ orig_new,
    float* __restrict__ hout, float* __restrict__ zout, int* __restrict__ inv,
    int n_old, int k, int tag) {
    int r = blockIdx.x;  // B*k
    int b = r / k, rr = r - b * k;
    int lane = threadIdx.x;
    int src = idx_local[b * NTOT + rr];
    float gg = gate[b * NTOT + rr];
    f32x4 v = ((const f32x4*)h)[(size_t)(b * n_old + src) * 64 + lane] * gg;
    ((f32x4*)hout)[(size_t)r * 64 + lane] = v;
    float s = v[0] + v[1] + v[2] + v[3];
    float ss = v[0] * v[0] + v[1] * v[1] + v[2] * v[2] + v[3] * v[3];
#pragma unroll
    for (int m = 1; m < 64; m <<= 1) { s += __shfl_xor(s, m); ss += __shfl_xor(ss, m); }
    float mean = s * (1.0f / DD);
    float rs = rsqrtf(ss * (1.0f / DD) - mean * mean + 1e-5f);
    f32x4 zv = (v - mean) * rs;
    ((f32x4*)zout)[(size_t)r * 64 + lane] = zv;
    if (lane == 0) inv[b * NTOT + orig_new[b * NTOT + rr]] = (tag << 12) | rr;
}

// ---------------- fused readout + final projection (4 blocks) ----------------
__global__ void __launch_bounds__(256) readout_final_kernel(
    const float* __restrict__ h, const float* __restrict__ lw,
    const float* __restrict__ lb, float* __restrict__ out) {
    __shared__ float feat[512];
    int b = blockIdx.x, d = threadIdx.x;
    const float* hb = h + (size_t)b * 256 * DD;
    float s = 0.f;
    for (int i = 0; i < 256; ++i) s += hb[(size_t)i * DD + d];
    float mean = s / 256.0f;
    float s2 = 0.f;
    for (int i = 0; i < 256; ++i) {
        float diff = hb[(size_t)i * DD + d] - mean;
        s2 += diff * diff;
    }
    feat[d] = mean;
    feat[256 + d] = sqrtf(s2 / 255.0f) + 1e-6f;
    __syncthreads();
    if (d < 128) {
        float acc = lb[d];
        for (int k = 0; k < 512; ++k) acc += feat[k] * lw[k * 128 + d];
        out[b * 128 + d] = acc;
    }
}

extern "C" void kernel_launch(void* const* d_in, const int* in_sizes, int n_in,
                              void* d_out, int out_size, void* d_ws, size_t ws_size,
                              hipStream_t stream) {
    (void)in_sizes; (void)n_in; (void)out_size; (void)ws_size;
    const float* x     = (const float*)d_in[0];
    const float* adj   = (const float*)d_in[1];
    const float* pos   = (const float*)d_in[2];
    const float* in_w  = (const float*)d_in[3];
    const float* in_b  = (const float*)d_in[4];
    const float* pw1   = (const float*)d_in[5];
    const float* pb1   = (const float*)d_in[6];
    const float* pw2   = (const float*)d_in[7];
    const float* pb2   = (const float*)d_in[8];
    const float* bg    = (const float*)d_in[9];
    const float* bb    = (const float*)d_in[10];
    const float* bw1   = (const float*)d_in[11];
    const float* bb1   = (const float*)d_in[12];
    const float* bw2   = (const float*)d_in[13];
    const float* bb2   = (const float*)d_in[14];
    const float* beps  = (const float*)d_in[15];
    const float* poolp = (const float*)d_in[16];
    const float* lw    = (const float*)d_in[17];
    const float* lb    = (const float*)d_in[18];
    float* out = (float*)d_out;

    char* wp = (char*)d_ws;
    auto alloc = [&](size_t bytes) -> void* {
        void* p = (void*)wp;
        wp += (bytes + 255) & ~(size_t)255;
        return p;
    };
    const size_t HBYTES = (size_t)BSZ * NTOT * DD * sizeof(float);  // 8.39 MB
    float*  h    = (float*)alloc(HBYTES);
    float*  bufC = (float*)alloc(HBYTES);          // gather target
    float*  zA   = (float*)alloc(HBYTES);
    float*  zB   = (float*)alloc(HBYTES);
    half_t* Wt   = (half_t*)alloc((size_t)17 * DD * DD * sizeof(half_t));
    float* pstats  = (float*)alloc(8 * sizeof(float));
    float* pinv    = (float*)alloc(4 * sizeof(float));
    float* scores  = (float*)alloc(BSZ * NTOT * sizeof(float));
    float* gate    = (float*)alloc(BSZ * NTOT * sizeof(float));
    int*   origA   = (int*)alloc(BSZ * NTOT * sizeof(int));
    int*   origB   = (int*)alloc(BSZ * NTOT * sizeof(int));
    int*   idxl    = (int*)alloc(BSZ * NTOT * sizeof(int));
    int*   inv     = (int*)alloc(BSZ * NTOT * sizeof(int));
    int*   ldeg0   = (int*)alloc(NTOT * sizeof(int));
    int*   lcol0   = (int*)alloc((size_t)NTOT * 64 * sizeof(int));

    // ---- init: 2 dispatches ----
    setup_kernel<<<SB_MAPS, 256, 0, stream>>>(bw1, bw2, pw2, Wt, pos, pstats, poolp, pinv,
                                              adj, ldeg0, lcol0, origA, inv);
    pe_h_kernel<<<NTOT / 16, 256, 0, stream>>>(pos, pstats, pw1, pb1,
                                               Wt + (size_t)16 * DD * DD, pb2,
                                               x, in_w, in_b, h, zA);

    float* hcur = h;
    float* halt = bufC;
    float* zin = zA;
    float* zout = zB;
    int* orig = origA;
    int* orign = origB;
    int n = NTOT;
    int blk = 0;
    for (int dep = 0; dep < 4; ++dep) {
        for (int s = 0; s < 2; ++s) {
            int rows = BSZ * n;
            const half_t* W1 = Wt + (size_t)blk * DD * DD;
            const half_t* W2 = Wt + (size_t)(8 + blk) * DD * DD;
            const float* B1 = bb1 + blk * DD;
            const float* B2 = bb2 + blk * DD;
            const float* G  = bg + blk * DD;
            const float* BB = bb + blk * DD;
            int sc = (s == 1 && dep < 3) ? 1 : 0;
            if (dep < 2) {
                if (sc) layer_kernel<8, 1><<<rows / 8, 256, 0, stream>>>(
                    hcur, zin, zout, W1, W2, B1, B2, G, BB, beps, blk,
                    ldeg0, lcol0, orig, inv, poolp, pinv, scores, dep, n, dep);
                else    layer_kernel<8, 0><<<rows / 8, 256, 0, stream>>>(
                    hcur, zin, zout, W1, W2, B1, B2, G, BB, beps, blk,
                    ldeg0, lcol0, orig, inv, nullptr, nullptr, nullptr, 0, n, dep);
            } else {
                if (sc) layer_kernel<4, 1><<<rows / 4, 256, 0, stream>>>(
                    hcur, zin, zout, W1, W2, B1, B2, G, BB, beps, blk,
                    ldeg0, lcol0, orig, inv, poolp, pinv, scores, dep, n, dep);
                else    layer_kernel<4, 0><<<rows / 4, 256, 0, stream>>>(
                    hcur, zin, zout, W1, W2, B1, B2, G, BB, beps, blk,
                    ldeg0, lcol0, orig, inv, nullptr, nullptr, nullptr, 0, n, dep);
            }
            { float* t = zin; zin = zout; zout = t; }
            ++blk;
        }
        if (dep < 3) {
            int k = n / 2;
            topk_kernel<<<BSZ, 256, 0, stream>>>(scores, orig, orign, idxl, gate, n, k);
            { int* t = orig; orig = orign; orign = t; }
            gather_kernel<<<BSZ * k, 64, 0, stream>>>(hcur, idxl, gate, orig, halt, zin, inv,
                                                      n, k, dep + 1);
            { float* t = hcur; hcur = halt; halt = t; }
            n = k;
        }
    }
    // ---- readout + final ----
    readout_final_kernel<<<BSZ, 256, 0, stream>>>(hcur, lw, lb, out);
}

// Round 10
// 293.535 us; speedup vs baseline: 1.1177x; 1.1177x over previous
//
#include <hip/hip_runtime.h>
#include <hip/hip_bf16.h>

#define NTOT 2048
#define DD 256
#define BSZ 4

typedef _Float16 half_t;
typedef __attribute__((ext_vector_type(8))) _Float16 halfx8;
typedef __attribute__((ext_vector_type(4))) _Float16 halfx4;
typedef __attribute__((ext_vector_type(4))) float f32x4;

// ---------------- block reduce (256 threads) ----------------
__device__ __forceinline__ float blockReduceSum256(float v) {
    __shared__ float red[4];
    for (int off = 32; off > 0; off >>= 1) v += __shfl_down(v, off);
    int lane = threadIdx.x & 63, w = threadIdx.x >> 6;
    __syncthreads();
    if (lane == 0) red[w] = v;
    __syncthreads();
    return red[0] + red[1] + red[2] + red[3];
}

// ---------------- mega setup: wprep | stats | adj->lcol0 | maps ----------------
#define SB_WPREP 4352
#define SB_STAT  4356
#define SB_A2L   4868
#define SB_MAPS  4900
__global__ void __launch_bounds__(256) setup_kernel(
    const float* __restrict__ bw1, const float* __restrict__ bw2,
    const float* __restrict__ pw2, half_t* __restrict__ Wt,
    const float* __restrict__ pos, float* __restrict__ pstats,
    const float* __restrict__ poolp, float* __restrict__ pinv,
    const float* __restrict__ adj, int* __restrict__ ldeg0, int* __restrict__ lcol0,
    int* __restrict__ orig, int* __restrict__ inv) {
    int bid = blockIdx.x, tid = threadIdx.x;
    if (bid < SB_WPREP) {
        int m = bid >> 8, rem = bid & 255;
        int nb = (rem >> 4) * 16, kb = (rem & 15) * 16;
        const float* W = (m < 8) ? (bw1 + (size_t)m * DD * DD)
                      : (m < 16) ? (bw2 + (size_t)(m - 8) * DD * DD)
                                 : pw2;
        __shared__ float s[16][17];
        int i = tid >> 4, j = tid & 15;
        s[i][j] = W[(size_t)(kb + i) * DD + nb + j];
        __syncthreads();
        Wt[(size_t)m * DD * DD + (size_t)(nb + i) * DD + kb + j] = (half_t)s[j][i];
    } else if (bid < SB_STAT) {
        int which = bid - SB_WPREP;
        if (which == 0) {
            float s[3] = {0.f, 0.f, 0.f};
            for (int i = tid; i < NTOT; i += 256)
                for (int c = 0; c < 3; ++c) s[c] += pos[i * 3 + c];
            float m[3];
            for (int c = 0; c < 3; ++c) m[c] = blockReduceSum256(s[c]) / (float)NTOT;
            float q[3] = {0.f, 0.f, 0.f};
            for (int i = tid; i < NTOT; i += 256)
                for (int c = 0; c < 3; ++c) { float d = pos[i * 3 + c] - m[c]; q[c] += d * d; }
            for (int c = 0; c < 3; ++c) {
                float t = blockReduceSum256(q[c]);
                if (tid == 0) {
                    float var = ((float)BSZ * t) / ((float)BSZ * NTOT - 1.0f);
                    pstats[c] = m[c];
                    pstats[3 + c] = 1.0f / (sqrtf(var) + 1e-8f);
                }
            }
        } else {
            int dep = which - 1;
            float v = poolp[dep * DD + tid];
            float ss = blockReduceSum256(v * v);
            if (tid == 0) pinv[dep] = rsqrtf(ss);
        }
    } else if (bid < SB_A2L) {
        int row = (bid - SB_STAT) * 4 + (tid >> 6);
        int lane = tid & 63;
        int run = 0;
        for (int j0 = 0; j0 < NTOT; j0 += 64) {
            int j = j0 + lane;
            bool pred = adj[(size_t)row * NTOT + j] != 0.f;
            unsigned long long mask = __ballot(pred);
            if (pred) {
                int pos2 = run + __popcll(mask & ((1ull << lane) - 1ull));
                if (pos2 < 64) lcol0[row * 64 + pos2] = j;
            }
            run += __popcll(mask);
        }
        if (lane == 0) ldeg0[row] = run < 64 ? run : 64;
    } else {
        int t = (bid - SB_A2L) * 256 + tid;  // B*NTOT
        int i = t & (NTOT - 1);
        orig[t] = i; inv[t] = i;  // tag 0
    }
}

// ---------------- fused pe + input projection + h/z init ----------------
__global__ void __launch_bounds__(256) pe_h_kernel(
    const float* __restrict__ pos, const float* __restrict__ pstats,
    const float* __restrict__ pw1, const float* __restrict__ pb1,
    const half_t* __restrict__ Wt16, const float* __restrict__ pb2,
    const float* __restrict__ x, const float* __restrict__ in_w,
    const float* __restrict__ in_b, float* __restrict__ h, float* __restrict__ z) {
    __shared__ half_t tb[16][264];
    __shared__ float iw[16][DD];
    __shared__ float xs[16][16];
    __shared__ float part[4][16][2];
    __shared__ float mrs[16][2];
    int tid = threadIdx.x;
    int i0 = blockIdx.x * 16;
    {
        int rl = tid >> 4, cb = (tid & 15) * 16;
        float pn[3];
#pragma unroll
        for (int c = 0; c < 3; ++c)
            pn[c] = (pos[(i0 + rl) * 3 + c] - pstats[c]) * pstats[3 + c];
#pragma unroll
        for (int u = 0; u < 16; ++u) {
            int d = cb + u;
            float a = pb1[d];
            a += pn[0] * pw1[d];
            a += pn[1] * pw1[DD + d];
            a += pn[2] * pw1[2 * DD + d];
            a = a / (1.0f + expf(-a));
            tb[rl][d] = (half_t)a;
        }
        int k = tid >> 4;
#pragma unroll
        for (int u = 0; u < 16; ++u) iw[k][cb + u] = in_w[k * DD + cb + u];
    }
    __syncthreads();
    int w = tid >> 6, l = tid & 63;
    int lo = l & 15, hi = l >> 4;
    int kb = hi * 8;
    float pe_r[4][4];
    {
        f32x4 acc[4] = {};
#pragma unroll
        for (int k0 = 0; k0 < DD; k0 += 32) {
            halfx8 a0 = *(const halfx8*)&tb[lo][kb + k0];
#pragma unroll
            for (int j = 0; j < 4; ++j) {
                halfx8 bj = *(const halfx8*)(Wt16 + (size_t)(w * 64 + j * 16 + lo) * DD + kb + k0);
                acc[j] = __builtin_amdgcn_mfma_f32_16x16x32_f16(a0, bj, acc[j], 0, 0, 0);
            }
        }
#pragma unroll
        for (int j = 0; j < 4; ++j) {
            float bs = pb2[w * 64 + j * 16 + lo];
#pragma unroll
            for (int q = 0; q < 4; ++q) pe_r[j][q] = acc[j][q] + bs;
        }
    }
    float xb[4];
#pragma unroll
    for (int j = 0; j < 4; ++j) xb[j] = in_b[w * 64 + j * 16 + lo];
    for (int b = 0; b < BSZ; ++b) {
        __syncthreads();
        xs[tid >> 4][tid & 15] = x[(size_t)(b * NTOT + i0 + (tid >> 4)) * 16 + (tid & 15)];
        __syncthreads();
        float vh[4][4];
#pragma unroll
        for (int q = 0; q < 4; ++q) {
            int rl = hi * 4 + q;
            float s = 0.f, ss = 0.f;
#pragma unroll
            for (int j = 0; j < 4; ++j) {
                int c = w * 64 + j * 16 + lo;
                float acc = xb[j];
#pragma unroll
                for (int k = 0; k < 16; ++k) acc += xs[rl][k] * iw[k][c];
                float v = acc + pe_r[j][q];
                vh[j][q] = v;
                s += v; ss += v * v;
            }
#pragma unroll
            for (int m = 1; m < 16; m <<= 1) { s += __shfl_xor(s, m); ss += __shfl_xor(ss, m); }
            if (lo == 0) { part[w][rl][0] = s; part[w][rl][1] = ss; }
        }
        __syncthreads();
        if (tid < 16) {
            float s = 0.f, ss = 0.f;
#pragma unroll
            for (int w2 = 0; w2 < 4; ++w2) { s += part[w2][tid][0]; ss += part[w2][tid][1]; }
            float mean = s * (1.0f / DD);
            float var = ss * (1.0f / DD) - mean * mean;
            mrs[tid][0] = mean;
            mrs[tid][1] = rsqrtf(var + 1e-5f);
        }
        __syncthreads();
#pragma unroll
        for (int q = 0; q < 4; ++q) {
            int rl = hi * 4 + q;
            size_t r = (size_t)(b * NTOT + i0 + rl);
            float mean = mrs[rl][0], rs = mrs[rl][1];
#pragma unroll
            for (int j = 0; j < 4; ++j) {
                int c = w * 64 + j * 16 + lo;
                float v = vh[j][q];
                h[r * DD + c] = v;
                z[r * DD + c] = (v - mean) * rs;
            }
        }
    }
}

// ---------------- standalone aggregation: one wave per row (big tiers) ----------------
// t = g*(eps1*z_s + sum_j z_j) + (eps1+cnt)*b -> f16 tb (global)
__global__ void __launch_bounds__(256) agg_kernel(
    const float* __restrict__ zin, half_t* __restrict__ tb,
    const float* __restrict__ gv, const float* __restrict__ bbv,
    const float* __restrict__ beps, int blk,
    const int* __restrict__ ldeg0, const int* __restrict__ lcol0,
    const int* __restrict__ orig, const int* __restrict__ inv, int n, int tag) {
    int w = threadIdx.x >> 6, lane = threadIdx.x & 63;
    int r = blockIdx.x * 4 + w;  // 0..B*n-1
    int b = r / n, i = r - b * n;
    float eps1 = 1.0f + beps[blk];
    const f32x4* zb = (const f32x4*)zin + (size_t)b * n * 64;
    f32x4 acc = zb[(size_t)i * 64 + lane] * eps1;
    int cnt = 0;
    if (tag == 0) {
        int deg = ldeg0[i];
        const int* lc = lcol0 + i * 64;
        int p = 0;
        for (; p + 4 <= deg; p += 4) {
            int j0 = lc[p], j1 = lc[p + 1], j2 = lc[p + 2], j3 = lc[p + 3];
            f32x4 v0 = zb[(size_t)j0 * 64 + lane];
            f32x4 v1 = zb[(size_t)j1 * 64 + lane];
            f32x4 v2 = zb[(size_t)j2 * 64 + lane];
            f32x4 v3 = zb[(size_t)j3 * 64 + lane];
            acc += (v0 + v1) + (v2 + v3);
        }
        for (; p < deg; ++p) acc += zb[(size_t)lc[p] * 64 + lane];
        cnt = deg;
    } else {
        int o = orig[b * NTOT + i];
        int deg = ldeg0[o];
        const int* lc = lcol0 + o * 64;
        const int* invb = inv + b * NTOT;
        int p = 0;
        for (; p + 4 <= deg; p += 4) {
            int v0 = invb[lc[p]], v1 = invb[lc[p + 1]];
            int v2 = invb[lc[p + 2]], v3 = invb[lc[p + 3]];
            if ((v0 >> 12) == tag) { acc += zb[(size_t)(v0 & 4095) * 64 + lane]; ++cnt; }
            if ((v1 >> 12) == tag) { acc += zb[(size_t)(v1 & 4095) * 64 + lane]; ++cnt; }
            if ((v2 >> 12) == tag) { acc += zb[(size_t)(v2 & 4095) * 64 + lane]; ++cnt; }
            if ((v3 >> 12) == tag) { acc += zb[(size_t)(v3 & 4095) * 64 + lane]; ++cnt; }
        }
        for (; p < deg; ++p) {
            int v = invb[lc[p]];
            if ((v >> 12) == tag) { acc += zb[(size_t)(v & 4095) * 64 + lane]; ++cnt; }
        }
    }
    float coefb = eps1 + (float)cnt;
    f32x4 gvv = ((const f32x4*)gv)[lane];
    f32x4 bvv = ((const f32x4*)bbv)[lane];
    f32x4 tv = gvv * acc + bvv * coefb;
    halfx4 th;
#pragma unroll
    for (int e = 0; e < 4; ++e) th[e] = (half_t)tv[e];
    ((halfx4*)tb)[(size_t)r * 64 + lane] = th;
}

// ---------------- MLP (big tiers): A from global tb; mm1+silu -> LDS -> mm2+res/stats/z ----
template <int SCORE>
__global__ void __launch_bounds__(256) mlp_kernel(
    float* __restrict__ h, const half_t* __restrict__ tbg, float* __restrict__ zout,
    const half_t* __restrict__ Wt1, const half_t* __restrict__ Wt2,
    const float* __restrict__ b1v, const float* __restrict__ b2v,
    const float* __restrict__ poolp, const float* __restrict__ pinv_all,
    float* __restrict__ scores, int dep, int n) {
    __shared__ half_t ub[16][264];
    __shared__ float part[4][16][3];
    __shared__ float mrs[16][2];
    int tid = threadIdx.x;
    int rowBase = blockIdx.x * 16;
    int w = tid >> 6, l = tid & 63;
    int lo = l & 15, hi = l >> 4;
    int kb = hi * 8;

    {
        const half_t* a0p = tbg + (size_t)(rowBase + lo) * DD + kb;
        f32x4 acc[4] = {};
#pragma unroll
        for (int k0 = 0; k0 < DD; k0 += 32) {
            halfx8 a0 = *(const halfx8*)(a0p + k0);
#pragma unroll
            for (int j = 0; j < 4; ++j) {
                halfx8 bj = *(const halfx8*)(Wt1 + (size_t)(w * 64 + j * 16 + lo) * DD + kb + k0);
                acc[j] = __builtin_amdgcn_mfma_f32_16x16x32_f16(a0, bj, acc[j], 0, 0, 0);
            }
        }
        float bs[4];
#pragma unroll
        for (int j = 0; j < 4; ++j) bs[j] = b1v[w * 64 + j * 16 + lo];
#pragma unroll
        for (int q = 0; q < 4; ++q)
#pragma unroll
            for (int j = 0; j < 4; ++j) {
                float v = acc[j][q] + bs[j];
                v = v / (1.0f + expf(-v));
                ub[hi * 4 + q][w * 64 + j * 16 + lo] = (half_t)v;
            }
    }
    __syncthreads();

    {
        f32x4 acc[4] = {};
#pragma unroll
        for (int k0 = 0; k0 < DD; k0 += 32) {
            halfx8 a0 = *(const halfx8*)&ub[lo][kb + k0];
#pragma unroll
            for (int j = 0; j < 4; ++j) {
                halfx8 bj = *(const halfx8*)(Wt2 + (size_t)(w * 64 + j * 16 + lo) * DD + kb + k0);
                acc[j] = __builtin_amdgcn_mfma_f32_16x16x32_f16(a0, bj, acc[j], 0, 0, 0);
            }
        }
        float bs[4], pv[4] = {};
#pragma unroll
        for (int j = 0; j < 4; ++j) bs[j] = b2v[w * 64 + j * 16 + lo];
        if (SCORE) {
#pragma unroll
            for (int j = 0; j < 4; ++j) pv[j] = poolp[dep * DD + w * 64 + j * 16 + lo];
        }
        float vh[4][4];
#pragma unroll
        for (int q = 0; q < 4; ++q) {
            int r = rowBase + hi * 4 + q;
            float s = 0.f, ss = 0.f, sp = 0.f;
#pragma unroll
            for (int j = 0; j < 4; ++j) {
                int c = w * 64 + j * 16 + lo;
                float v = h[(size_t)r * DD + c] + acc[j][q] + bs[j];
                vh[j][q] = v;
                s += v; ss += v * v;
                if (SCORE) sp += v * pv[j];
            }
#pragma unroll
            for (int m = 1; m < 16; m <<= 1) {
                s += __shfl_xor(s, m); ss += __shfl_xor(ss, m);
                if (SCORE) sp += __shfl_xor(sp, m);
            }
            if (lo == 0) {
                int rl = hi * 4 + q;
                part[w][rl][0] = s; part[w][rl][1] = ss;
                if (SCORE) part[w][rl][2] = sp;
            }
        }
        __syncthreads();
        if (tid < 16) {
            float s = 0.f, ss = 0.f, sp = 0.f;
#pragma unroll
            for (int w2 = 0; w2 < 4; ++w2) {
                s += part[w2][tid][0]; ss += part[w2][tid][1];
                if (SCORE) sp += part[w2][tid][2];
            }
            float mean = s * (1.0f / DD);
            float var = ss * (1.0f / DD) - mean * mean;
            mrs[tid][0] = mean;
            mrs[tid][1] = rsqrtf(var + 1e-5f);
            if (SCORE) {
                int r = rowBase + tid;
                int b2 = r / n, ii = r - b2 * n;
                scores[b2 * NTOT + ii] = sp * pinv_all[dep];
            }
        }
        __syncthreads();
#pragma unroll
        for (int q = 0; q < 4; ++q) {
            int rl = hi * 4 + q;
            int r = rowBase + rl;
            float mean = mrs[rl][0], rs = mrs[rl][1];
#pragma unroll
            for (int j = 0; j < 4; ++j) {
                int c = w * 64 + j * 16 + lo;
                float v = vh[j][q];
                h[(size_t)r * DD + c] = v;
                zout[(size_t)r * DD + c] = (v - mean) * rs;
            }
        }
    }
}

// ---------------- fused layer (small tiers), 16 rows/block ----------------
template <int SCORE>
__global__ void __launch_bounds__(256) layer_kernel(
    float* __restrict__ h, const float* __restrict__ zin, float* __restrict__ zout,
    const half_t* __restrict__ Wt1, const half_t* __restrict__ Wt2,
    const float* __restrict__ b1v, const float* __restrict__ b2v,
    const float* __restrict__ gv, const float* __restrict__ bbv,
    const float* __restrict__ beps, int blk,
    const int* __restrict__ ldeg0, const int* __restrict__ lcol0,
    const int* __restrict__ orig, const int* __restrict__ inv,
    const float* __restrict__ poolp, const float* __restrict__ pinv_all,
    float* __restrict__ scores, int dep, int n, int tag) {
    __shared__ half_t tb[16][264];
    __shared__ half_t ub[16][264];
    __shared__ float part[4][16][3];
    __shared__ float mrs[16][2];
    int tid = threadIdx.x;
    int rowBase = blockIdx.x * 16;
    float eps1 = 1.0f + beps[blk];

    // ---- phase A ----
    {
        int rl = tid >> 4, cg = tid & 15;
        int r = rowBase + rl;
        int b = r / n, i = r - b * n;
        const f32x4* zb = (const f32x4*)zin + (size_t)b * n * 64;
        f32x4 acc[4];
#pragma unroll
        for (int u = 0; u < 4; ++u) acc[u] = zb[(size_t)i * 64 + cg + 16 * u] * eps1;
        int cnt = 0;
        if (tag == 0) {
            int deg = ldeg0[i];
            const int* lc = lcol0 + i * 64;
            int p = 0;
            for (; p + 4 <= deg; p += 4) {
                int j0 = lc[p], j1 = lc[p + 1], j2 = lc[p + 2], j3 = lc[p + 3];
#pragma unroll
                for (int u = 0; u < 4; ++u) {
                    f32x4 v0 = zb[(size_t)j0 * 64 + cg + 16 * u];
                    f32x4 v1 = zb[(size_t)j1 * 64 + cg + 16 * u];
                    f32x4 v2 = zb[(size_t)j2 * 64 + cg + 16 * u];
                    f32x4 v3 = zb[(size_t)j3 * 64 + cg + 16 * u];
                    acc[u] += (v0 + v1) + (v2 + v3);
                }
            }
            for (; p < deg; ++p) {
                int j = lc[p];
#pragma unroll
                for (int u = 0; u < 4; ++u) acc[u] += zb[(size_t)j * 64 + cg + 16 * u];
            }
            cnt = deg;
        } else {
            int o = orig[b * NTOT + i];
            int deg = ldeg0[o];
            const int* lc = lcol0 + o * 64;
            const int* invb = inv + b * NTOT;
            int p = 0;
            for (; p + 4 <= deg; p += 4) {
                int v0 = invb[lc[p]], v1 = invb[lc[p + 1]];
                int v2 = invb[lc[p + 2]], v3 = invb[lc[p + 3]];
                if ((v0 >> 12) == tag) {
                    int j = v0 & 4095; ++cnt;
#pragma unroll
                    for (int u = 0; u < 4; ++u) acc[u] += zb[(size_t)j * 64 + cg + 16 * u];
                }
                if ((v1 >> 12) == tag) {
                    int j = v1 & 4095; ++cnt;
#pragma unroll
                    for (int u = 0; u < 4; ++u) acc[u] += zb[(size_t)j * 64 + cg + 16 * u];
                }
                if ((v2 >> 12) == tag) {
                    int j = v2 & 4095; ++cnt;
#pragma unroll
                    for (int u = 0; u < 4; ++u) acc[u] += zb[(size_t)j * 64 + cg + 16 * u];
                }
                if ((v3 >> 12) == tag) {
                    int j = v3 & 4095; ++cnt;
#pragma unroll
                    for (int u = 0; u < 4; ++u) acc[u] += zb[(size_t)j * 64 + cg + 16 * u];
                }
            }
            for (; p < deg; ++p) {
                int v = invb[lc[p]];
                if ((v >> 12) == tag) {
                    int j = v & 4095; ++cnt;
#pragma unroll
                    for (int u = 0; u < 4; ++u) acc[u] += zb[(size_t)j * 64 + cg + 16 * u];
                }
            }
        }
        float coefb = eps1 + (float)cnt;
#pragma unroll
        for (int u = 0; u < 4; ++u) {
            int c4 = cg + 16 * u;
            f32x4 gvv = ((const f32x4*)gv)[c4];
            f32x4 bvv = ((const f32x4*)bbv)[c4];
            f32x4 tv = gvv * acc[u] + bvv * coefb;
            halfx4 th;
#pragma unroll
            for (int e = 0; e < 4; ++e) th[e] = (half_t)tv[e];
            *(halfx4*)&tb[rl][c4 * 4] = th;
        }
    }
    __syncthreads();

    int w = tid >> 6, l = tid & 63;
    int lo = l & 15, hi = l >> 4;
    int kb = hi * 8;

    // ---- phase B ----
    {
        f32x4 acc[4] = {};
#pragma unroll
        for (int k0 = 0; k0 < DD; k0 += 32) {
            halfx8 a0 = *(const halfx8*)&tb[lo][kb + k0];
#pragma unroll
            for (int j = 0; j < 4; ++j) {
                halfx8 bj = *(const halfx8*)(Wt1 + (size_t)(w * 64 + j * 16 + lo) * DD + kb + k0);
                acc[j] = __builtin_amdgcn_mfma_f32_16x16x32_f16(a0, bj, acc[j], 0, 0, 0);
            }
        }
        float bs[4];
#pragma unroll
        for (int j = 0; j < 4; ++j) bs[j] = b1v[w * 64 + j * 16 + lo];
#pragma unroll
        for (int q = 0; q < 4; ++q)
#pragma unroll
            for (int j = 0; j < 4; ++j) {
                float v = acc[j][q] + bs[j];
                v = v / (1.0f + expf(-v));
                ub[hi * 4 + q][w * 64 + j * 16 + lo] = (half_t)v;
            }
    }
    __syncthreads();

    // ---- phase C ----
    {
        f32x4 acc[4] = {};
#pragma unroll
        for (int k0 = 0; k0 < DD; k0 += 32) {
            halfx8 a0 = *(const halfx8*)&ub[lo][kb + k0];
#pragma unroll
            for (int j = 0; j < 4; ++j) {
                halfx8 bj = *(const halfx8*)(Wt2 + (size_t)(w * 64 + j * 16 + lo) * DD + kb + k0);
                acc[j] = __builtin_amdgcn_mfma_f32_16x16x32_f16(a0, bj, acc[j], 0, 0, 0);
            }
        }
        float bs[4], pv[4] = {};
#pragma unroll
        for (int j = 0; j < 4; ++j) bs[j] = b2v[w * 64 + j * 16 + lo];
        if (SCORE) {
#pragma unroll
            for (int j = 0; j < 4; ++j) pv[j] = poolp[dep * DD + w * 64 + j * 16 + lo];
        }
        float vh[4][4];
#pragma unroll
        for (int q = 0; q < 4; ++q) {
            int r = rowBase + hi * 4 + q;
            float s = 0.f, ss = 0.f, sp = 0.f;
#pragma unroll
            for (int j = 0; j < 4; ++j) {
                int c = w * 64 + j * 16 + lo;
                float v = h[(size_t)r * DD + c] + acc[j][q] + bs[j];
                vh[j][q] = v;
                s += v; ss += v * v;
                if (SCORE) sp += v * pv[j];
            }
#pragma unroll
            for (int m = 1; m < 16; m <<= 1) {
                s += __shfl_xor(s, m); ss += __shfl_xor(ss, m);
                if (SCORE) sp += __shfl_xor(sp, m);
            }
            if (lo == 0) {
                int rl = hi * 4 + q;
                part[w][rl][0] = s; part[w][rl][1] = ss;
                if (SCORE) part[w][rl][2] = sp;
            }
        }
        __syncthreads();
        if (tid < 16) {
            float s = 0.f, ss = 0.f, sp = 0.f;
#pragma unroll
            for (int w2 = 0; w2 < 4; ++w2) {
                s += part[w2][tid][0]; ss += part[w2][tid][1];
                if (SCORE) sp += part[w2][tid][2];
            }
            float mean = s * (1.0f / DD);
            float var = ss * (1.0f / DD) - mean * mean;
            mrs[tid][0] = mean;
            mrs[tid][1] = rsqrtf(var + 1e-5f);
            if (SCORE) {
                int r = rowBase + tid;
                int b2 = r / n, ii = r - b2 * n;
                scores[b2 * NTOT + ii] = sp * pinv_all[dep];
            }
        }
        __syncthreads();
#pragma unroll
        for (int q = 0; q < 4; ++q) {
            int rl = hi * 4 + q;
            int r = rowBase + rl;
            float mean = mrs[rl][0], rs = mrs[rl][1];
#pragma unroll
            for (int j = 0; j < 4; ++j) {
                int c = w * 64 + j * 16 + lo;
                float v = vh[j][q];
                h[(size_t)r * DD + c] = v;
                zout[(size_t)r * DD + c] = (v - mean) * rs;
            }
        }
    }
}

// ---------------- pooling: 1-pass radix + candidate rank (fallback: full radix) ----------------
__global__ void topk_kernel(const float* __restrict__ scores, const int* __restrict__ orig_cur,
                            int* __restrict__ orig_next, int* __restrict__ idx_local,
                            float* __restrict__ gate, int n, int k) {
    __shared__ unsigned keys[2048];
    __shared__ int hist[256];
    __shared__ int sg[256], se[256];
    __shared__ int sh_bucket, sh_r, sh_cnt;
    __shared__ unsigned cand[256];
    __shared__ unsigned sh_thr;
    int b = blockIdx.x;
    const float* sc = scores + b * NTOT;
    int tid = threadIdx.x;
    for (int i = tid; i < n; i += 256) {
        unsigned u = __float_as_uint(sc[i]);
        keys[i] = (u & 0x80000000u) ? ~u : (u | 0x80000000u);
    }
    hist[tid] = 0;
    if (tid == 0) sh_cnt = 0;
    __syncthreads();
    for (int i = tid; i < n; i += 256) atomicAdd(&hist[keys[i] >> 24], 1);
    __syncthreads();
    int cnt = hist[tid];
    sg[tid] = cnt;
    __syncthreads();
    for (int off = 1; off < 256; off <<= 1) {
        int v = (tid >= off) ? sg[tid - off] : 0;
        __syncthreads();
        sg[tid] += v;
        __syncthreads();
    }
    int r = n - k;  // 0-indexed rank ascending
    int incl = sg[tid], excl = incl - cnt;
    if (excl <= r && r < incl) { sh_bucket = tid; sh_r = r - excl; }
    __syncthreads();
    int b1 = sh_bucket, r1 = sh_r;
    int c = hist[b1];
    unsigned thrkey;
    if (c <= 256) {
        for (int i = tid; i < n; i += 256) {
            unsigned key = keys[i];
            if ((key >> 24) == (unsigned)b1) {
                int pos = atomicAdd(&sh_cnt, 1);
                cand[pos] = key;
            }
        }
        __syncthreads();
        if (tid < c) {
            unsigned mine = cand[tid];
            int less = 0, eq = 0;
            for (int j = 0; j < c; ++j) {
                unsigned oth = cand[j];
                less += (oth < mine); eq += (oth == mine);
            }
            if (less <= r1 && r1 < less + eq) sh_thr = mine;
        }
        __syncthreads();
        thrkey = sh_thr;
    } else {
        unsigned prefix = ((unsigned)b1) << 24;
        int rr = r1;
        for (int shift = 16; shift >= 0; shift -= 8) {
            __syncthreads();
            hist[tid] = 0;
            __syncthreads();
            unsigned mask = 0xFFFFFFFFu << (shift + 8);
            for (int i = tid; i < n; i += 256) {
                unsigned key = keys[i];
                if ((key & mask) == (prefix & mask)) atomicAdd(&hist[(key >> shift) & 255], 1);
            }
            __syncthreads();
            int cnt2 = hist[tid];
            sg[tid] = cnt2;
            __syncthreads();
            for (int off = 1; off < 256; off <<= 1) {
                int v = (tid >= off) ? sg[tid - off] : 0;
                __syncthreads();
                sg[tid] += v;
                __syncthreads();
            }
            int incl2 = sg[tid], excl2 = incl2 - cnt2;
            if (excl2 <= rr && rr < incl2) { sh_bucket = tid; sh_r = rr - excl2; }
            __syncthreads();
            prefix |= ((unsigned)sh_bucket) << shift;
            rr = sh_r;
            __syncthreads();
        }
        thrkey = prefix;
    }
    unsigned uthr = (thrkey & 0x80000000u) ? (thrkey ^ 0x80000000u) : ~thrkey;
    float thr = __uint_as_float(uthr);  // exact k-th largest value
    int chunk = n / 256;
    int base = tid * chunk;
    int cgt = 0, ceq = 0;
    for (int u = 0; u < chunk; ++u) {
        float s = sc[base + u];
        cgt += (s > thr); ceq += (s == thr);
    }
    sg[tid] = cgt; se[tid] = ceq; __syncthreads();
    for (int off = 1; off < 256; off <<= 1) {
        int vg = (tid >= off) ? sg[tid - off] : 0;
        int ve = (tid >= off) ? se[tid - off] : 0;
        __syncthreads();
        sg[tid] += vg; se[tid] += ve;
        __syncthreads();
    }
    int total_gt = sg[255];
    int ties = k - total_gt;
    int gtb = sg[tid] - cgt, eqb = se[tid] - ceq;
    for (int u = 0; u < chunk; ++u) {
        int i = base + u;
        float s = sc[i];
        bool isgt = (s > thr), iseq = (s == thr);
        bool keep = isgt || (iseq && eqb < ties);
        if (keep) {
            int pos = gtb + (eqb < ties ? eqb : ties);
            idx_local[b * NTOT + pos] = i;
            gate[b * NTOT + pos] = tanhf(s);
            orig_next[b * NTOT + pos] = orig_cur[b * NTOT + i];
        }
        gtb += isgt; eqb += iseq;
    }
}

// gather gated rows, recompute stats, write z, and set inverse map
__global__ void __launch_bounds__(64) gather_kernel(
    const float* __restrict__ h, const int* __restrict__ idx_local,
    const float* __restrict__ gate, const int* __restrict__ orig_new,
    float* __restrict__ hout, float* __restrict__ zout, int* __restrict__ inv,
    int n_old, int k, int tag) {
    int r = blockIdx.x;  // B*k
    int b = r / k, rr = r - b * k;
    int lane = threadIdx.x;
    int src = idx_local[b * NTOT + rr];
    float gg = gate[b * NTOT + rr];
    f32x4 v = ((const f32x4*)h)[(size_t)(b * n_old + src) * 64 + lane] * gg;
    ((f32x4*)hout)[(size_t)r * 64 + lane] = v;
    float s = v[0] + v[1] + v[2] + v[3];
    float ss = v[0] * v[0] + v[1] * v[1] + v[2] * v[2] + v[3] * v[3];
#pragma unroll
    for (int m = 1; m < 64; m <<= 1) { s += __shfl_xor(s, m); ss += __shfl_xor(ss, m); }
    float mean = s * (1.0f / DD);
    float rs = rsqrtf(ss * (1.0f / DD) - mean * mean + 1e-5f);
    f32x4 zv = (v - mean) * rs;
    ((f32x4*)zout)[(size_t)r * 64 + lane] = zv;
    if (lane == 0) inv[b * NTOT + orig_new[b * NTOT + rr]] = (tag << 12) | rr;
}

// ---------------- fused readout + final projection (4 blocks) ----------------
__global__ void __launch_bounds__(256) readout_final_kernel(
    const float* __restrict__ h, const float* __restrict__ lw,
    const float* __restrict__ lb, float* __restrict__ out) {
    __shared__ float feat[512];
    int b = blockIdx.x, d = threadIdx.x;
    const float* hb = h + (size_t)b * 256 * DD;
    float s = 0.f;
    for (int i = 0; i < 256; ++i) s += hb[(size_t)i * DD + d];
    float mean = s / 256.0f;
    float s2 = 0.f;
    for (int i = 0; i < 256; ++i) {
        float diff = hb[(size_t)i * DD + d] - mean;
        s2 += diff * diff;
    }
    feat[d] = mean;
    feat[256 + d] = sqrtf(s2 / 255.0f) + 1e-6f;
    __syncthreads();
    if (d < 128) {
        float acc = lb[d];
        for (int k = 0; k < 512; ++k) acc += feat[k] * lw[k * 128 + d];
        out[b * 128 + d] = acc;
    }
}

extern "C" void kernel_launch(void* const* d_in, const int* in_sizes, int n_in,
                              void* d_out, int out_size, void* d_ws, size_t ws_size,
                              hipStream_t stream) {
    (void)in_sizes; (void)n_in; (void)out_size; (void)ws_size;
    const float* x     = (const float*)d_in[0];
    const float* adj   = (const float*)d_in[1];
    const float* pos   = (const float*)d_in[2];
    const float* in_w  = (const float*)d_in[3];
    const float* in_b  = (const float*)d_in[4];
    const float* pw1   = (const float*)d_in[5];
    const float* pb1   = (const float*)d_in[6];
    const float* pw2   = (const float*)d_in[7];
    const float* pb2   = (const float*)d_in[8];
    const float* bg    = (const float*)d_in[9];
    const float* bb    = (const float*)d_in[10];
    const float* bw1   = (const float*)d_in[11];
    const float* bb1   = (const float*)d_in[12];
    const float* bw2   = (const float*)d_in[13];
    const float* bb2   = (const float*)d_in[14];
    const float* beps  = (const float*)d_in[15];
    const float* poolp = (const float*)d_in[16];
    const float* lw    = (const float*)d_in[17];
    const float* lb    = (const float*)d_in[18];
    float* out = (float*)d_out;

    char* wp = (char*)d_ws;
    auto alloc = [&](size_t bytes) -> void* {
        void* p = (void*)wp;
        wp += (bytes + 255) & ~(size_t)255;
        return p;
    };
    const size_t HBYTES = (size_t)BSZ * NTOT * DD * sizeof(float);  // 8.39 MB
    float*  h    = (float*)alloc(HBYTES);
    float*  bufC = (float*)alloc(HBYTES);          // gather target
    float*  zA   = (float*)alloc(HBYTES);
    float*  zB   = (float*)alloc(HBYTES);
    half_t* tbg  = (half_t*)alloc(HBYTES / 2);     // agg out (f16), big tiers
    half_t* Wt   = (half_t*)alloc((size_t)17 * DD * DD * sizeof(half_t));
    float* pstats  = (float*)alloc(8 * sizeof(float));
    float* pinv    = (float*)alloc(4 * sizeof(float));
    float* scores  = (float*)alloc(BSZ * NTOT * sizeof(float));
    float* gate    = (float*)alloc(BSZ * NTOT * sizeof(float));
    int*   origA   = (int*)alloc(BSZ * NTOT * sizeof(int));
    int*   origB   = (int*)alloc(BSZ * NTOT * sizeof(int));
    int*   idxl    = (int*)alloc(BSZ * NTOT * sizeof(int));
    int*   inv     = (int*)alloc(BSZ * NTOT * sizeof(int));
    int*   ldeg0   = (int*)alloc(NTOT * sizeof(int));
    int*   lcol0   = (int*)alloc((size_t)NTOT * 64 * sizeof(int));

    // ---- init: 2 dispatches ----
    setup_kernel<<<SB_MAPS, 256, 0, stream>>>(bw1, bw2, pw2, Wt, pos, pstats, poolp, pinv,
                                              adj, ldeg0, lcol0, origA, inv);
    pe_h_kernel<<<NTOT / 16, 256, 0, stream>>>(pos, pstats, pw1, pb1,
                                               Wt + (size_t)16 * DD * DD, pb2,
                                               x, in_w, in_b, h, zA);

    float* hcur = h;
    float* halt = bufC;
    float* zin = zA;
    float* zout = zB;
    int* orig = origA;
    int* orign = origB;
    int n = NTOT;
    int blk = 0;
    for (int dep = 0; dep < 4; ++dep) {
        for (int s = 0; s < 2; ++s) {
            int rows = BSZ * n;
            const half_t* W1 = Wt + (size_t)blk * DD * DD;
            const half_t* W2 = Wt + (size_t)(8 + blk) * DD * DD;
            const float* B1 = bb1 + blk * DD;
            const float* B2 = bb2 + blk * DD;
            const float* G  = bg + blk * DD;
            const float* BB = bb + blk * DD;
            int sc = (s == 1 && dep < 3) ? 1 : 0;
            if (dep < 2) {
                // split: high-occupancy gather, then MFMA MLP
                agg_kernel<<<rows / 4, 256, 0, stream>>>(
                    zin, tbg, G, BB, beps, blk, ldeg0, lcol0, orig, inv, n, dep);
                if (sc) mlp_kernel<1><<<rows / 16, 256, 0, stream>>>(
                    hcur, tbg, zout, W1, W2, B1, B2, poolp, pinv, scores, dep, n);
                else    mlp_kernel<0><<<rows / 16, 256, 0, stream>>>(
                    hcur, tbg, zout, W1, W2, B1, B2, nullptr, nullptr, nullptr, 0, n);
            } else {
                if (sc) layer_kernel<1><<<rows / 16, 256, 0, stream>>>(
                    hcur, zin, zout, W1, W2, B1, B2, G, BB, beps, blk,
                    ldeg0, lcol0, orig, inv, poolp, pinv, scores, dep, n, dep);
                else    layer_kernel<0><<<rows / 16, 256, 0, stream>>>(
                    hcur, zin, zout, W1, W2, B1, B2, G, BB, beps, blk,
                    ldeg0, lcol0, orig, inv, nullptr, nullptr, nullptr, 0, n, dep);
            }
            { float* t = zin; zin = zout; zout = t; }
            ++blk;
        }
        if (dep < 3) {
            int k = n / 2;
            topk_kernel<<<BSZ, 256, 0, stream>>>(scores, orig, orign, idxl, gate, n, k);
            { int* t = orig; orig = orign; orign = t; }
            gather_kernel<<<BSZ * k, 64, 0, stream>>>(hcur, idxl, gate, orig, halt, zin, inv,
                                                      n, k, dep + 1);
            { float* t = hcur; hcur = halt; halt = t; }
            n = k;
        }
    }
    // ---- readout + final ----
    readout_final_kernel<<<BSZ, 256, 0, stream>>>(hcur, lw, lb, out);
}

// Round 11
// 276.051 us; speedup vs baseline: 1.1885x; 1.0633x over previous
//
#include <hip/hip_runtime.h>
#include <hip/hip_bf16.h>

#define NTOT 2048
#define DD 256
#define BSZ 4

typedef _Float16 half_t;
typedef __attribute__((ext_vector_type(8))) _Float16 halfx8;
typedef __attribute__((ext_vector_type(4))) _Float16 halfx4;
typedef __attribute__((ext_vector_type(4))) float f32x4;

// ---------------- block reduce (256 threads) ----------------
__device__ __forceinline__ float blockReduceSum256(float v) {
    __shared__ float red[4];
    for (int off = 32; off > 0; off >>= 1) v += __shfl_down(v, off);
    int lane = threadIdx.x & 63, w = threadIdx.x >> 6;
    __syncthreads();
    if (lane == 0) red[w] = v;
    __syncthreads();
    return red[0] + red[1] + red[2] + red[3];
}

// ---------------- mega setup: wprep | stats | adj->lcol0 | maps ----------------
#define SB_WPREP 4352
#define SB_STAT  4356
#define SB_A2L   4868
#define SB_MAPS  4900
__global__ void __launch_bounds__(256) setup_kernel(
    const float* __restrict__ bw1, const float* __restrict__ bw2,
    const float* __restrict__ pw2, half_t* __restrict__ Wt,
    const float* __restrict__ pos, float* __restrict__ pstats,
    const float* __restrict__ poolp, float* __restrict__ pinv,
    const float* __restrict__ adj, int* __restrict__ ldeg0, int* __restrict__ lcol0,
    int* __restrict__ orig, int* __restrict__ inv) {
    int bid = blockIdx.x, tid = threadIdx.x;
    if (bid < SB_WPREP) {
        int m = bid >> 8, rem = bid & 255;
        int nb = (rem >> 4) * 16, kb = (rem & 15) * 16;
        const float* W = (m < 8) ? (bw1 + (size_t)m * DD * DD)
                      : (m < 16) ? (bw2 + (size_t)(m - 8) * DD * DD)
                                 : pw2;
        __shared__ float s[16][17];
        int i = tid >> 4, j = tid & 15;
        s[i][j] = W[(size_t)(kb + i) * DD + nb + j];
        __syncthreads();
        Wt[(size_t)m * DD * DD + (size_t)(nb + i) * DD + kb + j] = (half_t)s[j][i];
    } else if (bid < SB_STAT) {
        int which = bid - SB_WPREP;
        if (which == 0) {
            float s[3] = {0.f, 0.f, 0.f};
            for (int i = tid; i < NTOT; i += 256)
                for (int c = 0; c < 3; ++c) s[c] += pos[i * 3 + c];
            float m[3];
            for (int c = 0; c < 3; ++c) m[c] = blockReduceSum256(s[c]) / (float)NTOT;
            float q[3] = {0.f, 0.f, 0.f};
            for (int i = tid; i < NTOT; i += 256)
                for (int c = 0; c < 3; ++c) { float d = pos[i * 3 + c] - m[c]; q[c] += d * d; }
            for (int c = 0; c < 3; ++c) {
                float t = blockReduceSum256(q[c]);
                if (tid == 0) {
                    float var = ((float)BSZ * t) / ((float)BSZ * NTOT - 1.0f);
                    pstats[c] = m[c];
                    pstats[3 + c] = 1.0f / (sqrtf(var) + 1e-8f);
                }
            }
        } else {
            int dep = which - 1;
            float v = poolp[dep * DD + tid];
            float ss = blockReduceSum256(v * v);
            if (tid == 0) pinv[dep] = rsqrtf(ss);
        }
    } else if (bid < SB_A2L) {
        int row = (bid - SB_STAT) * 4 + (tid >> 6);
        int lane = tid & 63;
        int run = 0;
        for (int j0 = 0; j0 < NTOT; j0 += 64) {
            int j = j0 + lane;
            bool pred = adj[(size_t)row * NTOT + j] != 0.f;
            unsigned long long mask = __ballot(pred);
            if (pred) {
                int pos2 = run + __popcll(mask & ((1ull << lane) - 1ull));
                if (pos2 < 64) lcol0[row * 64 + pos2] = j;
            }
            run += __popcll(mask);
        }
        if (lane == 0) ldeg0[row] = run < 64 ? run : 64;
    } else {
        int t = (bid - SB_A2L) * 256 + tid;  // B*NTOT
        int i = t & (NTOT - 1);
        orig[t] = i; inv[t] = i;  // tag 0
    }
}

// ---------------- fused pe + input projection + h/z init ----------------
__global__ void __launch_bounds__(256) pe_h_kernel(
    const float* __restrict__ pos, const float* __restrict__ pstats,
    const float* __restrict__ pw1, const float* __restrict__ pb1,
    const half_t* __restrict__ Wt16, const float* __restrict__ pb2,
    const float* __restrict__ x, const float* __restrict__ in_w,
    const float* __restrict__ in_b, float* __restrict__ h, float* __restrict__ z) {
    __shared__ half_t tb[16][264];
    __shared__ float iw[16][DD];
    __shared__ float xs[16][16];
    __shared__ float part[4][16][2];
    __shared__ float mrs[16][2];
    int tid = threadIdx.x;
    int i0 = blockIdx.x * 16;
    {
        int rl = tid >> 4, cb = (tid & 15) * 16;
        float pn[3];
#pragma unroll
        for (int c = 0; c < 3; ++c)
            pn[c] = (pos[(i0 + rl) * 3 + c] - pstats[c]) * pstats[3 + c];
#pragma unroll
        for (int u = 0; u < 16; ++u) {
            int d = cb + u;
            float a = pb1[d];
            a += pn[0] * pw1[d];
            a += pn[1] * pw1[DD + d];
            a += pn[2] * pw1[2 * DD + d];
            a = a / (1.0f + expf(-a));
            tb[rl][d] = (half_t)a;
        }
        int k = tid >> 4;
#pragma unroll
        for (int u = 0; u < 16; ++u) iw[k][cb + u] = in_w[k * DD + cb + u];
    }
    __syncthreads();
    int w = tid >> 6, l = tid & 63;
    int lo = l & 15, hi = l >> 4;
    int kb = hi * 8;
    float pe_r[4][4];
    {
        f32x4 acc[4] = {};
#pragma unroll
        for (int k0 = 0; k0 < DD; k0 += 32) {
            halfx8 a0 = *(const halfx8*)&tb[lo][kb + k0];
#pragma unroll
            for (int j = 0; j < 4; ++j) {
                halfx8 bj = *(const halfx8*)(Wt16 + (size_t)(w * 64 + j * 16 + lo) * DD + kb + k0);
                acc[j] = __builtin_amdgcn_mfma_f32_16x16x32_f16(a0, bj, acc[j], 0, 0, 0);
            }
        }
#pragma unroll
        for (int j = 0; j < 4; ++j) {
            float bs = pb2[w * 64 + j * 16 + lo];
#pragma unroll
            for (int q = 0; q < 4; ++q) pe_r[j][q] = acc[j][q] + bs;
        }
    }
    float xb[4];
#pragma unroll
    for (int j = 0; j < 4; ++j) xb[j] = in_b[w * 64 + j * 16 + lo];
    for (int b = 0; b < BSZ; ++b) {
        __syncthreads();
        xs[tid >> 4][tid & 15] = x[(size_t)(b * NTOT + i0 + (tid >> 4)) * 16 + (tid & 15)];
        __syncthreads();
        float vh[4][4];
#pragma unroll
        for (int q = 0; q < 4; ++q) {
            int rl = hi * 4 + q;
            float s = 0.f, ss = 0.f;
#pragma unroll
            for (int j = 0; j < 4; ++j) {
                int c = w * 64 + j * 16 + lo;
                float acc = xb[j];
#pragma unroll
                for (int k = 0; k < 16; ++k) acc += xs[rl][k] * iw[k][c];
                float v = acc + pe_r[j][q];
                vh[j][q] = v;
                s += v; ss += v * v;
            }
#pragma unroll
            for (int m = 1; m < 16; m <<= 1) { s += __shfl_xor(s, m); ss += __shfl_xor(ss, m); }
            if (lo == 0) { part[w][rl][0] = s; part[w][rl][1] = ss; }
        }
        __syncthreads();
        if (tid < 16) {
            float s = 0.f, ss = 0.f;
#pragma unroll
            for (int w2 = 0; w2 < 4; ++w2) { s += part[w2][tid][0]; ss += part[w2][tid][1]; }
            float mean = s * (1.0f / DD);
            float var = ss * (1.0f / DD) - mean * mean;
            mrs[tid][0] = mean;
            mrs[tid][1] = rsqrtf(var + 1e-5f);
        }
        __syncthreads();
#pragma unroll
        for (int q = 0; q < 4; ++q) {
            int rl = hi * 4 + q;
            size_t r = (size_t)(b * NTOT + i0 + rl);
            float mean = mrs[rl][0], rs = mrs[rl][1];
#pragma unroll
            for (int j = 0; j < 4; ++j) {
                int c = w * 64 + j * 16 + lo;
                float v = vh[j][q];
                h[r * DD + c] = v;
                z[r * DD + c] = (v - mean) * rs;
            }
        }
    }
}

// ---------------- fused layer, 16 rows/block, XCD-swizzled ----------------
// blockIdx remap: xcd = bid&7 owns batch (xcd>>1); all gather reads then hit the
// 2.1MB per-batch z-slice resident in that XCD's 4MB L2.
template <int SCORE>
__global__ void __launch_bounds__(256) layer_kernel(
    float* __restrict__ h, const float* __restrict__ zin, float* __restrict__ zout,
    const half_t* __restrict__ Wt1, const half_t* __restrict__ Wt2,
    const float* __restrict__ b1v, const float* __restrict__ b2v,
    const float* __restrict__ gv, const float* __restrict__ bbv,
    const float* __restrict__ beps, int blk,
    const int* __restrict__ ldeg0, const int* __restrict__ lcol0,
    const int* __restrict__ orig, const int* __restrict__ inv,
    const float* __restrict__ poolp, const float* __restrict__ pinv_all,
    float* __restrict__ scores, int dep, int n, int tag) {
    __shared__ half_t tb[16][264];
    __shared__ half_t ub[16][264];
    __shared__ float part[4][16][3];
    __shared__ float mrs[16][2];
    int tid = threadIdx.x;
    // XCD-aware swizzle (gridDim.x divisible by 8; BSZ=4, 8 XCDs -> 2 XCDs/batch)
    int bid = blockIdx.x;
    int xcd = bid & 7;
    int batch = xcd >> 1;
    int within = ((bid >> 3) << 1) | (xcd & 1);
    int rowBase = batch * n + within * 16;
    float eps1 = 1.0f + beps[blk];

    // ---- phase A: aggregation -> LDS tb (f16) ----
    {
        int rl = tid >> 4, cg = tid & 15;
        int r = rowBase + rl;
        int b = r / n, i = r - b * n;
        const f32x4* zb = (const f32x4*)zin + (size_t)b * n * 64;
        f32x4 acc[4];
#pragma unroll
        for (int u = 0; u < 4; ++u) acc[u] = zb[(size_t)i * 64 + cg + 16 * u] * eps1;
        int cnt = 0;
        if (tag == 0) {
            int deg = ldeg0[i];
            const int* lc = lcol0 + i * 64;
            int p = 0;
            for (; p + 4 <= deg; p += 4) {
                int j0 = lc[p], j1 = lc[p + 1], j2 = lc[p + 2], j3 = lc[p + 3];
#pragma unroll
                for (int u = 0; u < 4; ++u) {
                    f32x4 v0 = zb[(size_t)j0 * 64 + cg + 16 * u];
                    f32x4 v1 = zb[(size_t)j1 * 64 + cg + 16 * u];
                    f32x4 v2 = zb[(size_t)j2 * 64 + cg + 16 * u];
                    f32x4 v3 = zb[(size_t)j3 * 64 + cg + 16 * u];
                    acc[u] += (v0 + v1) + (v2 + v3);
                }
            }
            for (; p < deg; ++p) {
                int j = lc[p];
#pragma unroll
                for (int u = 0; u < 4; ++u) acc[u] += zb[(size_t)j * 64 + cg + 16 * u];
            }
            cnt = deg;
        } else {
            int o = orig[b * NTOT + i];
            int deg = ldeg0[o];
            const int* lc = lcol0 + o * 64;
            const int* invb = inv + b * NTOT;
            int p = 0;
            for (; p + 4 <= deg; p += 4) {
                int v0 = invb[lc[p]], v1 = invb[lc[p + 1]];
                int v2 = invb[lc[p + 2]], v3 = invb[lc[p + 3]];
                if ((v0 >> 12) == tag) {
                    int j = v0 & 4095; ++cnt;
#pragma unroll
                    for (int u = 0; u < 4; ++u) acc[u] += zb[(size_t)j * 64 + cg + 16 * u];
                }
                if ((v1 >> 12) == tag) {
                    int j = v1 & 4095; ++cnt;
#pragma unroll
                    for (int u = 0; u < 4; ++u) acc[u] += zb[(size_t)j * 64 + cg + 16 * u];
                }
                if ((v2 >> 12) == tag) {
                    int j = v2 & 4095; ++cnt;
#pragma unroll
                    for (int u = 0; u < 4; ++u) acc[u] += zb[(size_t)j * 64 + cg + 16 * u];
                }
                if ((v3 >> 12) == tag) {
                    int j = v3 & 4095; ++cnt;
#pragma unroll
                    for (int u = 0; u < 4; ++u) acc[u] += zb[(size_t)j * 64 + cg + 16 * u];
                }
            }
            for (; p < deg; ++p) {
                int v = invb[lc[p]];
                if ((v >> 12) == tag) {
                    int j = v & 4095; ++cnt;
#pragma unroll
                    for (int u = 0; u < 4; ++u) acc[u] += zb[(size_t)j * 64 + cg + 16 * u];
                }
            }
        }
        float coefb = eps1 + (float)cnt;
#pragma unroll
        for (int u = 0; u < 4; ++u) {
            int c4 = cg + 16 * u;
            f32x4 gvv = ((const f32x4*)gv)[c4];
            f32x4 bvv = ((const f32x4*)bbv)[c4];
            f32x4 tv = gvv * acc[u] + bvv * coefb;
            halfx4 th;
#pragma unroll
            for (int e = 0; e < 4; ++e) th[e] = (half_t)tv[e];
            *(halfx4*)&tb[rl][c4 * 4] = th;
        }
    }
    __syncthreads();

    int w = tid >> 6, l = tid & 63;
    int lo = l & 15, hi = l >> 4;
    int kb = hi * 8;

    // ---- phase B: mm1 + silu -> ub ----
    {
        f32x4 acc[4] = {};
#pragma unroll
        for (int k0 = 0; k0 < DD; k0 += 32) {
            halfx8 a0 = *(const halfx8*)&tb[lo][kb + k0];
#pragma unroll
            for (int j = 0; j < 4; ++j) {
                halfx8 bj = *(const halfx8*)(Wt1 + (size_t)(w * 64 + j * 16 + lo) * DD + kb + k0);
                acc[j] = __builtin_amdgcn_mfma_f32_16x16x32_f16(a0, bj, acc[j], 0, 0, 0);
            }
        }
        float bs[4];
#pragma unroll
        for (int j = 0; j < 4; ++j) bs[j] = b1v[w * 64 + j * 16 + lo];
#pragma unroll
        for (int q = 0; q < 4; ++q)
#pragma unroll
            for (int j = 0; j < 4; ++j) {
                float v = acc[j][q] + bs[j];
                v = v / (1.0f + expf(-v));
                ub[hi * 4 + q][w * 64 + j * 16 + lo] = (half_t)v;
            }
    }
    __syncthreads();

    // ---- phase C: mm2 + residual + stats (+score) + z ----
    {
        f32x4 acc[4] = {};
#pragma unroll
        for (int k0 = 0; k0 < DD; k0 += 32) {
            halfx8 a0 = *(const halfx8*)&ub[lo][kb + k0];
#pragma unroll
            for (int j = 0; j < 4; ++j) {
                halfx8 bj = *(const halfx8*)(Wt2 + (size_t)(w * 64 + j * 16 + lo) * DD + kb + k0);
                acc[j] = __builtin_amdgcn_mfma_f32_16x16x32_f16(a0, bj, acc[j], 0, 0, 0);
            }
        }
        float bs[4], pv[4] = {};
#pragma unroll
        for (int j = 0; j < 4; ++j) bs[j] = b2v[w * 64 + j * 16 + lo];
        if (SCORE) {
#pragma unroll
            for (int j = 0; j < 4; ++j) pv[j] = poolp[dep * DD + w * 64 + j * 16 + lo];
        }
        float vh[4][4];
#pragma unroll
        for (int q = 0; q < 4; ++q) {
            int r = rowBase + hi * 4 + q;
            float s = 0.f, ss = 0.f, sp = 0.f;
#pragma unroll
            for (int j = 0; j < 4; ++j) {
                int c = w * 64 + j * 16 + lo;
                float v = h[(size_t)r * DD + c] + acc[j][q] + bs[j];
                vh[j][q] = v;
                s += v; ss += v * v;
                if (SCORE) sp += v * pv[j];
            }
#pragma unroll
            for (int m = 1; m < 16; m <<= 1) {
                s += __shfl_xor(s, m); ss += __shfl_xor(ss, m);
                if (SCORE) sp += __shfl_xor(sp, m);
            }
            if (lo == 0) {
                int rl = hi * 4 + q;
                part[w][rl][0] = s; part[w][rl][1] = ss;
                if (SCORE) part[w][rl][2] = sp;
            }
        }
        __syncthreads();
        if (tid < 16) {
            float s = 0.f, ss = 0.f, sp = 0.f;
#pragma unroll
            for (int w2 = 0; w2 < 4; ++w2) {
                s += part[w2][tid][0]; ss += part[w2][tid][1];
                if (SCORE) sp += part[w2][tid][2];
            }
            float mean = s * (1.0f / DD);
            float var = ss * (1.0f / DD) - mean * mean;
            mrs[tid][0] = mean;
            mrs[tid][1] = rsqrtf(var + 1e-5f);
            if (SCORE) {
                int r = rowBase + tid;
                int b2 = r / n, ii = r - b2 * n;
                scores[b2 * NTOT + ii] = sp * pinv_all[dep];
            }
        }
        __syncthreads();
#pragma unroll
        for (int q = 0; q < 4; ++q) {
            int rl = hi * 4 + q;
            int r = rowBase + rl;
            float mean = mrs[rl][0], rs = mrs[rl][1];
#pragma unroll
            for (int j = 0; j < 4; ++j) {
                int c = w * 64 + j * 16 + lo;
                float v = vh[j][q];
                h[(size_t)r * DD + c] = v;
                zout[(size_t)r * DD + c] = (v - mean) * rs;
            }
        }
    }
}

// ---------------- pooling: 1-pass radix + candidate rank (fallback: full radix) ----------------
__global__ void topk_kernel(const float* __restrict__ scores, const int* __restrict__ orig_cur,
                            int* __restrict__ orig_next, int* __restrict__ idx_local,
                            float* __restrict__ gate, int n, int k) {
    __shared__ unsigned keys[2048];
    __shared__ int hist[256];
    __shared__ int sg[256], se[256];
    __shared__ int sh_bucket, sh_r, sh_cnt;
    __shared__ unsigned cand[256];
    __shared__ unsigned sh_thr;
    int b = blockIdx.x;
    const float* sc = scores + b * NTOT;
    int tid = threadIdx.x;
    for (int i = tid; i < n; i += 256) {
        unsigned u = __float_as_uint(sc[i]);
        keys[i] = (u & 0x80000000u) ? ~u : (u | 0x80000000u);
    }
    hist[tid] = 0;
    if (tid == 0) sh_cnt = 0;
    __syncthreads();
    for (int i = tid; i < n; i += 256) atomicAdd(&hist[keys[i] >> 24], 1);
    __syncthreads();
    int cnt = hist[tid];
    sg[tid] = cnt;
    __syncthreads();
    for (int off = 1; off < 256; off <<= 1) {
        int v = (tid >= off) ? sg[tid - off] : 0;
        __syncthreads();
        sg[tid] += v;
        __syncthreads();
    }
    int r = n - k;  // 0-indexed rank ascending
    int incl = sg[tid], excl = incl - cnt;
    if (excl <= r && r < incl) { sh_bucket = tid; sh_r = r - excl; }
    __syncthreads();
    int b1 = sh_bucket, r1 = sh_r;
    int c = hist[b1];
    unsigned thrkey;
    if (c <= 256) {
        for (int i = tid; i < n; i += 256) {
            unsigned key = keys[i];
            if ((key >> 24) == (unsigned)b1) {
                int pos = atomicAdd(&sh_cnt, 1);
                cand[pos] = key;
            }
        }
        __syncthreads();
        if (tid < c) {
            unsigned mine = cand[tid];
            int less = 0, eq = 0;
            for (int j = 0; j < c; ++j) {
                unsigned oth = cand[j];
                less += (oth < mine); eq += (oth == mine);
            }
            if (less <= r1 && r1 < less + eq) sh_thr = mine;
        }
        __syncthreads();
        thrkey = sh_thr;
    } else {
        unsigned prefix = ((unsigned)b1) << 24;
        int rr = r1;
        for (int shift = 16; shift >= 0; shift -= 8) {
            __syncthreads();
            hist[tid] = 0;
            __syncthreads();
            unsigned mask = 0xFFFFFFFFu << (shift + 8);
            for (int i = tid; i < n; i += 256) {
                unsigned key = keys[i];
                if ((key & mask) == (prefix & mask)) atomicAdd(&hist[(key >> shift) & 255], 1);
            }
            __syncthreads();
            int cnt2 = hist[tid];
            sg[tid] = cnt2;
            __syncthreads();
            for (int off = 1; off < 256; off <<= 1) {
                int v = (tid >= off) ? sg[tid - off] : 0;
                __syncthreads();
                sg[tid] += v;
                __syncthreads();
            }
            int incl2 = sg[tid], excl2 = incl2 - cnt2;
            if (excl2 <= rr && rr < incl2) { sh_bucket = tid; sh_r = rr - excl2; }
            __syncthreads();
            prefix |= ((unsigned)sh_bucket) << shift;
            rr = sh_r;
            __syncthreads();
        }
        thrkey = prefix;
    }
    unsigned uthr = (thrkey & 0x80000000u) ? (thrkey ^ 0x80000000u) : ~thrkey;
    float thr = __uint_as_float(uthr);  // exact k-th largest value
    int chunk = n / 256;
    int base = tid * chunk;
    int cgt = 0, ceq = 0;
    for (int u = 0; u < chunk; ++u) {
        float s = sc[base + u];
        cgt += (s > thr); ceq += (s == thr);
    }
    sg[tid] = cgt; se[tid] = ceq; __syncthreads();
    for (int off = 1; off < 256; off <<= 1) {
        int vg = (tid >= off) ? sg[tid - off] : 0;
        int ve = (tid >= off) ? se[tid - off] : 0;
        __syncthreads();
        sg[tid] += vg; se[tid] += ve;
        __syncthreads();
    }
    int total_gt = sg[255];
    int ties = k - total_gt;
    int gtb = sg[tid] - cgt, eqb = se[tid] - ceq;
    for (int u = 0; u < chunk; ++u) {
        int i = base + u;
        float s = sc[i];
        bool isgt = (s > thr), iseq = (s == thr);
        bool keep = isgt || (iseq && eqb < ties);
        if (keep) {
            int pos = gtb + (eqb < ties ? eqb : ties);
            idx_local[b * NTOT + pos] = i;
            gate[b * NTOT + pos] = tanhf(s);
            orig_next[b * NTOT + pos] = orig_cur[b * NTOT + i];
        }
        gtb += isgt; eqb += iseq;
    }
}

// gather gated rows, recompute stats, write z, and set inverse map (XCD-swizzled)
__global__ void __launch_bounds__(64) gather_kernel(
    const float* __restrict__ h, const int* __restrict__ idx_local,
    const float* __restrict__ gate, const int* __restrict__ orig_new,
    float* __restrict__ hout, float* __restrict__ zout, int* __restrict__ inv,
    int n_old, int k, int tag) {
    // blockIdx remap: xcd pair owns one batch (gridDim = B*k divisible by 8)
    int bid = blockIdx.x;
    int xcd = bid & 7;
    int b = xcd >> 1;
    int rr = ((bid >> 3) << 1) | (xcd & 1);  // [0, k)
    int r = b * k + rr;
    int lane = threadIdx.x;
    int src = idx_local[b * NTOT + rr];
    float gg = gate[b * NTOT + rr];
    f32x4 v = ((const f32x4*)h)[(size_t)(b * n_old + src) * 64 + lane] * gg;
    ((f32x4*)hout)[(size_t)r * 64 + lane] = v;
    float s = v[0] + v[1] + v[2] + v[3];
    float ss = v[0] * v[0] + v[1] * v[1] + v[2] * v[2] + v[3] * v[3];
#pragma unroll
    for (int m = 1; m < 64; m <<= 1) { s += __shfl_xor(s, m); ss += __shfl_xor(ss, m); }
    float mean = s * (1.0f / DD);
    float rs = rsqrtf(ss * (1.0f / DD) - mean * mean + 1e-5f);
    f32x4 zv = (v - mean) * rs;
    ((f32x4*)zout)[(size_t)r * 64 + lane] = zv;
    if (lane == 0) inv[b * NTOT + orig_new[b * NTOT + rr]] = (tag << 12) | rr;
}

// ---------------- fused readout + final projection (4 blocks) ----------------
__global__ void __launch_bounds__(256) readout_final_kernel(
    const float* __restrict__ h, const float* __restrict__ lw,
    const float* __restrict__ lb, float* __restrict__ out) {
    __shared__ float feat[512];
    int b = blockIdx.x, d = threadIdx.x;
    const float* hb = h + (size_t)b * 256 * DD;
    float s = 0.f;
    for (int i = 0; i < 256; ++i) s += hb[(size_t)i * DD + d];
    float mean = s / 256.0f;
    float s2 = 0.f;
    for (int i = 0; i < 256; ++i) {
        float diff = hb[(size_t)i * DD + d] - mean;
        s2 += diff * diff;
    }
    feat[d] = mean;
    feat[256 + d] = sqrtf(s2 / 255.0f) + 1e-6f;
    __syncthreads();
    if (d < 128) {
        float acc = lb[d];
        for (int k = 0; k < 512; ++k) acc += feat[k] * lw[k * 128 + d];
        out[b * 128 + d] = acc;
    }
}

extern "C" void kernel_launch(void* const* d_in, const int* in_sizes, int n_in,
                              void* d_out, int out_size, void* d_ws, size_t ws_size,
                              hipStream_t stream) {
    (void)in_sizes; (void)n_in; (void)out_size; (void)ws_size;
    const float* x     = (const float*)d_in[0];
    const float* adj   = (const float*)d_in[1];
    const float* pos   = (const float*)d_in[2];
    const float* in_w  = (const float*)d_in[3];
    const float* in_b  = (const float*)d_in[4];
    const float* pw1   = (const float*)d_in[5];
    const float* pb1   = (const float*)d_in[6];
    const float* pw2   = (const float*)d_in[7];
    const float* pb2   = (const float*)d_in[8];
    const float* bg    = (const float*)d_in[9];
    const float* bb    = (const float*)d_in[10];
    const float* bw1   = (const float*)d_in[11];
    const float* bb1   = (const float*)d_in[12];
    const float* bw2   = (const float*)d_in[13];
    const float* bb2   = (const float*)d_in[14];
    const float* beps  = (const float*)d_in[15];
    const float* poolp = (const float*)d_in[16];
    const float* lw    = (const float*)d_in[17];
    const float* lb    = (const float*)d_in[18];
    float* out = (float*)d_out;

    char* wp = (char*)d_ws;
    auto alloc = [&](size_t bytes) -> void* {
        void* p = (void*)wp;
        wp += (bytes + 255) & ~(size_t)255;
        return p;
    };
    const size_t HBYTES = (size_t)BSZ * NTOT * DD * sizeof(float);  // 8.39 MB
    float*  h    = (float*)alloc(HBYTES);
    float*  bufC = (float*)alloc(HBYTES);          // gather target
    float*  zA   = (float*)alloc(HBYTES);
    float*  zB   = (float*)alloc(HBYTES);
    half_t* Wt   = (half_t*)alloc((size_t)17 * DD * DD * sizeof(half_t));
    float* pstats  = (float*)alloc(8 * sizeof(float));
    float* pinv    = (float*)alloc(4 * sizeof(float));
    float* scores  = (float*)alloc(BSZ * NTOT * sizeof(float));
    float* gate    = (float*)alloc(BSZ * NTOT * sizeof(float));
    int*   origA   = (int*)alloc(BSZ * NTOT * sizeof(int));
    int*   origB   = (int*)alloc(BSZ * NTOT * sizeof(int));
    int*   idxl    = (int*)alloc(BSZ * NTOT * sizeof(int));
    int*   inv     = (int*)alloc(BSZ * NTOT * sizeof(int));
    int*   ldeg0   = (int*)alloc(NTOT * sizeof(int));
    int*   lcol0   = (int*)alloc((size_t)NTOT * 64 * sizeof(int));

    // ---- init: 2 dispatches ----
    setup_kernel<<<SB_MAPS, 256, 0, stream>>>(bw1, bw2, pw2, Wt, pos, pstats, poolp, pinv,
                                              adj, ldeg0, lcol0, origA, inv);
    pe_h_kernel<<<NTOT / 16, 256, 0, stream>>>(pos, pstats, pw1, pb1,
                                               Wt + (size_t)16 * DD * DD, pb2,
                                               x, in_w, in_b, h, zA);

    float* hcur = h;
    float* halt = bufC;
    float* zin = zA;
    float* zout = zB;
    int* orig = origA;
    int* orign = origB;
    int n = NTOT;
    int blk = 0;
    for (int dep = 0; dep < 4; ++dep) {
        for (int s = 0; s < 2; ++s) {
            int rows = BSZ * n;
            const half_t* W1 = Wt + (size_t)blk * DD * DD;
            const half_t* W2 = Wt + (size_t)(8 + blk) * DD * DD;
            const float* B1 = bb1 + blk * DD;
            const float* B2 = bb2 + blk * DD;
            const float* G  = bg + blk * DD;
            const float* BB = bb + blk * DD;
            int sc = (s == 1 && dep < 3) ? 1 : 0;
            if (sc) layer_kernel<1><<<rows / 16, 256, 0, stream>>>(
                hcur, zin, zout, W1, W2, B1, B2, G, BB, beps, blk,
                ldeg0, lcol0, orig, inv, poolp, pinv, scores, dep, n, dep);
            else    layer_kernel<0><<<rows / 16, 256, 0, stream>>>(
                hcur, zin, zout, W1, W2, B1, B2, G, BB, beps, blk,
                ldeg0, lcol0, orig, inv, nullptr, nullptr, nullptr, 0, n, dep);
            { float* t = zin; zin = zout; zout = t; }
            ++blk;
        }
        if (dep < 3) {
            int k = n / 2;
            topk_kernel<<<BSZ, 256, 0, stream>>>(scores, orig, orign, idxl, gate, n, k);
            { int* t = orig; orig = orign; orign = t; }
            gather_kernel<<<BSZ * k, 64, 0, stream>>>(hcur, idxl, gate, orig, halt, zin, inv,
                                                      n, k, dep + 1);
            { float* t = hcur; hcur = halt; halt = t; }
            n = k;
        }
    }
    // ---- readout + final ----
    readout_final_kernel<<<BSZ, 256, 0, stream>>>(hcur, lw, lb, out);
}

// Round 12
// 272.100 us; speedup vs baseline: 1.2057x; 1.0145x over previous
//
#include <hip/hip_runtime.h>
#include <hip/hip_bf16.h>

#define NTOT 2048
#define DD 256
#define BSZ 4

typedef _Float16 half_t;
typedef __attribute__((ext_vector_type(8))) _Float16 halfx8;
typedef __attribute__((ext_vector_type(4))) _Float16 halfx4;
typedef __attribute__((ext_vector_type(4))) float f32x4;

__device__ __forceinline__ f32x4 h2f(halfx4 v) {
    f32x4 r;
#pragma unroll
    for (int e = 0; e < 4; ++e) r[e] = (float)v[e];
    return r;
}
__device__ __forceinline__ halfx4 f2h(f32x4 v) {
    halfx4 r;
#pragma unroll
    for (int e = 0; e < 4; ++e) r[e] = (half_t)v[e];
    return r;
}

// ---------------- block reduce (256 threads) ----------------
__device__ __forceinline__ float blockReduceSum256(float v) {
    __shared__ float red[4];
    for (int off = 32; off > 0; off >>= 1) v += __shfl_down(v, off);
    int lane = threadIdx.x & 63, w = threadIdx.x >> 6;
    __syncthreads();
    if (lane == 0) red[w] = v;
    __syncthreads();
    return red[0] + red[1] + red[2] + red[3];
}

// ---------------- mega setup: wprep | stats | adj->lcol0 | maps ----------------
#define SB_WPREP 4352
#define SB_STAT  4356
#define SB_A2L   4868
#define SB_MAPS  4900
__global__ void __launch_bounds__(256) setup_kernel(
    const float* __restrict__ bw1, const float* __restrict__ bw2,
    const float* __restrict__ pw2, half_t* __restrict__ Wt,
    const float* __restrict__ pos, float* __restrict__ pstats,
    const float* __restrict__ poolp, float* __restrict__ pinv,
    const float* __restrict__ adj, int* __restrict__ ldeg0, int* __restrict__ lcol0,
    int* __restrict__ orig, int* __restrict__ inv) {
    int bid = blockIdx.x, tid = threadIdx.x;
    if (bid < SB_WPREP) {
        int m = bid >> 8, rem = bid & 255;
        int nb = (rem >> 4) * 16, kb = (rem & 15) * 16;
        const float* W = (m < 8) ? (bw1 + (size_t)m * DD * DD)
                      : (m < 16) ? (bw2 + (size_t)(m - 8) * DD * DD)
                                 : pw2;
        __shared__ float s[16][17];
        int i = tid >> 4, j = tid & 15;
        s[i][j] = W[(size_t)(kb + i) * DD + nb + j];
        __syncthreads();
        Wt[(size_t)m * DD * DD + (size_t)(nb + i) * DD + kb + j] = (half_t)s[j][i];
    } else if (bid < SB_STAT) {
        int which = bid - SB_WPREP;
        if (which == 0) {
            float s[3] = {0.f, 0.f, 0.f};
            for (int i = tid; i < NTOT; i += 256)
                for (int c = 0; c < 3; ++c) s[c] += pos[i * 3 + c];
            float m[3];
            for (int c = 0; c < 3; ++c) m[c] = blockReduceSum256(s[c]) / (float)NTOT;
            float q[3] = {0.f, 0.f, 0.f};
            for (int i = tid; i < NTOT; i += 256)
                for (int c = 0; c < 3; ++c) { float d = pos[i * 3 + c] - m[c]; q[c] += d * d; }
            for (int c = 0; c < 3; ++c) {
                float t = blockReduceSum256(q[c]);
                if (tid == 0) {
                    float var = ((float)BSZ * t) / ((float)BSZ * NTOT - 1.0f);
                    pstats[c] = m[c];
                    pstats[3 + c] = 1.0f / (sqrtf(var) + 1e-8f);
                }
            }
        } else {
            int dep = which - 1;
            float v = poolp[dep * DD + tid];
            float ss = blockReduceSum256(v * v);
            if (tid == 0) pinv[dep] = rsqrtf(ss);
        }
    } else if (bid < SB_A2L) {
        int row = (bid - SB_STAT) * 4 + (tid >> 6);
        int lane = tid & 63;
        int run = 0;
        for (int j0 = 0; j0 < NTOT; j0 += 64) {
            int j = j0 + lane;
            bool pred = adj[(size_t)row * NTOT + j] != 0.f;
            unsigned long long mask = __ballot(pred);
            if (pred) {
                int pos2 = run + __popcll(mask & ((1ull << lane) - 1ull));
                if (pos2 < 64) lcol0[row * 64 + pos2] = j;
            }
            run += __popcll(mask);
        }
        if (lane == 0) ldeg0[row] = run < 64 ? run : 64;
    } else {
        int t = (bid - SB_A2L) * 256 + tid;  // B*NTOT
        int i = t & (NTOT - 1);
        orig[t] = i; inv[t] = i;  // tag 0
    }
}

// ---------------- fused pe + input projection + h/z init (z -> f16) ----------------
__global__ void __launch_bounds__(256) pe_h_kernel(
    const float* __restrict__ pos, const float* __restrict__ pstats,
    const float* __restrict__ pw1, const float* __restrict__ pb1,
    const half_t* __restrict__ Wt16, const float* __restrict__ pb2,
    const float* __restrict__ x, const float* __restrict__ in_w,
    const float* __restrict__ in_b, float* __restrict__ h, half_t* __restrict__ z) {
    __shared__ half_t tb[16][264];
    __shared__ float iw[16][DD];
    __shared__ float xs[16][16];
    __shared__ float part[4][16][2];
    __shared__ float mrs[16][2];
    int tid = threadIdx.x;
    int i0 = blockIdx.x * 16;
    {
        int rl = tid >> 4, cb = (tid & 15) * 16;
        float pn[3];
#pragma unroll
        for (int c = 0; c < 3; ++c)
            pn[c] = (pos[(i0 + rl) * 3 + c] - pstats[c]) * pstats[3 + c];
#pragma unroll
        for (int u = 0; u < 16; ++u) {
            int d = cb + u;
            float a = pb1[d];
            a += pn[0] * pw1[d];
            a += pn[1] * pw1[DD + d];
            a += pn[2] * pw1[2 * DD + d];
            a = a / (1.0f + expf(-a));
            tb[rl][d] = (half_t)a;
        }
        int k = tid >> 4;
#pragma unroll
        for (int u = 0; u < 16; ++u) iw[k][cb + u] = in_w[k * DD + cb + u];
    }
    __syncthreads();
    int w = tid >> 6, l = tid & 63;
    int lo = l & 15, hi = l >> 4;
    int kb = hi * 8;
    float pe_r[4][4];
    {
        f32x4 acc[4] = {};
#pragma unroll
        for (int k0 = 0; k0 < DD; k0 += 32) {
            halfx8 a0 = *(const halfx8*)&tb[lo][kb + k0];
#pragma unroll
            for (int j = 0; j < 4; ++j) {
                halfx8 bj = *(const halfx8*)(Wt16 + (size_t)(w * 64 + j * 16 + lo) * DD + kb + k0);
                acc[j] = __builtin_amdgcn_mfma_f32_16x16x32_f16(a0, bj, acc[j], 0, 0, 0);
            }
        }
#pragma unroll
        for (int j = 0; j < 4; ++j) {
            float bs = pb2[w * 64 + j * 16 + lo];
#pragma unroll
            for (int q = 0; q < 4; ++q) pe_r[j][q] = acc[j][q] + bs;
        }
    }
    float xb[4];
#pragma unroll
    for (int j = 0; j < 4; ++j) xb[j] = in_b[w * 64 + j * 16 + lo];
    for (int b = 0; b < BSZ; ++b) {
        __syncthreads();
        xs[tid >> 4][tid & 15] = x[(size_t)(b * NTOT + i0 + (tid >> 4)) * 16 + (tid & 15)];
        __syncthreads();
        float vh[4][4];
#pragma unroll
        for (int q = 0; q < 4; ++q) {
            int rl = hi * 4 + q;
            float s = 0.f, ss = 0.f;
#pragma unroll
            for (int j = 0; j < 4; ++j) {
                int c = w * 64 + j * 16 + lo;
                float acc = xb[j];
#pragma unroll
                for (int k = 0; k < 16; ++k) acc += xs[rl][k] * iw[k][c];
                float v = acc + pe_r[j][q];
                vh[j][q] = v;
                s += v; ss += v * v;
            }
#pragma unroll
            for (int m = 1; m < 16; m <<= 1) { s += __shfl_xor(s, m); ss += __shfl_xor(ss, m); }
            if (lo == 0) { part[w][rl][0] = s; part[w][rl][1] = ss; }
        }
        __syncthreads();
        if (tid < 16) {
            float s = 0.f, ss = 0.f;
#pragma unroll
            for (int w2 = 0; w2 < 4; ++w2) { s += part[w2][tid][0]; ss += part[w2][tid][1]; }
            float mean = s * (1.0f / DD);
            float var = ss * (1.0f / DD) - mean * mean;
            mrs[tid][0] = mean;
            mrs[tid][1] = rsqrtf(var + 1e-5f);
        }
        __syncthreads();
#pragma unroll
        for (int q = 0; q < 4; ++q) {
            int rl = hi * 4 + q;
            size_t r = (size_t)(b * NTOT + i0 + rl);
            float mean = mrs[rl][0], rs = mrs[rl][1];
#pragma unroll
            for (int j = 0; j < 4; ++j) {
                int c = w * 64 + j * 16 + lo;
                float v = vh[j][q];
                h[r * DD + c] = v;
                z[r * DD + c] = (half_t)((v - mean) * rs);
            }
        }
    }
}

// ---------------- fused layer, 16 rows/block, XCD-swizzled, z in f16 ----------------
template <int SCORE>
__global__ void __launch_bounds__(256) layer_kernel(
    float* __restrict__ h, const half_t* __restrict__ zin, half_t* __restrict__ zout,
    const half_t* __restrict__ Wt1, const half_t* __restrict__ Wt2,
    const float* __restrict__ b1v, const float* __restrict__ b2v,
    const float* __restrict__ gv, const float* __restrict__ bbv,
    const float* __restrict__ beps, int blk,
    const int* __restrict__ ldeg0, const int* __restrict__ lcol0,
    const int* __restrict__ orig, const int* __restrict__ inv,
    const float* __restrict__ poolp, const float* __restrict__ pinv_all,
    float* __restrict__ scores, int dep, int n, int tag) {
    __shared__ half_t tb[16][264];
    __shared__ half_t ub[16][264];
    __shared__ float part[4][16][3];
    __shared__ float mrs[16][2];
    int tid = threadIdx.x;
    // XCD-aware swizzle (gridDim.x divisible by 8; BSZ=4, 8 XCDs -> 2 XCDs/batch)
    int bid = blockIdx.x;
    int xcd = bid & 7;
    int batch = xcd >> 1;
    int within = ((bid >> 3) << 1) | (xcd & 1);
    int rowBase = batch * n + within * 16;
    float eps1 = 1.0f + beps[blk];

    // ---- phase A: aggregation -> LDS tb (f16) ----
    {
        int rl = tid >> 4, cg = tid & 15;
        int r = rowBase + rl;
        int b = r / n, i = r - b * n;
        const halfx4* zb = (const halfx4*)zin + (size_t)b * n * 64;
        f32x4 acc[4];
#pragma unroll
        for (int u = 0; u < 4; ++u) acc[u] = h2f(zb[(size_t)i * 64 + cg + 16 * u]) * eps1;
        int cnt = 0;
        if (tag == 0) {
            int deg = ldeg0[i];
            const int* lc = lcol0 + i * 64;
            int p = 0;
            for (; p + 4 <= deg; p += 4) {
                int j0 = lc[p], j1 = lc[p + 1], j2 = lc[p + 2], j3 = lc[p + 3];
#pragma unroll
                for (int u = 0; u < 4; ++u) {
                    f32x4 v0 = h2f(zb[(size_t)j0 * 64 + cg + 16 * u]);
                    f32x4 v1 = h2f(zb[(size_t)j1 * 64 + cg + 16 * u]);
                    f32x4 v2 = h2f(zb[(size_t)j2 * 64 + cg + 16 * u]);
                    f32x4 v3 = h2f(zb[(size_t)j3 * 64 + cg + 16 * u]);
                    acc[u] += (v0 + v1) + (v2 + v3);
                }
            }
            for (; p < deg; ++p) {
                int j = lc[p];
#pragma unroll
                for (int u = 0; u < 4; ++u) acc[u] += h2f(zb[(size_t)j * 64 + cg + 16 * u]);
            }
            cnt = deg;
        } else {
            int o = orig[b * NTOT + i];
            int deg = ldeg0[o];
            const int* lc = lcol0 + o * 64;
            const int* invb = inv + b * NTOT;
            int p = 0;
            for (; p + 4 <= deg; p += 4) {
                int v0 = invb[lc[p]], v1 = invb[lc[p + 1]];
                int v2 = invb[lc[p + 2]], v3 = invb[lc[p + 3]];
                if ((v0 >> 12) == tag) {
                    int j = v0 & 4095; ++cnt;
#pragma unroll
                    for (int u = 0; u < 4; ++u) acc[u] += h2f(zb[(size_t)j * 64 + cg + 16 * u]);
                }
                if ((v1 >> 12) == tag) {
                    int j = v1 & 4095; ++cnt;
#pragma unroll
                    for (int u = 0; u < 4; ++u) acc[u] += h2f(zb[(size_t)j * 64 + cg + 16 * u]);
                }
                if ((v2 >> 12) == tag) {
                    int j = v2 & 4095; ++cnt;
#pragma unroll
                    for (int u = 0; u < 4; ++u) acc[u] += h2f(zb[(size_t)j * 64 + cg + 16 * u]);
                }
                if ((v3 >> 12) == tag) {
                    int j = v3 & 4095; ++cnt;
#pragma unroll
                    for (int u = 0; u < 4; ++u) acc[u] += h2f(zb[(size_t)j * 64 + cg + 16 * u]);
                }
            }
            for (; p < deg; ++p) {
                int v = invb[lc[p]];
                if ((v >> 12) == tag) {
                    int j = v & 4095; ++cnt;
#pragma unroll
                    for (int u = 0; u < 4; ++u) acc[u] += h2f(zb[(size_t)j * 64 + cg + 16 * u]);
                }
            }
        }
        float coefb = eps1 + (float)cnt;
#pragma unroll
        for (int u = 0; u < 4; ++u) {
            int c4 = cg + 16 * u;
            f32x4 gvv = ((const f32x4*)gv)[c4];
            f32x4 bvv = ((const f32x4*)bbv)[c4];
            f32x4 tv = gvv * acc[u] + bvv * coefb;
            *(halfx4*)&tb[rl][c4 * 4] = f2h(tv);
        }
    }
    __syncthreads();

    int w = tid >> 6, l = tid & 63;
    int lo = l & 15, hi = l >> 4;
    int kb = hi * 8;

    // ---- phase B: mm1 + silu -> ub ----
    {
        f32x4 acc[4] = {};
#pragma unroll
        for (int k0 = 0; k0 < DD; k0 += 32) {
            halfx8 a0 = *(const halfx8*)&tb[lo][kb + k0];
#pragma unroll
            for (int j = 0; j < 4; ++j) {
                halfx8 bj = *(const halfx8*)(Wt1 + (size_t)(w * 64 + j * 16 + lo) * DD + kb + k0);
                acc[j] = __builtin_amdgcn_mfma_f32_16x16x32_f16(a0, bj, acc[j], 0, 0, 0);
            }
        }
        float bs[4];
#pragma unroll
        for (int j = 0; j < 4; ++j) bs[j] = b1v[w * 64 + j * 16 + lo];
#pragma unroll
        for (int q = 0; q < 4; ++q)
#pragma unroll
            for (int j = 0; j < 4; ++j) {
                float v = acc[j][q] + bs[j];
                v = v / (1.0f + expf(-v));
                ub[hi * 4 + q][w * 64 + j * 16 + lo] = (half_t)v;
            }
    }
    __syncthreads();

    // ---- phase C: mm2 + residual + stats (+score) + z ----
    {
        f32x4 acc[4] = {};
#pragma unroll
        for (int k0 = 0; k0 < DD; k0 += 32) {
            halfx8 a0 = *(const halfx8*)&ub[lo][kb + k0];
#pragma unroll
            for (int j = 0; j < 4; ++j) {
                halfx8 bj = *(const halfx8*)(Wt2 + (size_t)(w * 64 + j * 16 + lo) * DD + kb + k0);
                acc[j] = __builtin_amdgcn_mfma_f32_16x16x32_f16(a0, bj, acc[j], 0, 0, 0);
            }
        }
        float bs[4], pv[4] = {};
#pragma unroll
        for (int j = 0; j < 4; ++j) bs[j] = b2v[w * 64 + j * 16 + lo];
        if (SCORE) {
#pragma unroll
            for (int j = 0; j < 4; ++j) pv[j] = poolp[dep * DD + w * 64 + j * 16 + lo];
        }
        float vh[4][4];
#pragma unroll
        for (int q = 0; q < 4; ++q) {
            int r = rowBase + hi * 4 + q;
            float s = 0.f, ss = 0.f, sp = 0.f;
#pragma unroll
            for (int j = 0; j < 4; ++j) {
                int c = w * 64 + j * 16 + lo;
                float v = h[(size_t)r * DD + c] + acc[j][q] + bs[j];
                vh[j][q] = v;
                s += v; ss += v * v;
                if (SCORE) sp += v * pv[j];
            }
#pragma unroll
            for (int m = 1; m < 16; m <<= 1) {
                s += __shfl_xor(s, m); ss += __shfl_xor(ss, m);
                if (SCORE) sp += __shfl_xor(sp, m);
            }
            if (lo == 0) {
                int rl = hi * 4 + q;
                part[w][rl][0] = s; part[w][rl][1] = ss;
                if (SCORE) part[w][rl][2] = sp;
            }
        }
        __syncthreads();
        if (tid < 16) {
            float s = 0.f, ss = 0.f, sp = 0.f;
#pragma unroll
            for (int w2 = 0; w2 < 4; ++w2) {
                s += part[w2][tid][0]; ss += part[w2][tid][1];
                if (SCORE) sp += part[w2][tid][2];
            }
            float mean = s * (1.0f / DD);
            float var = ss * (1.0f / DD) - mean * mean;
            mrs[tid][0] = mean;
            mrs[tid][1] = rsqrtf(var + 1e-5f);
            if (SCORE) {
                int r = rowBase + tid;
                int b2 = r / n, ii = r - b2 * n;
                scores[b2 * NTOT + ii] = sp * pinv_all[dep];
            }
        }
        __syncthreads();
#pragma unroll
        for (int q = 0; q < 4; ++q) {
            int rl = hi * 4 + q;
            int r = rowBase + rl;
            float mean = mrs[rl][0], rs = mrs[rl][1];
#pragma unroll
            for (int j = 0; j < 4; ++j) {
                int c = w * 64 + j * 16 + lo;
                float v = vh[j][q];
                h[(size_t)r * DD + c] = v;
                zout[(size_t)r * DD + c] = (half_t)((v - mean) * rs);
            }
        }
    }
}

// ---------------- pooling: 1-pass radix + candidate rank (fallback: full radix) ----------------
__global__ void topk_kernel(const float* __restrict__ scores, const int* __restrict__ orig_cur,
                            int* __restrict__ orig_next, int* __restrict__ idx_local,
                            float* __restrict__ gate, int n, int k) {
    __shared__ unsigned keys[2048];
    __shared__ int hist[256];
    __shared__ int sg[256], se[256];
    __shared__ int sh_bucket, sh_r, sh_cnt;
    __shared__ unsigned cand[256];
    __shared__ unsigned sh_thr;
    int b = blockIdx.x;
    const float* sc = scores + b * NTOT;
    int tid = threadIdx.x;
    for (int i = tid; i < n; i += 256) {
        unsigned u = __float_as_uint(sc[i]);
        keys[i] = (u & 0x80000000u) ? ~u : (u | 0x80000000u);
    }
    hist[tid] = 0;
    if (tid == 0) sh_cnt = 0;
    __syncthreads();
    for (int i = tid; i < n; i += 256) atomicAdd(&hist[keys[i] >> 24], 1);
    __syncthreads();
    int cnt = hist[tid];
    sg[tid] = cnt;
    __syncthreads();
    for (int off = 1; off < 256; off <<= 1) {
        int v = (tid >= off) ? sg[tid - off] : 0;
        __syncthreads();
        sg[tid] += v;
        __syncthreads();
    }
    int r = n - k;  // 0-indexed rank ascending
    int incl = sg[tid], excl = incl - cnt;
    if (excl <= r && r < incl) { sh_bucket = tid; sh_r = r - excl; }
    __syncthreads();
    int b1 = sh_bucket, r1 = sh_r;
    int c = hist[b1];
    unsigned thrkey;
    if (c <= 256) {
        for (int i = tid; i < n; i += 256) {
            unsigned key = keys[i];
            if ((key >> 24) == (unsigned)b1) {
                int pos = atomicAdd(&sh_cnt, 1);
                cand[pos] = key;
            }
        }
        __syncthreads();
        if (tid < c) {
            unsigned mine = cand[tid];
            int less = 0, eq = 0;
            for (int j = 0; j < c; ++j) {
                unsigned oth = cand[j];
                less += (oth < mine); eq += (oth == mine);
            }
            if (less <= r1 && r1 < less + eq) sh_thr = mine;
        }
        __syncthreads();
        thrkey = sh_thr;
    } else {
        unsigned prefix = ((unsigned)b1) << 24;
        int rr = r1;
        for (int shift = 16; shift >= 0; shift -= 8) {
            __syncthreads();
            hist[tid] = 0;
            __syncthreads();
            unsigned mask = 0xFFFFFFFFu << (shift + 8);
            for (int i = tid; i < n; i += 256) {
                unsigned key = keys[i];
                if ((key & mask) == (prefix & mask)) atomicAdd(&hist[(key >> shift) & 255], 1);
            }
            __syncthreads();
            int cnt2 = hist[tid];
            sg[tid] = cnt2;
            __syncthreads();
            for (int off = 1; off < 256; off <<= 1) {
                int v = (tid >= off) ? sg[tid - off] : 0;
                __syncthreads();
                sg[tid] += v;
                __syncthreads();
            }
            int incl2 = sg[tid], excl2 = incl2 - cnt2;
            if (excl2 <= rr && rr < incl2) { sh_bucket = tid; sh_r = rr - excl2; }
            __syncthreads();
            prefix |= ((unsigned)sh_bucket) << shift;
            rr = sh_r;
            __syncthreads();
        }
        thrkey = prefix;
    }
    unsigned uthr = (thrkey & 0x80000000u) ? (thrkey ^ 0x80000000u) : ~thrkey;
    float thr = __uint_as_float(uthr);  // exact k-th largest value
    int chunk = n / 256;
    int base = tid * chunk;
    int cgt = 0, ceq = 0;
    for (int u = 0; u < chunk; ++u) {
        float s = sc[base + u];
        cgt += (s > thr); ceq += (s == thr);
    }
    sg[tid] = cgt; se[tid] = ceq; __syncthreads();
    for (int off = 1; off < 256; off <<= 1) {
        int vg = (tid >= off) ? sg[tid - off] : 0;
        int ve = (tid >= off) ? se[tid - off] : 0;
        __syncthreads();
        sg[tid] += vg; se[tid] += ve;
        __syncthreads();
    }
    int total_gt = sg[255];
    int ties = k - total_gt;
    int gtb = sg[tid] - cgt, eqb = se[tid] - ceq;
    for (int u = 0; u < chunk; ++u) {
        int i = base + u;
        float s = sc[i];
        bool isgt = (s > thr), iseq = (s == thr);
        bool keep = isgt || (iseq && eqb < ties);
        if (keep) {
            int pos = gtb + (eqb < ties ? eqb : ties);
            idx_local[b * NTOT + pos] = i;
            gate[b * NTOT + pos] = tanhf(s);
            orig_next[b * NTOT + pos] = orig_cur[b * NTOT + i];
        }
        gtb += isgt; eqb += iseq;
    }
}

// gather gated rows, recompute stats, write z (f16), set inverse map (XCD-swizzled)
__global__ void __launch_bounds__(64) gather_kernel(
    const float* __restrict__ h, const int* __restrict__ idx_local,
    const float* __restrict__ gate, const int* __restrict__ orig_new,
    float* __restrict__ hout, half_t* __restrict__ zout, int* __restrict__ inv,
    int n_old, int k, int tag) {
    int bid = blockIdx.x;
    int xcd = bid & 7;
    int b = xcd >> 1;
    int rr = ((bid >> 3) << 1) | (xcd & 1);  // [0, k)
    int r = b * k + rr;
    int lane = threadIdx.x;
    int src = idx_local[b * NTOT + rr];
    float gg = gate[b * NTOT + rr];
    f32x4 v = ((const f32x4*)h)[(size_t)(b * n_old + src) * 64 + lane] * gg;
    ((f32x4*)hout)[(size_t)r * 64 + lane] = v;
    float s = v[0] + v[1] + v[2] + v[3];
    float ss = v[0] * v[0] + v[1] * v[1] + v[2] * v[2] + v[3] * v[3];
#pragma unroll
    for (int m = 1; m < 64; m <<= 1) { s += __shfl_xor(s, m); ss += __shfl_xor(ss, m); }
    float mean = s * (1.0f / DD);
    float rs = rsqrtf(ss * (1.0f / DD) - mean * mean + 1e-5f);
    ((halfx4*)zout)[(size_t)r * 64 + lane] = f2h((v - mean) * rs);
    if (lane == 0) inv[b * NTOT + orig_new[b * NTOT + rr]] = (tag << 12) | rr;
}

// ---------------- fused readout + final projection (4 blocks) ----------------
__global__ void __launch_bounds__(256) readout_final_kernel(
    const float* __restrict__ h, const float* __restrict__ lw,
    const float* __restrict__ lb, float* __restrict__ out) {
    __shared__ float feat[512];
    int b = blockIdx.x, d = threadIdx.x;
    const float* hb = h + (size_t)b * 256 * DD;
    float s = 0.f;
    for (int i = 0; i < 256; ++i) s += hb[(size_t)i * DD + d];
    float mean = s / 256.0f;
    float s2 = 0.f;
    for (int i = 0; i < 256; ++i) {
        float diff = hb[(size_t)i * DD + d] - mean;
        s2 += diff * diff;
    }
    feat[d] = mean;
    feat[256 + d] = sqrtf(s2 / 255.0f) + 1e-6f;
    __syncthreads();
    if (d < 128) {
        float acc = lb[d];
        for (int k = 0; k < 512; ++k) acc += feat[k] * lw[k * 128 + d];
        out[b * 128 + d] = acc;
    }
}

extern "C" void kernel_launch(void* const* d_in, const int* in_sizes, int n_in,
                              void* d_out, int out_size, void* d_ws, size_t ws_size,
                              hipStream_t stream) {
    (void)in_sizes; (void)n_in; (void)out_size; (void)ws_size;
    const float* x     = (const float*)d_in[0];
    const float* adj   = (const float*)d_in[1];
    const float* pos   = (const float*)d_in[2];
    const float* in_w  = (const float*)d_in[3];
    const float* in_b  = (const float*)d_in[4];
    const float* pw1   = (const float*)d_in[5];
    const float* pb1   = (const float*)d_in[6];
    const float* pw2   = (const float*)d_in[7];
    const float* pb2   = (const float*)d_in[8];
    const float* bg    = (const float*)d_in[9];
    const float* bb    = (const float*)d_in[10];
    const float* bw1   = (const float*)d_in[11];
    const float* bb1   = (const float*)d_in[12];
    const float* bw2   = (const float*)d_in[13];
    const float* bb2   = (const float*)d_in[14];
    const float* beps  = (const float*)d_in[15];
    const float* poolp = (const float*)d_in[16];
    const float* lw    = (const float*)d_in[17];
    const float* lb    = (const float*)d_in[18];
    float* out = (float*)d_out;

    char* wp = (char*)d_ws;
    auto alloc = [&](size_t bytes) -> void* {
        void* p = (void*)wp;
        wp += (bytes + 255) & ~(size_t)255;
        return p;
    };
    const size_t HBYTES = (size_t)BSZ * NTOT * DD * sizeof(float);  // 8.39 MB
    float*  h    = (float*)alloc(HBYTES);
    float*  bufC = (float*)alloc(HBYTES);          // gather target
    half_t* zA   = (half_t*)alloc(HBYTES / 2);
    half_t* zB   = (half_t*)alloc(HBYTES / 2);
    half_t* Wt   = (half_t*)alloc((size_t)17 * DD * DD * sizeof(half_t));
    float* pstats  = (float*)alloc(8 * sizeof(float));
    float* pinv    = (float*)alloc(4 * sizeof(float));
    float* scores  = (float*)alloc(BSZ * NTOT * sizeof(float));
    float* gate    = (float*)alloc(BSZ * NTOT * sizeof(float));
    int*   origA   = (int*)alloc(BSZ * NTOT * sizeof(int));
    int*   origB   = (int*)alloc(BSZ * NTOT * sizeof(int));
    int*   idxl    = (int*)alloc(BSZ * NTOT * sizeof(int));
    int*   inv     = (int*)alloc(BSZ * NTOT * sizeof(int));
    int*   ldeg0   = (int*)alloc(NTOT * sizeof(int));
    int*   lcol0   = (int*)alloc((size_t)NTOT * 64 * sizeof(int));

    // ---- init: 2 dispatches ----
    setup_kernel<<<SB_MAPS, 256, 0, stream>>>(bw1, bw2, pw2, Wt, pos, pstats, poolp, pinv,
                                              adj, ldeg0, lcol0, origA, inv);
    pe_h_kernel<<<NTOT / 16, 256, 0, stream>>>(pos, pstats, pw1, pb1,
                                               Wt + (size_t)16 * DD * DD, pb2,
                                               x, in_w, in_b, h, zA);

    float* hcur = h;
    float* halt = bufC;
    half_t* zin = zA;
    half_t* zout = zB;
    int* orig = origA;
    int* orign = origB;
    int n = NTOT;
    int blk = 0;
    for (int dep = 0; dep < 4; ++dep) {
        for (int s = 0; s < 2; ++s) {
            int rows = BSZ * n;
            const half_t* W1 = Wt + (size_t)blk * DD * DD;
            const half_t* W2 = Wt + (size_t)(8 + blk) * DD * DD;
            const float* B1 = bb1 + blk * DD;
            const float* B2 = bb2 + blk * DD;
            const float* G  = bg + blk * DD;
            const float* BB = bb + blk * DD;
            int sc = (s == 1 && dep < 3) ? 1 : 0;
            if (sc) layer_kernel<1><<<rows / 16, 256, 0, stream>>>(
                hcur, zin, zout, W1, W2, B1, B2, G, BB, beps, blk,
                ldeg0, lcol0, orig, inv, poolp, pinv, scores, dep, n, dep);
            else    layer_kernel<0><<<rows / 16, 256, 0, stream>>>(
                hcur, zin, zout, W1, W2, B1, B2, G, BB, beps, blk,
                ldeg0, lcol0, orig, inv, nullptr, nullptr, nullptr, 0, n, dep);
            { half_t* t = zin; zin = zout; zout = t; }
            ++blk;
        }
        if (dep < 3) {
            int k = n / 2;
            topk_kernel<<<BSZ, 256, 0, stream>>>(scores, orig, orign, idxl, gate, n, k);
            { int* t = orig; orig = orign; orign = t; }
            gather_kernel<<<BSZ * k, 64, 0, stream>>>(hcur, idxl, gate, orig, halt, zin, inv,
                                                      n, k, dep + 1);
            { float* t = hcur; hcur = halt; halt = t; }
            n = k;
        }
    }
    // ---- readout + final ----
    readout_final_kernel<<<BSZ, 256, 0, stream>>>(hcur, lw, lb, out);
}

// Round 13
// 261.620 us; speedup vs baseline: 1.2540x; 1.0401x over previous
//
#include <hip/hip_runtime.h>
#include <hip/hip_bf16.h>

#define NTOT 2048
#define DD 256
#define BSZ 4

typedef _Float16 half_t;
typedef __attribute__((ext_vector_type(8))) _Float16 halfx8;
typedef __attribute__((ext_vector_type(4))) _Float16 halfx4;
typedef __attribute__((ext_vector_type(4))) float f32x4;

__device__ __forceinline__ f32x4 h2f(halfx4 v) {
    f32x4 r;
#pragma unroll
    for (int e = 0; e < 4; ++e) r[e] = (float)v[e];
    return r;
}
__device__ __forceinline__ halfx4 f2h(f32x4 v) {
    halfx4 r;
#pragma unroll
    for (int e = 0; e < 4; ++e) r[e] = (half_t)v[e];
    return r;
}

// ---------------- block reduce (256 threads) ----------------
__device__ __forceinline__ float blockReduceSum256(float v) {
    __shared__ float red[4];
    for (int off = 32; off > 0; off >>= 1) v += __shfl_down(v, off);
    int lane = threadIdx.x & 63, w = threadIdx.x >> 6;
    __syncthreads();
    if (lane == 0) red[w] = v;
    __syncthreads();
    return red[0] + red[1] + red[2] + red[3];
}

// ---------------- mega setup: wprep | stats | adj->lcol0 | maps ----------------
#define SB_WPREP 4352
#define SB_STAT  4356
#define SB_A2L   4868
#define SB_MAPS  4900
__global__ void __launch_bounds__(256) setup_kernel(
    const float* __restrict__ bw1, const float* __restrict__ bw2,
    const float* __restrict__ pw2, half_t* __restrict__ Wt,
    const float* __restrict__ pos, float* __restrict__ pstats,
    const float* __restrict__ poolp, float* __restrict__ pinv,
    const float* __restrict__ adj, int* __restrict__ ldeg0, int* __restrict__ lcol0,
    int* __restrict__ orig, int* __restrict__ inv) {
    int bid = blockIdx.x, tid = threadIdx.x;
    if (bid < SB_WPREP) {
        int m = bid >> 8, rem = bid & 255;
        int nb = (rem >> 4) * 16, kb = (rem & 15) * 16;
        const float* W = (m < 8) ? (bw1 + (size_t)m * DD * DD)
                      : (m < 16) ? (bw2 + (size_t)(m - 8) * DD * DD)
                                 : pw2;
        __shared__ float s[16][17];
        int i = tid >> 4, j = tid & 15;
        s[i][j] = W[(size_t)(kb + i) * DD + nb + j];
        __syncthreads();
        Wt[(size_t)m * DD * DD + (size_t)(nb + i) * DD + kb + j] = (half_t)s[j][i];
    } else if (bid < SB_STAT) {
        int which = bid - SB_WPREP;
        if (which == 0) {
            float s[3] = {0.f, 0.f, 0.f};
            for (int i = tid; i < NTOT; i += 256)
                for (int c = 0; c < 3; ++c) s[c] += pos[i * 3 + c];
            float m[3];
            for (int c = 0; c < 3; ++c) m[c] = blockReduceSum256(s[c]) / (float)NTOT;
            float q[3] = {0.f, 0.f, 0.f};
            for (int i = tid; i < NTOT; i += 256)
                for (int c = 0; c < 3; ++c) { float d = pos[i * 3 + c] - m[c]; q[c] += d * d; }
            for (int c = 0; c < 3; ++c) {
                float t = blockReduceSum256(q[c]);
                if (tid == 0) {
                    float var = ((float)BSZ * t) / ((float)BSZ * NTOT - 1.0f);
                    pstats[c] = m[c];
                    pstats[3 + c] = 1.0f / (sqrtf(var) + 1e-8f);
                }
            }
        } else {
            int dep = which - 1;
            float v = poolp[dep * DD + tid];
            float ss = blockReduceSum256(v * v);
            if (tid == 0) pinv[dep] = rsqrtf(ss);
        }
    } else if (bid < SB_A2L) {
        int row = (bid - SB_STAT) * 4 + (tid >> 6);
        int lane = tid & 63;
        int run = 0;
        for (int j0 = 0; j0 < NTOT; j0 += 64) {
            int j = j0 + lane;
            bool pred = adj[(size_t)row * NTOT + j] != 0.f;
            unsigned long long mask = __ballot(pred);
            if (pred) {
                int pos2 = run + __popcll(mask & ((1ull << lane) - 1ull));
                if (pos2 < 64) lcol0[row * 64 + pos2] = j;
            }
            run += __popcll(mask);
        }
        if (lane == 0) ldeg0[row] = run < 64 ? run : 64;
    } else {
        int t = (bid - SB_A2L) * 256 + tid;  // B*NTOT
        int i = t & (NTOT - 1);
        orig[t] = i; inv[t] = i;  // tag 0
    }
}

// ---------------- fused pe + input projection + h/z init (z -> f16) ----------------
__global__ void __launch_bounds__(256) pe_h_kernel(
    const float* __restrict__ pos, const float* __restrict__ pstats,
    const float* __restrict__ pw1, const float* __restrict__ pb1,
    const half_t* __restrict__ Wt16, const float* __restrict__ pb2,
    const float* __restrict__ x, const float* __restrict__ in_w,
    const float* __restrict__ in_b, float* __restrict__ h, half_t* __restrict__ z) {
    __shared__ half_t tb[16][264];
    __shared__ float iw[16][DD];
    __shared__ float xs[16][16];
    __shared__ float part[4][16][2];
    __shared__ float mrs[16][2];
    int tid = threadIdx.x;
    int i0 = blockIdx.x * 16;
    {
        int rl = tid >> 4, cb = (tid & 15) * 16;
        float pn[3];
#pragma unroll
        for (int c = 0; c < 3; ++c)
            pn[c] = (pos[(i0 + rl) * 3 + c] - pstats[c]) * pstats[3 + c];
#pragma unroll
        for (int u = 0; u < 16; ++u) {
            int d = cb + u;
            float a = pb1[d];
            a += pn[0] * pw1[d];
            a += pn[1] * pw1[DD + d];
            a += pn[2] * pw1[2 * DD + d];
            a = a / (1.0f + expf(-a));
            tb[rl][d] = (half_t)a;
        }
        int k = tid >> 4;
#pragma unroll
        for (int u = 0; u < 16; ++u) iw[k][cb + u] = in_w[k * DD + cb + u];
    }
    __syncthreads();
    int w = tid >> 6, l = tid & 63;
    int lo = l & 15, hi = l >> 4;
    int kb = hi * 8;
    float pe_r[4][4];
    {
        f32x4 acc[4] = {};
#pragma unroll
        for (int k0 = 0; k0 < DD; k0 += 32) {
            halfx8 a0 = *(const halfx8*)&tb[lo][kb + k0];
#pragma unroll
            for (int j = 0; j < 4; ++j) {
                halfx8 bj = *(const halfx8*)(Wt16 + (size_t)(w * 64 + j * 16 + lo) * DD + kb + k0);
                acc[j] = __builtin_amdgcn_mfma_f32_16x16x32_f16(a0, bj, acc[j], 0, 0, 0);
            }
        }
#pragma unroll
        for (int j = 0; j < 4; ++j) {
            float bs = pb2[w * 64 + j * 16 + lo];
#pragma unroll
            for (int q = 0; q < 4; ++q) pe_r[j][q] = acc[j][q] + bs;
        }
    }
    float xb[4];
#pragma unroll
    for (int j = 0; j < 4; ++j) xb[j] = in_b[w * 64 + j * 16 + lo];
    for (int b = 0; b < BSZ; ++b) {
        __syncthreads();
        xs[tid >> 4][tid & 15] = x[(size_t)(b * NTOT + i0 + (tid >> 4)) * 16 + (tid & 15)];
        __syncthreads();
        float vh[4][4];
#pragma unroll
        for (int q = 0; q < 4; ++q) {
            int rl = hi * 4 + q;
            float s = 0.f, ss = 0.f;
#pragma unroll
            for (int j = 0; j < 4; ++j) {
                int c = w * 64 + j * 16 + lo;
                float acc = xb[j];
#pragma unroll
                for (int k = 0; k < 16; ++k) acc += xs[rl][k] * iw[k][c];
                float v = acc + pe_r[j][q];
                vh[j][q] = v;
                s += v; ss += v * v;
            }
#pragma unroll
            for (int m = 1; m < 16; m <<= 1) { s += __shfl_xor(s, m); ss += __shfl_xor(ss, m); }
            if (lo == 0) { part[w][rl][0] = s; part[w][rl][1] = ss; }
        }
        __syncthreads();
        if (tid < 16) {
            float s = 0.f, ss = 0.f;
#pragma unroll
            for (int w2 = 0; w2 < 4; ++w2) { s += part[w2][tid][0]; ss += part[w2][tid][1]; }
            float mean = s * (1.0f / DD);
            float var = ss * (1.0f / DD) - mean * mean;
            mrs[tid][0] = mean;
            mrs[tid][1] = rsqrtf(var + 1e-5f);
        }
        __syncthreads();
#pragma unroll
        for (int q = 0; q < 4; ++q) {
            int rl = hi * 4 + q;
            size_t r = (size_t)(b * NTOT + i0 + rl);
            float mean = mrs[rl][0], rs = mrs[rl][1];
#pragma unroll
            for (int j = 0; j < 4; ++j) {
                int c = w * 64 + j * 16 + lo;
                float v = vh[j][q];
                h[r * DD + c] = v;
                z[r * DD + c] = (half_t)((v - mean) * rs);
            }
        }
    }
}

// ---------------- fused layer, 16 rows/block, 512 threads (8 waves), XCD-swizzled ----
// wave w owns cols [32w, 32w+32); phase A: 32 thr/row, 2 halfx4 chunks each.
template <int SCORE>
__global__ void __launch_bounds__(512) layer_kernel(
    float* __restrict__ h, const half_t* __restrict__ zin, half_t* __restrict__ zout,
    const half_t* __restrict__ Wt1, const half_t* __restrict__ Wt2,
    const float* __restrict__ b1v, const float* __restrict__ b2v,
    const float* __restrict__ gv, const float* __restrict__ bbv,
    const float* __restrict__ beps, int blk,
    const int* __restrict__ ldeg0, const int* __restrict__ lcol0,
    const int* __restrict__ orig, const int* __restrict__ inv,
    const float* __restrict__ poolp, const float* __restrict__ pinv_all,
    float* __restrict__ scores, int dep, int n, int tag) {
    __shared__ half_t tb[16][264];
    __shared__ half_t ub[16][264];
    __shared__ float part[8][16][3];
    __shared__ float mrs[16][2];
    int tid = threadIdx.x;
    // XCD-aware swizzle (gridDim.x divisible by 8; BSZ=4, 8 XCDs -> 2 XCDs/batch)
    int bid = blockIdx.x;
    int xcd = bid & 7;
    int batch = xcd >> 1;
    int within = ((bid >> 3) << 1) | (xcd & 1);
    int rowBase = batch * n + within * 16;
    float eps1 = 1.0f + beps[blk];

    // ---- phase A: aggregation -> LDS tb (f16); 32 thr/row ----
    {
        int rl = tid >> 5, cg = tid & 31;
        int r = rowBase + rl;
        int b = r / n, i = r - b * n;
        const halfx4* zb = (const halfx4*)zin + (size_t)b * n * 64;
        f32x4 acc[2];
#pragma unroll
        for (int u = 0; u < 2; ++u) acc[u] = h2f(zb[(size_t)i * 64 + cg + 32 * u]) * eps1;
        int cnt = 0;
        if (tag == 0) {
            int deg = ldeg0[i];
            const int* lc = lcol0 + i * 64;
            int p = 0;
            for (; p + 4 <= deg; p += 4) {
                int j0 = lc[p], j1 = lc[p + 1], j2 = lc[p + 2], j3 = lc[p + 3];
#pragma unroll
                for (int u = 0; u < 2; ++u) {
                    f32x4 v0 = h2f(zb[(size_t)j0 * 64 + cg + 32 * u]);
                    f32x4 v1 = h2f(zb[(size_t)j1 * 64 + cg + 32 * u]);
                    f32x4 v2 = h2f(zb[(size_t)j2 * 64 + cg + 32 * u]);
                    f32x4 v3 = h2f(zb[(size_t)j3 * 64 + cg + 32 * u]);
                    acc[u] += (v0 + v1) + (v2 + v3);
                }
            }
            for (; p < deg; ++p) {
                int j = lc[p];
#pragma unroll
                for (int u = 0; u < 2; ++u) acc[u] += h2f(zb[(size_t)j * 64 + cg + 32 * u]);
            }
            cnt = deg;
        } else {
            int o = orig[b * NTOT + i];
            int deg = ldeg0[o];
            const int* lc = lcol0 + o * 64;
            const int* invb = inv + b * NTOT;
            int p = 0;
            for (; p + 4 <= deg; p += 4) {
                int v0 = invb[lc[p]], v1 = invb[lc[p + 1]];
                int v2 = invb[lc[p + 2]], v3 = invb[lc[p + 3]];
                if ((v0 >> 12) == tag) {
                    int j = v0 & 4095; ++cnt;
#pragma unroll
                    for (int u = 0; u < 2; ++u) acc[u] += h2f(zb[(size_t)j * 64 + cg + 32 * u]);
                }
                if ((v1 >> 12) == tag) {
                    int j = v1 & 4095; ++cnt;
#pragma unroll
                    for (int u = 0; u < 2; ++u) acc[u] += h2f(zb[(size_t)j * 64 + cg + 32 * u]);
                }
                if ((v2 >> 12) == tag) {
                    int j = v2 & 4095; ++cnt;
#pragma unroll
                    for (int u = 0; u < 2; ++u) acc[u] += h2f(zb[(size_t)j * 64 + cg + 32 * u]);
                }
                if ((v3 >> 12) == tag) {
                    int j = v3 & 4095; ++cnt;
#pragma unroll
                    for (int u = 0; u < 2; ++u) acc[u] += h2f(zb[(size_t)j * 64 + cg + 32 * u]);
                }
            }
            for (; p < deg; ++p) {
                int v = invb[lc[p]];
                if ((v >> 12) == tag) {
                    int j = v & 4095; ++cnt;
#pragma unroll
                    for (int u = 0; u < 2; ++u) acc[u] += h2f(zb[(size_t)j * 64 + cg + 32 * u]);
                }
            }
        }
        float coefb = eps1 + (float)cnt;
#pragma unroll
        for (int u = 0; u < 2; ++u) {
            int c4 = cg + 32 * u;
            f32x4 gvv = ((const f32x4*)gv)[c4];
            f32x4 bvv = ((const f32x4*)bbv)[c4];
            f32x4 tv = gvv * acc[u] + bvv * coefb;
            *(halfx4*)&tb[rl][c4 * 4] = f2h(tv);
        }
    }
    __syncthreads();

    int w = tid >> 6, l = tid & 63;   // w: 0..7
    int lo = l & 15, hi = l >> 4;
    int kb = hi * 8;

    // ---- phase B: mm1 + silu -> ub (wave w -> cols [32w, 32w+32)) ----
    {
        f32x4 acc[2] = {};
#pragma unroll
        for (int k0 = 0; k0 < DD; k0 += 32) {
            halfx8 a0 = *(const halfx8*)&tb[lo][kb + k0];
#pragma unroll
            for (int j = 0; j < 2; ++j) {
                halfx8 bj = *(const halfx8*)(Wt1 + (size_t)(w * 32 + j * 16 + lo) * DD + kb + k0);
                acc[j] = __builtin_amdgcn_mfma_f32_16x16x32_f16(a0, bj, acc[j], 0, 0, 0);
            }
        }
        float bs[2];
#pragma unroll
        for (int j = 0; j < 2; ++j) bs[j] = b1v[w * 32 + j * 16 + lo];
#pragma unroll
        for (int q = 0; q < 4; ++q)
#pragma unroll
            for (int j = 0; j < 2; ++j) {
                float v = acc[j][q] + bs[j];
                v = v / (1.0f + expf(-v));
                ub[hi * 4 + q][w * 32 + j * 16 + lo] = (half_t)v;
            }
    }
    __syncthreads();

    // ---- phase C: mm2 + residual + stats (+score) + z ----
    {
        f32x4 acc[2] = {};
#pragma unroll
        for (int k0 = 0; k0 < DD; k0 += 32) {
            halfx8 a0 = *(const halfx8*)&ub[lo][kb + k0];
#pragma unroll
            for (int j = 0; j < 2; ++j) {
                halfx8 bj = *(const halfx8*)(Wt2 + (size_t)(w * 32 + j * 16 + lo) * DD + kb + k0);
                acc[j] = __builtin_amdgcn_mfma_f32_16x16x32_f16(a0, bj, acc[j], 0, 0, 0);
            }
        }
        float bs[2], pv[2] = {};
#pragma unroll
        for (int j = 0; j < 2; ++j) bs[j] = b2v[w * 32 + j * 16 + lo];
        if (SCORE) {
#pragma unroll
            for (int j = 0; j < 2; ++j) pv[j] = poolp[dep * DD + w * 32 + j * 16 + lo];
        }
        float vh[2][4];
#pragma unroll
        for (int q = 0; q < 4; ++q) {
            int r = rowBase + hi * 4 + q;
            float s = 0.f, ss = 0.f, sp = 0.f;
#pragma unroll
            for (int j = 0; j < 2; ++j) {
                int c = w * 32 + j * 16 + lo;
                float v = h[(size_t)r * DD + c] + acc[j][q] + bs[j];
                vh[j][q] = v;
                s += v; ss += v * v;
                if (SCORE) sp += v * pv[j];
            }
#pragma unroll
            for (int m = 1; m < 16; m <<= 1) {
                s += __shfl_xor(s, m); ss += __shfl_xor(ss, m);
                if (SCORE) sp += __shfl_xor(sp, m);
            }
            if (lo == 0) {
                int rl = hi * 4 + q;
                part[w][rl][0] = s; part[w][rl][1] = ss;
                if (SCORE) part[w][rl][2] = sp;
            }
        }
        __syncthreads();
        if (tid < 16) {
            float s = 0.f, ss = 0.f, sp = 0.f;
#pragma unroll
            for (int w2 = 0; w2 < 8; ++w2) {
                s += part[w2][tid][0]; ss += part[w2][tid][1];
                if (SCORE) sp += part[w2][tid][2];
            }
            float mean = s * (1.0f / DD);
            float var = ss * (1.0f / DD) - mean * mean;
            mrs[tid][0] = mean;
            mrs[tid][1] = rsqrtf(var + 1e-5f);
            if (SCORE) {
                int r = rowBase + tid;
                int b2 = r / n, ii = r - b2 * n;
                scores[b2 * NTOT + ii] = sp * pinv_all[dep];
            }
        }
        __syncthreads();
#pragma unroll
        for (int q = 0; q < 4; ++q) {
            int rl = hi * 4 + q;
            int r = rowBase + rl;
            float mean = mrs[rl][0], rs = mrs[rl][1];
#pragma unroll
            for (int j = 0; j < 2; ++j) {
                int c = w * 32 + j * 16 + lo;
                float v = vh[j][q];
                h[(size_t)r * DD + c] = v;
                zout[(size_t)r * DD + c] = (half_t)((v - mean) * rs);
            }
        }
    }
}

// ---------------- pooling: 1-pass radix + candidate rank (fallback: full radix) ----------------
__global__ void topk_kernel(const float* __restrict__ scores, const int* __restrict__ orig_cur,
                            int* __restrict__ orig_next, int* __restrict__ idx_local,
                            float* __restrict__ gate, int n, int k) {
    __shared__ unsigned keys[2048];
    __shared__ int hist[256];
    __shared__ int sg[256], se[256];
    __shared__ int sh_bucket, sh_r, sh_cnt;
    __shared__ unsigned cand[256];
    __shared__ unsigned sh_thr;
    int b = blockIdx.x;
    const float* sc = scores + b * NTOT;
    int tid = threadIdx.x;
    for (int i = tid; i < n; i += 256) {
        unsigned u = __float_as_uint(sc[i]);
        keys[i] = (u & 0x80000000u) ? ~u : (u | 0x80000000u);
    }
    hist[tid] = 0;
    if (tid == 0) sh_cnt = 0;
    __syncthreads();
    for (int i = tid; i < n; i += 256) atomicAdd(&hist[keys[i] >> 24], 1);
    __syncthreads();
    int cnt = hist[tid];
    sg[tid] = cnt;
    __syncthreads();
    for (int off = 1; off < 256; off <<= 1) {
        int v = (tid >= off) ? sg[tid - off] : 0;
        __syncthreads();
        sg[tid] += v;
        __syncthreads();
    }
    int r = n - k;  // 0-indexed rank ascending
    int incl = sg[tid], excl = incl - cnt;
    if (excl <= r && r < incl) { sh_bucket = tid; sh_r = r - excl; }
    __syncthreads();
    int b1 = sh_bucket, r1 = sh_r;
    int c = hist[b1];
    unsigned thrkey;
    if (c <= 256) {
        for (int i = tid; i < n; i += 256) {
            unsigned key = keys[i];
            if ((key >> 24) == (unsigned)b1) {
                int pos = atomicAdd(&sh_cnt, 1);
                cand[pos] = key;
            }
        }
        __syncthreads();
        if (tid < c) {
            unsigned mine = cand[tid];
            int less = 0, eq = 0;
            for (int j = 0; j < c; ++j) {
                unsigned oth = cand[j];
                less += (oth < mine); eq += (oth == mine);
            }
            if (less <= r1 && r1 < less + eq) sh_thr = mine;
        }
        __syncthreads();
        thrkey = sh_thr;
    } else {
        unsigned prefix = ((unsigned)b1) << 24;
        int rr = r1;
        for (int shift = 16; shift >= 0; shift -= 8) {
            __syncthreads();
            hist[tid] = 0;
            __syncthreads();
            unsigned mask = 0xFFFFFFFFu << (shift + 8);
            for (int i = tid; i < n; i += 256) {
                unsigned key = keys[i];
                if ((key & mask) == (prefix & mask)) atomicAdd(&hist[(key >> shift) & 255], 1);
            }
            __syncthreads();
            int cnt2 = hist[tid];
            sg[tid] = cnt2;
            __syncthreads();
            for (int off = 1; off < 256; off <<= 1) {
                int v = (tid >= off) ? sg[tid - off] : 0;
                __syncthreads();
                sg[tid] += v;
                __syncthreads();
            }
            int incl2 = sg[tid], excl2 = incl2 - cnt2;
            if (excl2 <= rr && rr < incl2) { sh_bucket = tid; sh_r = rr - excl2; }
            __syncthreads();
            prefix |= ((unsigned)sh_bucket) << shift;
            rr = sh_r;
            __syncthreads();
        }
        thrkey = prefix;
    }
    unsigned uthr = (thrkey & 0x80000000u) ? (thrkey ^ 0x80000000u) : ~thrkey;
    float thr = __uint_as_float(uthr);  // exact k-th largest value
    int chunk = n / 256;
    int base = tid * chunk;
    int cgt = 0, ceq = 0;
    for (int u = 0; u < chunk; ++u) {
        float s = sc[base + u];
        cgt += (s > thr); ceq += (s == thr);
    }
    sg[tid] = cgt; se[tid] = ceq; __syncthreads();
    for (int off = 1; off < 256; off <<= 1) {
        int vg = (tid >= off) ? sg[tid - off] : 0;
        int ve = (tid >= off) ? se[tid - off] : 0;
        __syncthreads();
        sg[tid] += vg; se[tid] += ve;
        __syncthreads();
    }
    int total_gt = sg[255];
    int ties = k - total_gt;
    int gtb = sg[tid] - cgt, eqb = se[tid] - ceq;
    for (int u = 0; u < chunk; ++u) {
        int i = base + u;
        float s = sc[i];
        bool isgt = (s > thr), iseq = (s == thr);
        bool keep = isgt || (iseq && eqb < ties);
        if (keep) {
            int pos = gtb + (eqb < ties ? eqb : ties);
            idx_local[b * NTOT + pos] = i;
            gate[b * NTOT + pos] = tanhf(s);
            orig_next[b * NTOT + pos] = orig_cur[b * NTOT + i];
        }
        gtb += isgt; eqb += iseq;
    }
}

// gather gated rows, recompute stats, write z (f16), set inverse map (XCD-swizzled)
__global__ void __launch_bounds__(64) gather_kernel(
    const float* __restrict__ h, const int* __restrict__ idx_local,
    const float* __restrict__ gate, const int* __restrict__ orig_new,
    float* __restrict__ hout, half_t* __restrict__ zout, int* __restrict__ inv,
    int n_old, int k, int tag) {
    int bid = blockIdx.x;
    int xcd = bid & 7;
    int b = xcd >> 1;
    int rr = ((bid >> 3) << 1) | (xcd & 1);  // [0, k)
    int r = b * k + rr;
    int lane = threadIdx.x;
    int src = idx_local[b * NTOT + rr];
    float gg = gate[b * NTOT + rr];
    f32x4 v = ((const f32x4*)h)[(size_t)(b * n_old + src) * 64 + lane] * gg;
    ((f32x4*)hout)[(size_t)r * 64 + lane] = v;
    float s = v[0] + v[1] + v[2] + v[3];
    float ss = v[0] * v[0] + v[1] * v[1] + v[2] * v[2] + v[3] * v[3];
#pragma unroll
    for (int m = 1; m < 64; m <<= 1) { s += __shfl_xor(s, m); ss += __shfl_xor(ss, m); }
    float mean = s * (1.0f / DD);
    float rs = rsqrtf(ss * (1.0f / DD) - mean * mean + 1e-5f);
    ((halfx4*)zout)[(size_t)r * 64 + lane] = f2h((v - mean) * rs);
    if (lane == 0) inv[b * NTOT + orig_new[b * NTOT + rr]] = (tag << 12) | rr;
}

// ---------------- fused readout + final projection (4 blocks) ----------------
__global__ void __launch_bounds__(256) readout_final_kernel(
    const float* __restrict__ h, const float* __restrict__ lw,
    const float* __restrict__ lb, float* __restrict__ out) {
    __shared__ float feat[512];
    int b = blockIdx.x, d = threadIdx.x;
    const float* hb = h + (size_t)b * 256 * DD;
    float s = 0.f;
    for (int i = 0; i < 256; ++i) s += hb[(size_t)i * DD + d];
    float mean = s / 256.0f;
    float s2 = 0.f;
    for (int i = 0; i < 256; ++i) {
        float diff = hb[(size_t)i * DD + d] - mean;
        s2 += diff * diff;
    }
    feat[d] = mean;
    feat[256 + d] = sqrtf(s2 / 255.0f) + 1e-6f;
    __syncthreads();
    if (d < 128) {
        float acc = lb[d];
        for (int k = 0; k < 512; ++k) acc += feat[k] * lw[k * 128 + d];
        out[b * 128 + d] = acc;
    }
}

extern "C" void kernel_launch(void* const* d_in, const int* in_sizes, int n_in,
                              void* d_out, int out_size, void* d_ws, size_t ws_size,
                              hipStream_t stream) {
    (void)in_sizes; (void)n_in; (void)out_size; (void)ws_size;
    const float* x     = (const float*)d_in[0];
    const float* adj   = (const float*)d_in[1];
    const float* pos   = (const float*)d_in[2];
    const float* in_w  = (const float*)d_in[3];
    const float* in_b  = (const float*)d_in[4];
    const float* pw1   = (const float*)d_in[5];
    const float* pb1   = (const float*)d_in[6];
    const float* pw2   = (const float*)d_in[7];
    const float* pb2   = (const float*)d_in[8];
    const float* bg    = (const float*)d_in[9];
    const float* bb    = (const float*)d_in[10];
    const float* bw1   = (const float*)d_in[11];
    const float* bb1   = (const float*)d_in[12];
    const float* bw2   = (const float*)d_in[13];
    const float* bb2   = (const float*)d_in[14];
    const float* beps  = (const float*)d_in[15];
    const float* poolp = (const float*)d_in[16];
    const float* lw    = (const float*)d_in[17];
    const float* lb    = (const float*)d_in[18];
    float* out = (float*)d_out;

    char* wp = (char*)d_ws;
    auto alloc = [&](size_t bytes) -> void* {
        void* p = (void*)wp;
        wp += (bytes + 255) & ~(size_t)255;
        return p;
    };
    const size_t HBYTES = (size_t)BSZ * NTOT * DD * sizeof(float);  // 8.39 MB
    float*  h    = (float*)alloc(HBYTES);
    float*  bufC = (float*)alloc(HBYTES);          // gather target
    half_t* zA   = (half_t*)alloc(HBYTES / 2);
    half_t* zB   = (half_t*)alloc(HBYTES / 2);
    half_t* Wt   = (half_t*)alloc((size_t)17 * DD * DD * sizeof(half_t));
    float* pstats  = (float*)alloc(8 * sizeof(float));
    float* pinv    = (float*)alloc(4 * sizeof(float));
    float* scores  = (float*)alloc(BSZ * NTOT * sizeof(float));
    float* gate    = (float*)alloc(BSZ * NTOT * sizeof(float));
    int*   origA   = (int*)alloc(BSZ * NTOT * sizeof(int));
    int*   origB   = (int*)alloc(BSZ * NTOT * sizeof(int));
    int*   idxl    = (int*)alloc(BSZ * NTOT * sizeof(int));
    int*   inv     = (int*)alloc(BSZ * NTOT * sizeof(int));
    int*   ldeg0   = (int*)alloc(NTOT * sizeof(int));
    int*   lcol0   = (int*)alloc((size_t)NTOT * 64 * sizeof(int));

    // ---- init: 2 dispatches ----
    setup_kernel<<<SB_MAPS, 256, 0, stream>>>(bw1, bw2, pw2, Wt, pos, pstats, poolp, pinv,
                                              adj, ldeg0, lcol0, origA, inv);
    pe_h_kernel<<<NTOT / 16, 256, 0, stream>>>(pos, pstats, pw1, pb1,
                                               Wt + (size_t)16 * DD * DD, pb2,
                                               x, in_w, in_b, h, zA);

    float* hcur = h;
    float* halt = bufC;
    half_t* zin = zA;
    half_t* zout = zB;
    int* orig = origA;
    int* orign = origB;
    int n = NTOT;
    int blk = 0;
    for (int dep = 0; dep < 4; ++dep) {
        for (int s = 0; s < 2; ++s) {
            int rows = BSZ * n;
            const half_t* W1 = Wt + (size_t)blk * DD * DD;
            const half_t* W2 = Wt + (size_t)(8 + blk) * DD * DD;
            const float* B1 = bb1 + blk * DD;
            const float* B2 = bb2 + blk * DD;
            const float* G  = bg + blk * DD;
            const float* BB = bb + blk * DD;
            int sc = (s == 1 && dep < 3) ? 1 : 0;
            if (sc) layer_kernel<1><<<rows / 16, 512, 0, stream>>>(
                hcur, zin, zout, W1, W2, B1, B2, G, BB, beps, blk,
                ldeg0, lcol0, orig, inv, poolp, pinv, scores, dep, n, dep);
            else    layer_kernel<0><<<rows / 16, 512, 0, stream>>>(
                hcur, zin, zout, W1, W2, B1, B2, G, BB, beps, blk,
                ldeg0, lcol0, orig, inv, nullptr, nullptr, nullptr, 0, n, dep);
            { half_t* t = zin; zin = zout; zout = t; }
            ++blk;
        }
        if (dep < 3) {
            int k = n / 2;
            topk_kernel<<<BSZ, 256, 0, stream>>>(scores, orig, orign, idxl, gate, n, k);
            { int* t = orig; orig = orign; orign = t; }
            gather_kernel<<<BSZ * k, 64, 0, stream>>>(hcur, idxl, gate, orig, halt, zin, inv,
                                                      n, k, dep + 1);
            { float* t = hcur; hcur = halt; halt = t; }
            n = k;
        }
    }
    // ---- readout + final ----
    readout_final_kernel<<<BSZ, 256, 0, stream>>>(hcur, lw, lb, out);
}

// Round 14
// 255.942 us; speedup vs baseline: 1.2818x; 1.0222x over previous
//
#include <hip/hip_runtime.h>
#include <hip/hip_bf16.h>

#define NTOT 2048
#define DD 256
#define BSZ 4

typedef _Float16 half_t;
typedef __attribute__((ext_vector_type(8))) _Float16 halfx8;
typedef __attribute__((ext_vector_type(4))) _Float16 halfx4;
typedef __attribute__((ext_vector_type(4))) float f32x4;

__device__ __forceinline__ f32x4 h2f(halfx4 v) {
    f32x4 r;
#pragma unroll
    for (int e = 0; e < 4; ++e) r[e] = (float)v[e];
    return r;
}
__device__ __forceinline__ halfx4 f2h(f32x4 v) {
    halfx4 r;
#pragma unroll
    for (int e = 0; e < 4; ++e) r[e] = (half_t)v[e];
    return r;
}

// ---------------- block reduce (256 threads) ----------------
__device__ __forceinline__ float blockReduceSum256(float v) {
    __shared__ float red[4];
    for (int off = 32; off > 0; off >>= 1) v += __shfl_down(v, off);
    int lane = threadIdx.x & 63, w = threadIdx.x >> 6;
    __syncthreads();
    if (lane == 0) red[w] = v;
    __syncthreads();
    return red[0] + red[1] + red[2] + red[3];
}

// inclusive scan of per-thread int across 256 threads (3 barriers)
__device__ __forceinline__ int blockScan256(int v, int* wsum) {
    int lane = threadIdx.x & 63, w = threadIdx.x >> 6;
#pragma unroll
    for (int off = 1; off < 64; off <<= 1) {
        int t = __shfl_up(v, off);
        if (lane >= off) v += t;
    }
    __syncthreads();                 // protect wsum reuse from previous call
    if (lane == 63) wsum[w] = v;
    __syncthreads();
    int add = 0;
#pragma unroll
    for (int i = 0; i < 4; ++i) add += (i < w) ? wsum[i] : 0;
    return v + add;
}

// ---------------- mega setup: wprep | stats | adj->lcol0 | maps ----------------
#define SB_WPREP 4352
#define SB_STAT  4356
#define SB_A2L   4868
#define SB_MAPS  4900
__global__ void __launch_bounds__(256) setup_kernel(
    const float* __restrict__ bw1, const float* __restrict__ bw2,
    const float* __restrict__ pw2, half_t* __restrict__ Wt,
    const float* __restrict__ pos, float* __restrict__ pstats,
    const float* __restrict__ poolp, float* __restrict__ pinv,
    const float* __restrict__ adj, int* __restrict__ ldeg0, int* __restrict__ lcol0,
    int* __restrict__ orig, int* __restrict__ inv) {
    int bid = blockIdx.x, tid = threadIdx.x;
    if (bid < SB_WPREP) {
        int m = bid >> 8, rem = bid & 255;
        int nb = (rem >> 4) * 16, kb = (rem & 15) * 16;
        const float* W = (m < 8) ? (bw1 + (size_t)m * DD * DD)
                      : (m < 16) ? (bw2 + (size_t)(m - 8) * DD * DD)
                                 : pw2;
        __shared__ float s[16][17];
        int i = tid >> 4, j = tid & 15;
        s[i][j] = W[(size_t)(kb + i) * DD + nb + j];
        __syncthreads();
        Wt[(size_t)m * DD * DD + (size_t)(nb + i) * DD + kb + j] = (half_t)s[j][i];
    } else if (bid < SB_STAT) {
        int which = bid - SB_WPREP;
        if (which == 0) {
            float s[3] = {0.f, 0.f, 0.f};
            for (int i = tid; i < NTOT; i += 256)
                for (int c = 0; c < 3; ++c) s[c] += pos[i * 3 + c];
            float m[3];
            for (int c = 0; c < 3; ++c) m[c] = blockReduceSum256(s[c]) / (float)NTOT;
            float q[3] = {0.f, 0.f, 0.f};
            for (int i = tid; i < NTOT; i += 256)
                for (int c = 0; c < 3; ++c) { float d = pos[i * 3 + c] - m[c]; q[c] += d * d; }
            for (int c = 0; c < 3; ++c) {
                float t = blockReduceSum256(q[c]);
                if (tid == 0) {
                    float var = ((float)BSZ * t) / ((float)BSZ * NTOT - 1.0f);
                    pstats[c] = m[c];
                    pstats[3 + c] = 1.0f / (sqrtf(var) + 1e-8f);
                }
            }
        } else {
            int dep = which - 1;
            float v = poolp[dep * DD + tid];
            float ss = blockReduceSum256(v * v);
            if (tid == 0) pinv[dep] = rsqrtf(ss);
        }
    } else if (bid < SB_A2L) {
        int row = (bid - SB_STAT) * 4 + (tid >> 6);
        int lane = tid & 63;
        int run = 0;
        for (int j0 = 0; j0 < NTOT; j0 += 64) {
            int j = j0 + lane;
            bool pred = adj[(size_t)row * NTOT + j] != 0.f;
            unsigned long long mask = __ballot(pred);
            if (pred) {
                int pos2 = run + __popcll(mask & ((1ull << lane) - 1ull));
                if (pos2 < 64) lcol0[row * 64 + pos2] = j;
            }
            run += __popcll(mask);
        }
        if (lane == 0) ldeg0[row] = run < 64 ? run : 64;
    } else {
        int t = (bid - SB_A2L) * 256 + tid;  // B*NTOT
        int i = t & (NTOT - 1);
        orig[t] = i; inv[t] = i;  // tag 0
    }
}

// ---------------- fused pe + input projection + h/z init (z -> f16) ----------------
__global__ void __launch_bounds__(256) pe_h_kernel(
    const float* __restrict__ pos, const float* __restrict__ pstats,
    const float* __restrict__ pw1, const float* __restrict__ pb1,
    const half_t* __restrict__ Wt16, const float* __restrict__ pb2,
    const float* __restrict__ x, const float* __restrict__ in_w,
    const float* __restrict__ in_b, float* __restrict__ h, half_t* __restrict__ z) {
    __shared__ half_t tb[16][264];
    __shared__ float iw[16][DD];
    __shared__ float xs[16][16];
    __shared__ float part[4][16][2];
    __shared__ float mrs[16][2];
    int tid = threadIdx.x;
    int i0 = blockIdx.x * 16;
    {
        int rl = tid >> 4, cb = (tid & 15) * 16;
        float pn[3];
#pragma unroll
        for (int c = 0; c < 3; ++c)
            pn[c] = (pos[(i0 + rl) * 3 + c] - pstats[c]) * pstats[3 + c];
#pragma unroll
        for (int u = 0; u < 16; ++u) {
            int d = cb + u;
            float a = pb1[d];
            a += pn[0] * pw1[d];
            a += pn[1] * pw1[DD + d];
            a += pn[2] * pw1[2 * DD + d];
            a = a / (1.0f + expf(-a));
            tb[rl][d] = (half_t)a;
        }
        int k = tid >> 4;
#pragma unroll
        for (int u = 0; u < 16; ++u) iw[k][cb + u] = in_w[k * DD + cb + u];
    }
    __syncthreads();
    int w = tid >> 6, l = tid & 63;
    int lo = l & 15, hi = l >> 4;
    int kb = hi * 8;
    float pe_r[4][4];
    {
        f32x4 acc[4] = {};
#pragma unroll
        for (int k0 = 0; k0 < DD; k0 += 32) {
            halfx8 a0 = *(const halfx8*)&tb[lo][kb + k0];
#pragma unroll
            for (int j = 0; j < 4; ++j) {
                halfx8 bj = *(const halfx8*)(Wt16 + (size_t)(w * 64 + j * 16 + lo) * DD + kb + k0);
                acc[j] = __builtin_amdgcn_mfma_f32_16x16x32_f16(a0, bj, acc[j], 0, 0, 0);
            }
        }
#pragma unroll
        for (int j = 0; j < 4; ++j) {
            float bs = pb2[w * 64 + j * 16 + lo];
#pragma unroll
            for (int q = 0; q < 4; ++q) pe_r[j][q] = acc[j][q] + bs;
        }
    }
    float xb[4];
#pragma unroll
    for (int j = 0; j < 4; ++j) xb[j] = in_b[w * 64 + j * 16 + lo];
    for (int b = 0; b < BSZ; ++b) {
        __syncthreads();
        xs[tid >> 4][tid & 15] = x[(size_t)(b * NTOT + i0 + (tid >> 4)) * 16 + (tid & 15)];
        __syncthreads();
        float vh[4][4];
#pragma unroll
        for (int q = 0; q < 4; ++q) {
            int rl = hi * 4 + q;
            float s = 0.f, ss = 0.f;
#pragma unroll
            for (int j = 0; j < 4; ++j) {
                int c = w * 64 + j * 16 + lo;
                float acc = xb[j];
#pragma unroll
                for (int k = 0; k < 16; ++k) acc += xs[rl][k] * iw[k][c];
                float v = acc + pe_r[j][q];
                vh[j][q] = v;
                s += v; ss += v * v;
            }
#pragma unroll
            for (int m = 1; m < 16; m <<= 1) { s += __shfl_xor(s, m); ss += __shfl_xor(ss, m); }
            if (lo == 0) { part[w][rl][0] = s; part[w][rl][1] = ss; }
        }
        __syncthreads();
        if (tid < 16) {
            float s = 0.f, ss = 0.f;
#pragma unroll
            for (int w2 = 0; w2 < 4; ++w2) { s += part[w2][tid][0]; ss += part[w2][tid][1]; }
            float mean = s * (1.0f / DD);
            float var = ss * (1.0f / DD) - mean * mean;
            mrs[tid][0] = mean;
            mrs[tid][1] = rsqrtf(var + 1e-5f);
        }
        __syncthreads();
#pragma unroll
        for (int q = 0; q < 4; ++q) {
            int rl = hi * 4 + q;
            size_t r = (size_t)(b * NTOT + i0 + rl);
            float mean = mrs[rl][0], rs = mrs[rl][1];
#pragma unroll
            for (int j = 0; j < 4; ++j) {
                int c = w * 64 + j * 16 + lo;
                float v = vh[j][q];
                h[r * DD + c] = v;
                z[r * DD + c] = (half_t)((v - mean) * rs);
            }
        }
    }
}

// ---------------- fused layer, 16 rows/block, NWAVES waves, XCD-swizzled ----------------
// wave w owns cols [W*w, W*w+W), W = 256/NWAVES. Phase A: TPR thr/row.
template <int NWAVES, int SCORE>
__global__ void __launch_bounds__(NWAVES * 64) layer_kernel(
    float* __restrict__ h, const half_t* __restrict__ zin, half_t* __restrict__ zout,
    const half_t* __restrict__ Wt1, const half_t* __restrict__ Wt2,
    const float* __restrict__ b1v, const float* __restrict__ b2v,
    const float* __restrict__ gv, const float* __restrict__ bbv,
    const float* __restrict__ beps, int blk,
    const int* __restrict__ ldeg0, const int* __restrict__ lcol0,
    const int* __restrict__ orig, const int* __restrict__ inv,
    const float* __restrict__ poolp, const float* __restrict__ pinv_all,
    float* __restrict__ scores, int dep, int n, int tag) {
    constexpr int W = 256 / NWAVES;    // cols per wave
    constexpr int JL = W / 16;         // MFMA col-frags per wave
    constexpr int TPR = (NWAVES * 64) / 16;  // threads per row in phase A
    constexpr int CH = 64 / TPR;       // halfx4 chunks per thread
    __shared__ half_t tb[16][264];
    __shared__ half_t ub[16][264];
    __shared__ float part[NWAVES][16][3];
    __shared__ float mrs[16][2];
    int tid = threadIdx.x;
    int bid = blockIdx.x;
    int xcd = bid & 7;
    int batch = xcd >> 1;
    int within = ((bid >> 3) << 1) | (xcd & 1);
    int rowBase = batch * n + within * 16;
    float eps1 = 1.0f + beps[blk];

    // ---- phase A: aggregation -> LDS tb (f16) ----
    {
        int rl = tid / TPR, cg = tid % TPR;
        int r = rowBase + rl;
        int b = r / n, i = r - b * n;
        const halfx4* zb = (const halfx4*)zin + (size_t)b * n * 64;
        f32x4 acc[CH];
#pragma unroll
        for (int u = 0; u < CH; ++u) acc[u] = h2f(zb[(size_t)i * 64 + cg + TPR * u]) * eps1;
        int cnt = 0;
        if (tag == 0) {
            int deg = ldeg0[i];
            const int* lc = lcol0 + i * 64;
            int p = 0;
            for (; p + 4 <= deg; p += 4) {
                int j0 = lc[p], j1 = lc[p + 1], j2 = lc[p + 2], j3 = lc[p + 3];
#pragma unroll
                for (int u = 0; u < CH; ++u) {
                    f32x4 v0 = h2f(zb[(size_t)j0 * 64 + cg + TPR * u]);
                    f32x4 v1 = h2f(zb[(size_t)j1 * 64 + cg + TPR * u]);
                    f32x4 v2 = h2f(zb[(size_t)j2 * 64 + cg + TPR * u]);
                    f32x4 v3 = h2f(zb[(size_t)j3 * 64 + cg + TPR * u]);
                    acc[u] += (v0 + v1) + (v2 + v3);
                }
            }
            for (; p < deg; ++p) {
                int j = lc[p];
#pragma unroll
                for (int u = 0; u < CH; ++u) acc[u] += h2f(zb[(size_t)j * 64 + cg + TPR * u]);
            }
            cnt = deg;
        } else {
            int o = orig[b * NTOT + i];
            int deg = ldeg0[o];
            const int* lc = lcol0 + o * 64;
            const int* invb = inv + b * NTOT;
            int p = 0;
            for (; p + 4 <= deg; p += 4) {
                int v0 = invb[lc[p]], v1 = invb[lc[p + 1]];
                int v2 = invb[lc[p + 2]], v3 = invb[lc[p + 3]];
                if ((v0 >> 12) == tag) {
                    int j = v0 & 4095; ++cnt;
#pragma unroll
                    for (int u = 0; u < CH; ++u) acc[u] += h2f(zb[(size_t)j * 64 + cg + TPR * u]);
                }
                if ((v1 >> 12) == tag) {
                    int j = v1 & 4095; ++cnt;
#pragma unroll
                    for (int u = 0; u < CH; ++u) acc[u] += h2f(zb[(size_t)j * 64 + cg + TPR * u]);
                }
                if ((v2 >> 12) == tag) {
                    int j = v2 & 4095; ++cnt;
#pragma unroll
                    for (int u = 0; u < CH; ++u) acc[u] += h2f(zb[(size_t)j * 64 + cg + TPR * u]);
                }
                if ((v3 >> 12) == tag) {
                    int j = v3 & 4095; ++cnt;
#pragma unroll
                    for (int u = 0; u < CH; ++u) acc[u] += h2f(zb[(size_t)j * 64 + cg + TPR * u]);
                }
            }
            for (; p < deg; ++p) {
                int v = invb[lc[p]];
                if ((v >> 12) == tag) {
                    int j = v & 4095; ++cnt;
#pragma unroll
                    for (int u = 0; u < CH; ++u) acc[u] += h2f(zb[(size_t)j * 64 + cg + TPR * u]);
                }
            }
        }
        float coefb = eps1 + (float)cnt;
#pragma unroll
        for (int u = 0; u < CH; ++u) {
            int c4 = cg + TPR * u;
            f32x4 gvv = ((const f32x4*)gv)[c4];
            f32x4 bvv = ((const f32x4*)bbv)[c4];
            f32x4 tv = gvv * acc[u] + bvv * coefb;
            *(halfx4*)&tb[rl][c4 * 4] = f2h(tv);
        }
    }
    __syncthreads();

    int w = tid >> 6, l = tid & 63;
    int lo = l & 15, hi = l >> 4;
    int kb = hi * 8;

    // ---- phase B: mm1 + silu -> ub ----
    {
        f32x4 acc[JL] = {};
#pragma unroll
        for (int k0 = 0; k0 < DD; k0 += 32) {
            halfx8 a0 = *(const halfx8*)&tb[lo][kb + k0];
#pragma unroll
            for (int j = 0; j < JL; ++j) {
                halfx8 bj = *(const halfx8*)(Wt1 + (size_t)(w * W + j * 16 + lo) * DD + kb + k0);
                acc[j] = __builtin_amdgcn_mfma_f32_16x16x32_f16(a0, bj, acc[j], 0, 0, 0);
            }
        }
        float bs[JL];
#pragma unroll
        for (int j = 0; j < JL; ++j) bs[j] = b1v[w * W + j * 16 + lo];
#pragma unroll
        for (int q = 0; q < 4; ++q)
#pragma unroll
            for (int j = 0; j < JL; ++j) {
                float v = acc[j][q] + bs[j];
                v = v / (1.0f + expf(-v));
                ub[hi * 4 + q][w * W + j * 16 + lo] = (half_t)v;
            }
    }
    __syncthreads();

    // ---- phase C: mm2 + residual + stats (+score) + z ----
    {
        f32x4 acc[JL] = {};
#pragma unroll
        for (int k0 = 0; k0 < DD; k0 += 32) {
            halfx8 a0 = *(const halfx8*)&ub[lo][kb + k0];
#pragma unroll
            for (int j = 0; j < JL; ++j) {
                halfx8 bj = *(const halfx8*)(Wt2 + (size_t)(w * W + j * 16 + lo) * DD + kb + k0);
                acc[j] = __builtin_amdgcn_mfma_f32_16x16x32_f16(a0, bj, acc[j], 0, 0, 0);
            }
        }
        float bs[JL], pv[JL];
#pragma unroll
        for (int j = 0; j < JL; ++j) { bs[j] = b2v[w * W + j * 16 + lo]; pv[j] = 0.f; }
        if (SCORE) {
#pragma unroll
            for (int j = 0; j < JL; ++j) pv[j] = poolp[dep * DD + w * W + j * 16 + lo];
        }
        float vh[JL][4];
#pragma unroll
        for (int q = 0; q < 4; ++q) {
            int r = rowBase + hi * 4 + q;
            float s = 0.f, ss = 0.f, sp = 0.f;
#pragma unroll
            for (int j = 0; j < JL; ++j) {
                int c = w * W + j * 16 + lo;
                float v = h[(size_t)r * DD + c] + acc[j][q] + bs[j];
                vh[j][q] = v;
                s += v; ss += v * v;
                if (SCORE) sp += v * pv[j];
            }
#pragma unroll
            for (int m = 1; m < 16; m <<= 1) {
                s += __shfl_xor(s, m); ss += __shfl_xor(ss, m);
                if (SCORE) sp += __shfl_xor(sp, m);
            }
            if (lo == 0) {
                int rl = hi * 4 + q;
                part[w][rl][0] = s; part[w][rl][1] = ss;
                if (SCORE) part[w][rl][2] = sp;
            }
        }
        __syncthreads();
        if (tid < 16) {
            float s = 0.f, ss = 0.f, sp = 0.f;
#pragma unroll
            for (int w2 = 0; w2 < NWAVES; ++w2) {
                s += part[w2][tid][0]; ss += part[w2][tid][1];
                if (SCORE) sp += part[w2][tid][2];
            }
            float mean = s * (1.0f / DD);
            float var = ss * (1.0f / DD) - mean * mean;
            mrs[tid][0] = mean;
            mrs[tid][1] = rsqrtf(var + 1e-5f);
            if (SCORE) {
                int r = rowBase + tid;
                int b2 = r / n, ii = r - b2 * n;
                scores[b2 * NTOT + ii] = sp * pinv_all[dep];
            }
        }
        __syncthreads();
#pragma unroll
        for (int q = 0; q < 4; ++q) {
            int rl = hi * 4 + q;
            int r = rowBase + rl;
            float mean = mrs[rl][0], rs = mrs[rl][1];
#pragma unroll
            for (int j = 0; j < JL; ++j) {
                int c = w * W + j * 16 + lo;
                float v = vh[j][q];
                h[(size_t)r * DD + c] = v;
                zout[(size_t)r * DD + c] = (half_t)((v - mean) * rs);
            }
        }
    }
}

// ---------------- pooling: 1-pass radix + candidate rank; wave-scan based ----------------
__global__ void topk_kernel(const float* __restrict__ scores, const int* __restrict__ orig_cur,
                            int* __restrict__ orig_next, int* __restrict__ idx_local,
                            float* __restrict__ gate, int n, int k) {
    __shared__ unsigned keys[2048];
    __shared__ int hist[256];
    __shared__ int wsum[4];
    __shared__ int sh_bucket, sh_r, sh_cnt, sh_tot;
    __shared__ unsigned cand[256];
    __shared__ unsigned sh_thr;
    int b = blockIdx.x;
    const float* sc = scores + b * NTOT;
    int tid = threadIdx.x;
    for (int i = tid; i < n; i += 256) {
        unsigned u = __float_as_uint(sc[i]);
        keys[i] = (u & 0x80000000u) ? ~u : (u | 0x80000000u);
    }
    hist[tid] = 0;
    if (tid == 0) sh_cnt = 0;
    __syncthreads();
    for (int i = tid; i < n; i += 256) atomicAdd(&hist[keys[i] >> 24], 1);
    __syncthreads();
    int cnt = hist[tid];
    int incl = blockScan256(cnt, wsum);
    int r = n - k;  // 0-indexed rank ascending
    int excl = incl - cnt;
    if (excl <= r && r < incl) { sh_bucket = tid; sh_r = r - excl; }
    __syncthreads();
    int b1 = sh_bucket, r1 = sh_r;
    int c = hist[b1];
    unsigned thrkey;
    if (c <= 256) {
        for (int i = tid; i < n; i += 256) {
            unsigned key = keys[i];
            if ((key >> 24) == (unsigned)b1) {
                int pos = atomicAdd(&sh_cnt, 1);
                cand[pos] = key;
            }
        }
        __syncthreads();
        if (tid < c) {
            unsigned mine = cand[tid];
            int less = 0, eq = 0;
            for (int j = 0; j < c; ++j) {
                unsigned oth = cand[j];
                less += (oth < mine); eq += (oth == mine);
            }
            if (less <= r1 && r1 < less + eq) sh_thr = mine;
        }
        __syncthreads();
        thrkey = sh_thr;
    } else {
        unsigned prefix = ((unsigned)b1) << 24;
        int rr = r1;
        for (int shift = 16; shift >= 0; shift -= 8) {
            __syncthreads();
            hist[tid] = 0;
            __syncthreads();
            unsigned mask = 0xFFFFFFFFu << (shift + 8);
            for (int i = tid; i < n; i += 256) {
                unsigned key = keys[i];
                if ((key & mask) == (prefix & mask)) atomicAdd(&hist[(key >> shift) & 255], 1);
            }
            __syncthreads();
            int cnt2 = hist[tid];
            int incl2 = blockScan256(cnt2, wsum);
            int excl2 = incl2 - cnt2;
            if (excl2 <= rr && rr < incl2) { sh_bucket = tid; sh_r = rr - excl2; }
            __syncthreads();
            prefix |= ((unsigned)sh_bucket) << shift;
            rr = sh_r;
            __syncthreads();
        }
        thrkey = prefix;
    }
    unsigned uthr = (thrkey & 0x80000000u) ? (thrkey ^ 0x80000000u) : ~thrkey;
    float thr = __uint_as_float(uthr);  // exact k-th largest value
    // tie-aware stable compaction via single packed scan (cgt*4096 + ceq)
    int chunk = n / 256;
    int base = tid * chunk;
    int cgt = 0, ceq = 0;
    for (int u = 0; u < chunk; ++u) {
        float s = sc[base + u];
        cgt += (s > thr); ceq += (s == thr);
    }
    int packed = (cgt << 12) | ceq;
    int pincl = blockScan256(packed, wsum);
    if (tid == 255) sh_tot = pincl;
    __syncthreads();
    int total_gt = sh_tot >> 12;
    int ties = k - total_gt;
    int pexcl = pincl - packed;
    int gtb = pexcl >> 12, eqb = pexcl & 4095;
    for (int u = 0; u < chunk; ++u) {
        int i = base + u;
        float s = sc[i];
        bool isgt = (s > thr), iseq = (s == thr);
        bool keep = isgt || (iseq && eqb < ties);
        if (keep) {
            int pos = gtb + (eqb < ties ? eqb : ties);
            idx_local[b * NTOT + pos] = i;
            gate[b * NTOT + pos] = tanhf(s);
            orig_next[b * NTOT + pos] = orig_cur[b * NTOT + i];
        }
        gtb += isgt; eqb += iseq;
    }
}

// gather gated rows, recompute stats, write z (f16), set inverse map (XCD-swizzled)
__global__ void __launch_bounds__(64) gather_kernel(
    const float* __restrict__ h, const int* __restrict__ idx_local,
    const float* __restrict__ gate, const int* __restrict__ orig_new,
    float* __restrict__ hout, half_t* __restrict__ zout, int* __restrict__ inv,
    int n_old, int k, int tag) {
    int bid = blockIdx.x;
    int xcd = bid & 7;
    int b = xcd >> 1;
    int rr = ((bid >> 3) << 1) | (xcd & 1);  // [0, k)
    int r = b * k + rr;
    int lane = threadIdx.x;
    int src = idx_local[b * NTOT + rr];
    float gg = gate[b * NTOT + rr];
    f32x4 v = ((const f32x4*)h)[(size_t)(b * n_old + src) * 64 + lane] * gg;
    ((f32x4*)hout)[(size_t)r * 64 + lane] = v;
    float s = v[0] + v[1] + v[2] + v[3];
    float ss = v[0] * v[0] + v[1] * v[1] + v[2] * v[2] + v[3] * v[3];
#pragma unroll
    for (int m = 1; m < 64; m <<= 1) { s += __shfl_xor(s, m); ss += __shfl_xor(ss, m); }
    float mean = s * (1.0f / DD);
    float rs = rsqrtf(ss * (1.0f / DD) - mean * mean + 1e-5f);
    ((halfx4*)zout)[(size_t)r * 64 + lane] = f2h((v - mean) * rs);
    if (lane == 0) inv[b * NTOT + orig_new[b * NTOT + rr]] = (tag << 12) | rr;
}

// ---------------- fused readout + final projection (4 blocks) ----------------
__global__ void __launch_bounds__(256) readout_final_kernel(
    const float* __restrict__ h, const float* __restrict__ lw,
    const float* __restrict__ lb, float* __restrict__ out) {
    __shared__ float feat[512];
    int b = blockIdx.x, d = threadIdx.x;
    const float* hb = h + (size_t)b * 256 * DD;
    float s = 0.f;
    for (int i = 0; i < 256; ++i) s += hb[(size_t)i * DD + d];
    float mean = s / 256.0f;
    float s2 = 0.f;
    for (int i = 0; i < 256; ++i) {
        float diff = hb[(size_t)i * DD + d] - mean;
        s2 += diff * diff;
    }
    feat[d] = mean;
    feat[256 + d] = sqrtf(s2 / 255.0f) + 1e-6f;
    __syncthreads();
    if (d < 128) {
        float acc = lb[d];
        for (int k = 0; k < 512; ++k) acc += feat[k] * lw[k * 128 + d];
        out[b * 128 + d] = acc;
    }
}

extern "C" void kernel_launch(void* const* d_in, const int* in_sizes, int n_in,
                              void* d_out, int out_size, void* d_ws, size_t ws_size,
                              hipStream_t stream) {
    (void)in_sizes; (void)n_in; (void)out_size; (void)ws_size;
    const float* x     = (const float*)d_in[0];
    const float* adj   = (const float*)d_in[1];
    const float* pos   = (const float*)d_in[2];
    const float* in_w  = (const float*)d_in[3];
    const float* in_b  = (const float*)d_in[4];
    const float* pw1   = (const float*)d_in[5];
    const float* pb1   = (const float*)d_in[6];
    const float* pw2   = (const float*)d_in[7];
    const float* pb2   = (const float*)d_in[8];
    const float* bg    = (const float*)d_in[9];
    const float* bb    = (const float*)d_in[10];
    const float* bw1   = (const float*)d_in[11];
    const float* bb1   = (const float*)d_in[12];
    const float* bw2   = (const float*)d_in[13];
    const float* bb2   = (const float*)d_in[14];
    const float* beps  = (const float*)d_in[15];
    const float* poolp = (const float*)d_in[16];
    const float* lw    = (const float*)d_in[17];
    const float* lb    = (const float*)d_in[18];
    float* out = (float*)d_out;

    char* wp = (char*)d_ws;
    auto alloc = [&](size_t bytes) -> void* {
        void* p = (void*)wp;
        wp += (bytes + 255) & ~(size_t)255;
        return p;
    };
    const size_t HBYTES = (size_t)BSZ * NTOT * DD * sizeof(float);  // 8.39 MB
    float*  h    = (float*)alloc(HBYTES);
    float*  bufC = (float*)alloc(HBYTES);          // gather target
    half_t* zA   = (half_t*)alloc(HBYTES / 2);
    half_t* zB   = (half_t*)alloc(HBYTES / 2);
    half_t* Wt   = (half_t*)alloc((size_t)17 * DD * DD * sizeof(half_t));
    float* pstats  = (float*)alloc(8 * sizeof(float));
    float* pinv    = (float*)alloc(4 * sizeof(float));
    float* scores  = (float*)alloc(BSZ * NTOT * sizeof(float));
    float* gate    = (float*)alloc(BSZ * NTOT * sizeof(float));
    int*   origA   = (int*)alloc(BSZ * NTOT * sizeof(int));
    int*   origB   = (int*)alloc(BSZ * NTOT * sizeof(int));
    int*   idxl    = (int*)alloc(BSZ * NTOT * sizeof(int));
    int*   inv     = (int*)alloc(BSZ * NTOT * sizeof(int));
    int*   ldeg0   = (int*)alloc(NTOT * sizeof(int));
    int*   lcol0   = (int*)alloc((size_t)NTOT * 64 * sizeof(int));

    // ---- init: 2 dispatches ----
    setup_kernel<<<SB_MAPS, 256, 0, stream>>>(bw1, bw2, pw2, Wt, pos, pstats, poolp, pinv,
                                              adj, ldeg0, lcol0, origA, inv);
    pe_h_kernel<<<NTOT / 16, 256, 0, stream>>>(pos, pstats, pw1, pb1,
                                               Wt + (size_t)16 * DD * DD, pb2,
                                               x, in_w, in_b, h, zA);

    float* hcur = h;
    float* halt = bufC;
    half_t* zin = zA;
    half_t* zout = zB;
    int* orig = origA;
    int* orign = origB;
    int n = NTOT;
    int blk = 0;
    for (int dep = 0; dep < 4; ++dep) {
        for (int s = 0; s < 2; ++s) {
            int rows = BSZ * n;
            const half_t* W1 = Wt + (size_t)blk * DD * DD;
            const half_t* W2 = Wt + (size_t)(8 + blk) * DD * DD;
            const float* B1 = bb1 + blk * DD;
            const float* B2 = bb2 + blk * DD;
            const float* G  = bg + blk * DD;
            const float* BB = bb + blk * DD;
            int sc = (s == 1 && dep < 3) ? 1 : 0;
            if (dep < 2) {
                if (sc) layer_kernel<16, 1><<<rows / 16, 1024, 0, stream>>>(
                    hcur, zin, zout, W1, W2, B1, B2, G, BB, beps, blk,
                    ldeg0, lcol0, orig, inv, poolp, pinv, scores, dep, n, dep);
                else    layer_kernel<16, 0><<<rows / 16, 1024, 0, stream>>>(
                    hcur, zin, zout, W1, W2, B1, B2, G, BB, beps, blk,
                    ldeg0, lcol0, orig, inv, nullptr, nullptr, nullptr, 0, n, dep);
            } else {
                if (sc) layer_kernel<8, 1><<<rows / 16, 512, 0, stream>>>(
                    hcur, zin, zout, W1, W2, B1, B2, G, BB, beps, blk,
                    ldeg0, lcol0, orig, inv, poolp, pinv, scores, dep, n, dep);
                else    layer_kernel<8, 0><<<rows / 16, 512, 0, stream>>>(
                    hcur, zin, zout, W1, W2, B1, B2, G, BB, beps, blk,
                    ldeg0, lcol0, orig, inv, nullptr, nullptr, nullptr, 0, n, dep);
            }
            { half_t* t = zin; zin = zout; zout = t; }
            ++blk;
        }
        if (dep < 3) {
            int k = n / 2;
            topk_kernel<<<BSZ, 256, 0, stream>>>(scores, orig, orign, idxl, gate, n, k);
            { int* t = orig; orig = orign; orign = t; }
            gather_kernel<<<BSZ * k, 64, 0, stream>>>(hcur, idxl, gate, orig, halt, zin, inv,
                                                      n, k, dep + 1);
            { float* t = hcur; hcur = halt; halt = t; }
            n = k;
        }
    }
    // ---- readout + final ----
    readout_final_kernel<<<BSZ, 256, 0, stream>>>(hcur, lw, lb, out);
}

// Round 15
// 246.604 us; speedup vs baseline: 1.3304x; 1.0379x over previous
//
#include <hip/hip_runtime.h>
#include <hip/hip_bf16.h>

#define NTOT 2048
#define DD 256
#define BSZ 4

typedef _Float16 half_t;
typedef __attribute__((ext_vector_type(8))) _Float16 halfx8;
typedef __attribute__((ext_vector_type(4))) _Float16 halfx4;
typedef __attribute__((ext_vector_type(4))) float f32x4;

__device__ __forceinline__ f32x4 h2f(halfx4 v) {
    f32x4 r;
#pragma unroll
    for (int e = 0; e < 4; ++e) r[e] = (float)v[e];
    return r;
}
__device__ __forceinline__ halfx4 f2h(f32x4 v) {
    halfx4 r;
#pragma unroll
    for (int e = 0; e < 4; ++e) r[e] = (half_t)v[e];
    return r;
}

// ---------------- block reduce (256 threads) ----------------
__device__ __forceinline__ float blockReduceSum256(float v) {
    __shared__ float red[4];
    for (int off = 32; off > 0; off >>= 1) v += __shfl_down(v, off);
    int lane = threadIdx.x & 63, w = threadIdx.x >> 6;
    __syncthreads();
    if (lane == 0) red[w] = v;
    __syncthreads();
    return red[0] + red[1] + red[2] + red[3];
}

// inclusive scan of per-thread int across 256 threads (3 barriers)
__device__ __forceinline__ int blockScan256(int v, int* wsum) {
    int lane = threadIdx.x & 63, w = threadIdx.x >> 6;
#pragma unroll
    for (int off = 1; off < 64; off <<= 1) {
        int t = __shfl_up(v, off);
        if (lane >= off) v += t;
    }
    __syncthreads();                 // protect wsum reuse from previous call
    if (lane == 63) wsum[w] = v;
    __syncthreads();
    int add = 0;
#pragma unroll
    for (int i = 0; i < 4; ++i) add += (i < w) ? wsum[i] : 0;
    return v + add;
}

// ---------------- mega setup: wprep | stats | adj->lcol0 | maps ----------------
#define SB_WPREP 4352
#define SB_STAT  4356
#define SB_A2L   4868
#define SB_MAPS  4900
__global__ void __launch_bounds__(256) setup_kernel(
    const float* __restrict__ bw1, const float* __restrict__ bw2,
    const float* __restrict__ pw2, half_t* __restrict__ Wt,
    const float* __restrict__ pos, float* __restrict__ pstats,
    const float* __restrict__ poolp, float* __restrict__ pinv,
    const float* __restrict__ adj, int* __restrict__ ldeg0, int* __restrict__ lcol0,
    int* __restrict__ orig, int* __restrict__ inv) {
    int bid = blockIdx.x, tid = threadIdx.x;
    if (bid < SB_WPREP) {
        int m = bid >> 8, rem = bid & 255;
        int nb = (rem >> 4) * 16, kb = (rem & 15) * 16;
        const float* W = (m < 8) ? (bw1 + (size_t)m * DD * DD)
                      : (m < 16) ? (bw2 + (size_t)(m - 8) * DD * DD)
                                 : pw2;
        __shared__ float s[16][17];
        int i = tid >> 4, j = tid & 15;
        s[i][j] = W[(size_t)(kb + i) * DD + nb + j];
        __syncthreads();
        Wt[(size_t)m * DD * DD + (size_t)(nb + i) * DD + kb + j] = (half_t)s[j][i];
    } else if (bid < SB_STAT) {
        int which = bid - SB_WPREP;
        if (which == 0) {
            float s[3] = {0.f, 0.f, 0.f};
            for (int i = tid; i < NTOT; i += 256)
                for (int c = 0; c < 3; ++c) s[c] += pos[i * 3 + c];
            float m[3];
            for (int c = 0; c < 3; ++c) m[c] = blockReduceSum256(s[c]) / (float)NTOT;
            float q[3] = {0.f, 0.f, 0.f};
            for (int i = tid; i < NTOT; i += 256)
                for (int c = 0; c < 3; ++c) { float d = pos[i * 3 + c] - m[c]; q[c] += d * d; }
            for (int c = 0; c < 3; ++c) {
                float t = blockReduceSum256(q[c]);
                if (tid == 0) {
                    float var = ((float)BSZ * t) / ((float)BSZ * NTOT - 1.0f);
                    pstats[c] = m[c];
                    pstats[3 + c] = 1.0f / (sqrtf(var) + 1e-8f);
                }
            }
        } else {
            int dep = which - 1;
            float v = poolp[dep * DD + tid];
            float ss = blockReduceSum256(v * v);
            if (tid == 0) pinv[dep] = rsqrtf(ss);
        }
    } else if (bid < SB_A2L) {
        int row = (bid - SB_STAT) * 4 + (tid >> 6);
        int lane = tid & 63;
        int run = 0;
        for (int j0 = 0; j0 < NTOT; j0 += 64) {
            int j = j0 + lane;
            bool pred = adj[(size_t)row * NTOT + j] != 0.f;
            unsigned long long mask = __ballot(pred);
            if (pred) {
                int pos2 = run + __popcll(mask & ((1ull << lane) - 1ull));
                if (pos2 < 64) lcol0[row * 64 + pos2] = j;
            }
            run += __popcll(mask);
        }
        if (lane == 0) ldeg0[row] = run < 64 ? run : 64;
    } else {
        int t = (bid - SB_A2L) * 256 + tid;  // B*NTOT
        int i = t & (NTOT - 1);
        orig[t] = i; inv[t] = i;  // tag 0
    }
}

// ---------------- fused pe + input projection + h/z init (z -> f16) ----------------
__global__ void __launch_bounds__(256) pe_h_kernel(
    const float* __restrict__ pos, const float* __restrict__ pstats,
    const float* __restrict__ pw1, const float* __restrict__ pb1,
    const half_t* __restrict__ Wt16, const float* __restrict__ pb2,
    const float* __restrict__ x, const float* __restrict__ in_w,
    const float* __restrict__ in_b, float* __restrict__ h, half_t* __restrict__ z) {
    __shared__ half_t tb[16][264];
    __shared__ float iw[16][DD];
    __shared__ float xs[16][16];
    __shared__ float part[4][16][2];
    __shared__ float mrs[16][2];
    int tid = threadIdx.x;
    int i0 = blockIdx.x * 16;
    {
        int rl = tid >> 4, cb = (tid & 15) * 16;
        float pn[3];
#pragma unroll
        for (int c = 0; c < 3; ++c)
            pn[c] = (pos[(i0 + rl) * 3 + c] - pstats[c]) * pstats[3 + c];
#pragma unroll
        for (int u = 0; u < 16; ++u) {
            int d = cb + u;
            float a = pb1[d];
            a += pn[0] * pw1[d];
            a += pn[1] * pw1[DD + d];
            a += pn[2] * pw1[2 * DD + d];
            a = a / (1.0f + expf(-a));
            tb[rl][d] = (half_t)a;
        }
        int k = tid >> 4;
#pragma unroll
        for (int u = 0; u < 16; ++u) iw[k][cb + u] = in_w[k * DD + cb + u];
    }
    __syncthreads();
    int w = tid >> 6, l = tid & 63;
    int lo = l & 15, hi = l >> 4;
    int kb = hi * 8;
    float pe_r[4][4];
    {
        f32x4 acc[4] = {};
#pragma unroll
        for (int k0 = 0; k0 < DD; k0 += 32) {
            halfx8 a0 = *(const halfx8*)&tb[lo][kb + k0];
#pragma unroll
            for (int j = 0; j < 4; ++j) {
                halfx8 bj = *(const halfx8*)(Wt16 + (size_t)(w * 64 + j * 16 + lo) * DD + kb + k0);
                acc[j] = __builtin_amdgcn_mfma_f32_16x16x32_f16(a0, bj, acc[j], 0, 0, 0);
            }
        }
#pragma unroll
        for (int j = 0; j < 4; ++j) {
            float bs = pb2[w * 64 + j * 16 + lo];
#pragma unroll
            for (int q = 0; q < 4; ++q) pe_r[j][q] = acc[j][q] + bs;
        }
    }
    float xb[4];
#pragma unroll
    for (int j = 0; j < 4; ++j) xb[j] = in_b[w * 64 + j * 16 + lo];
    for (int b = 0; b < BSZ; ++b) {
        __syncthreads();
        xs[tid >> 4][tid & 15] = x[(size_t)(b * NTOT + i0 + (tid >> 4)) * 16 + (tid & 15)];
        __syncthreads();
        float vh[4][4];
#pragma unroll
        for (int q = 0; q < 4; ++q) {
            int rl = hi * 4 + q;
            float s = 0.f, ss = 0.f;
#pragma unroll
            for (int j = 0; j < 4; ++j) {
                int c = w * 64 + j * 16 + lo;
                float acc = xb[j];
#pragma unroll
                for (int k = 0; k < 16; ++k) acc += xs[rl][k] * iw[k][c];
                float v = acc + pe_r[j][q];
                vh[j][q] = v;
                s += v; ss += v * v;
            }
#pragma unroll
            for (int m = 1; m < 16; m <<= 1) { s += __shfl_xor(s, m); ss += __shfl_xor(ss, m); }
            if (lo == 0) { part[w][rl][0] = s; part[w][rl][1] = ss; }
        }
        __syncthreads();
        if (tid < 16) {
            float s = 0.f, ss = 0.f;
#pragma unroll
            for (int w2 = 0; w2 < 4; ++w2) { s += part[w2][tid][0]; ss += part[w2][tid][1]; }
            float mean = s * (1.0f / DD);
            float var = ss * (1.0f / DD) - mean * mean;
            mrs[tid][0] = mean;
            mrs[tid][1] = rsqrtf(var + 1e-5f);
        }
        __syncthreads();
#pragma unroll
        for (int q = 0; q < 4; ++q) {
            int rl = hi * 4 + q;
            size_t r = (size_t)(b * NTOT + i0 + rl);
            float mean = mrs[rl][0], rs = mrs[rl][1];
#pragma unroll
            for (int j = 0; j < 4; ++j) {
                int c = w * 64 + j * 16 + lo;
                float v = vh[j][q];
                h[r * DD + c] = v;
                z[r * DD + c] = (half_t)((v - mean) * rs);
            }
        }
    }
}

// ---------------- fused layer, 16 rows/block, 16 waves (1024 thr), XCD-swizzled ----------
// wave w owns cols [16w, 16w+16). Phase A: 64 thr/row, 1 halfx4 chunk each.
template <int SCORE>
__global__ void __launch_bounds__(1024) layer_kernel(
    float* __restrict__ h, const half_t* __restrict__ zin, half_t* __restrict__ zout,
    const half_t* __restrict__ Wt1, const half_t* __restrict__ Wt2,
    const float* __restrict__ b1v, const float* __restrict__ b2v,
    const float* __restrict__ gv, const float* __restrict__ bbv,
    const float* __restrict__ beps, int blk,
    const int* __restrict__ ldeg0, const int* __restrict__ lcol0,
    const int* __restrict__ orig, const int* __restrict__ inv,
    const float* __restrict__ poolp, const float* __restrict__ pinv_all,
    float* __restrict__ scores, int dep, int n, int tag) {
    __shared__ half_t tb[16][264];
    __shared__ half_t ub[16][264];
    __shared__ float part[16][16][3];
    __shared__ float mrs[16][2];
    int tid = threadIdx.x;
    int bid = blockIdx.x;
    int xcd = bid & 7;
    int batch = xcd >> 1;
    int within = ((bid >> 3) << 1) | (xcd & 1);
    int rowBase = batch * n + within * 16;
    float eps1 = 1.0f + beps[blk];

    // ---- phase A: aggregation -> LDS tb (f16); 64 thr/row ----
    {
        int rl = tid >> 6, cg = tid & 63;
        int r = rowBase + rl;
        int b = r / n, i = r - b * n;
        const halfx4* zb = (const halfx4*)zin + (size_t)b * n * 64;
        f32x4 acc = h2f(zb[(size_t)i * 64 + cg]) * eps1;
        int cnt = 0;
        if (tag == 0) {
            int deg = ldeg0[i];
            const int* lc = lcol0 + i * 64;
            int p = 0;
            for (; p + 4 <= deg; p += 4) {
                int j0 = lc[p], j1 = lc[p + 1], j2 = lc[p + 2], j3 = lc[p + 3];
                f32x4 v0 = h2f(zb[(size_t)j0 * 64 + cg]);
                f32x4 v1 = h2f(zb[(size_t)j1 * 64 + cg]);
                f32x4 v2 = h2f(zb[(size_t)j2 * 64 + cg]);
                f32x4 v3 = h2f(zb[(size_t)j3 * 64 + cg]);
                acc += (v0 + v1) + (v2 + v3);
            }
            for (; p < deg; ++p) acc += h2f(zb[(size_t)lc[p] * 64 + cg]);
            cnt = deg;
        } else {
            int o = orig[b * NTOT + i];
            int deg = ldeg0[o];
            const int* lc = lcol0 + o * 64;
            const int* invb = inv + b * NTOT;
            int p = 0;
            for (; p + 4 <= deg; p += 4) {
                int v0 = invb[lc[p]], v1 = invb[lc[p + 1]];
                int v2 = invb[lc[p + 2]], v3 = invb[lc[p + 3]];
                if ((v0 >> 12) == tag) { acc += h2f(zb[(size_t)(v0 & 4095) * 64 + cg]); ++cnt; }
                if ((v1 >> 12) == tag) { acc += h2f(zb[(size_t)(v1 & 4095) * 64 + cg]); ++cnt; }
                if ((v2 >> 12) == tag) { acc += h2f(zb[(size_t)(v2 & 4095) * 64 + cg]); ++cnt; }
                if ((v3 >> 12) == tag) { acc += h2f(zb[(size_t)(v3 & 4095) * 64 + cg]); ++cnt; }
            }
            for (; p < deg; ++p) {
                int v = invb[lc[p]];
                if ((v >> 12) == tag) { acc += h2f(zb[(size_t)(v & 4095) * 64 + cg]); ++cnt; }
            }
        }
        float coefb = eps1 + (float)cnt;
        f32x4 gvv = ((const f32x4*)gv)[cg];
        f32x4 bvv = ((const f32x4*)bbv)[cg];
        f32x4 tv = gvv * acc + bvv * coefb;
        *(halfx4*)&tb[rl][cg * 4] = f2h(tv);
    }
    __syncthreads();

    int w = tid >> 6, l = tid & 63;   // w: 0..15
    int lo = l & 15, hi = l >> 4;
    int kb = hi * 8;

    // ---- phase B: mm1 + silu -> ub (wave w -> cols [16w, 16w+16)) ----
    {
        f32x4 acc = {};
#pragma unroll
        for (int k0 = 0; k0 < DD; k0 += 32) {
            halfx8 a0 = *(const halfx8*)&tb[lo][kb + k0];
            halfx8 bj = *(const halfx8*)(Wt1 + (size_t)(w * 16 + lo) * DD + kb + k0);
            acc = __builtin_amdgcn_mfma_f32_16x16x32_f16(a0, bj, acc, 0, 0, 0);
        }
        float bs = b1v[w * 16 + lo];
#pragma unroll
        for (int q = 0; q < 4; ++q) {
            float v = acc[q] + bs;
            v = v / (1.0f + expf(-v));
            ub[hi * 4 + q][w * 16 + lo] = (half_t)v;
        }
    }
    __syncthreads();

    // ---- phase C: mm2 + residual + stats (+score) + z ----
    {
        f32x4 acc = {};
#pragma unroll
        for (int k0 = 0; k0 < DD; k0 += 32) {
            halfx8 a0 = *(const halfx8*)&ub[lo][kb + k0];
            halfx8 bj = *(const halfx8*)(Wt2 + (size_t)(w * 16 + lo) * DD + kb + k0);
            acc = __builtin_amdgcn_mfma_f32_16x16x32_f16(a0, bj, acc, 0, 0, 0);
        }
        float bs = b2v[w * 16 + lo];
        float pv = 0.f;
        if (SCORE) pv = poolp[dep * DD + w * 16 + lo];
        float vh[4];
#pragma unroll
        for (int q = 0; q < 4; ++q) {
            int r = rowBase + hi * 4 + q;
            int c = w * 16 + lo;
            float v = h[(size_t)r * DD + c] + acc[q] + bs;
            vh[q] = v;
            float s = v, ss = v * v, sp = SCORE ? v * pv : 0.f;
#pragma unroll
            for (int m = 1; m < 16; m <<= 1) {
                s += __shfl_xor(s, m); ss += __shfl_xor(ss, m);
                if (SCORE) sp += __shfl_xor(sp, m);
            }
            if (lo == 0) {
                int rl = hi * 4 + q;
                part[w][rl][0] = s; part[w][rl][1] = ss;
                if (SCORE) part[w][rl][2] = sp;
            }
        }
        __syncthreads();
        if (tid < 16) {
            float s = 0.f, ss = 0.f, sp = 0.f;
#pragma unroll
            for (int w2 = 0; w2 < 16; ++w2) {
                s += part[w2][tid][0]; ss += part[w2][tid][1];
                if (SCORE) sp += part[w2][tid][2];
            }
            float mean = s * (1.0f / DD);
            float var = ss * (1.0f / DD) - mean * mean;
            mrs[tid][0] = mean;
            mrs[tid][1] = rsqrtf(var + 1e-5f);
            if (SCORE) {
                int r = rowBase + tid;
                int b2 = r / n, ii = r - b2 * n;
                scores[b2 * NTOT + ii] = sp * pinv_all[dep];
            }
        }
        __syncthreads();
#pragma unroll
        for (int q = 0; q < 4; ++q) {
            int rl = hi * 4 + q;
            int r = rowBase + rl;
            float mean = mrs[rl][0], rs = mrs[rl][1];
            int c = w * 16 + lo;
            float v = vh[q];
            h[(size_t)r * DD + c] = v;
            zout[(size_t)r * DD + c] = (half_t)((v - mean) * rs);
        }
    }
}

// ---------------- pooling: 1-pass radix + candidate rank; wave-scan based ----------------
__global__ void topk_kernel(const float* __restrict__ scores, const int* __restrict__ orig_cur,
                            int* __restrict__ orig_next, int* __restrict__ idx_local,
                            float* __restrict__ gate, int n, int k) {
    __shared__ unsigned keys[2048];
    __shared__ int hist[256];
    __shared__ int wsum[4];
    __shared__ int sh_bucket, sh_r, sh_cnt, sh_tot;
    __shared__ unsigned cand[256];
    __shared__ unsigned sh_thr;
    int b = blockIdx.x;
    const float* sc = scores + b * NTOT;
    int tid = threadIdx.x;
    for (int i = tid; i < n; i += 256) {
        unsigned u = __float_as_uint(sc[i]);
        keys[i] = (u & 0x80000000u) ? ~u : (u | 0x80000000u);
    }
    hist[tid] = 0;
    if (tid == 0) sh_cnt = 0;
    __syncthreads();
    for (int i = tid; i < n; i += 256) atomicAdd(&hist[keys[i] >> 24], 1);
    __syncthreads();
    int cnt = hist[tid];
    int incl = blockScan256(cnt, wsum);
    int r = n - k;  // 0-indexed rank ascending
    int excl = incl - cnt;
    if (excl <= r && r < incl) { sh_bucket = tid; sh_r = r - excl; }
    __syncthreads();
    int b1 = sh_bucket, r1 = sh_r;
    int c = hist[b1];
    unsigned thrkey;
    if (c <= 256) {
        for (int i = tid; i < n; i += 256) {
            unsigned key = keys[i];
            if ((key >> 24) == (unsigned)b1) {
                int pos = atomicAdd(&sh_cnt, 1);
                cand[pos] = key;
            }
        }
        __syncthreads();
        if (tid < c) {
            unsigned mine = cand[tid];
            int less = 0, eq = 0;
            for (int j = 0; j < c; ++j) {
                unsigned oth = cand[j];
                less += (oth < mine); eq += (oth == mine);
            }
            if (less <= r1 && r1 < less + eq) sh_thr = mine;
        }
        __syncthreads();
        thrkey = sh_thr;
    } else {
        unsigned prefix = ((unsigned)b1) << 24;
        int rr = r1;
        for (int shift = 16; shift >= 0; shift -= 8) {
            __syncthreads();
            hist[tid] = 0;
            __syncthreads();
            unsigned mask = 0xFFFFFFFFu << (shift + 8);
            for (int i = tid; i < n; i += 256) {
                unsigned key = keys[i];
                if ((key & mask) == (prefix & mask)) atomicAdd(&hist[(key >> shift) & 255], 1);
            }
            __syncthreads();
            int cnt2 = hist[tid];
            int incl2 = blockScan256(cnt2, wsum);
            int excl2 = incl2 - cnt2;
            if (excl2 <= rr && rr < incl2) { sh_bucket = tid; sh_r = rr - excl2; }
            __syncthreads();
            prefix |= ((unsigned)sh_bucket) << shift;
            rr = sh_r;
            __syncthreads();
        }
        thrkey = prefix;
    }
    unsigned uthr = (thrkey & 0x80000000u) ? (thrkey ^ 0x80000000u) : ~thrkey;
    float thr = __uint_as_float(uthr);  // exact k-th largest value
    // tie-aware stable compaction via single packed scan (cgt*4096 + ceq)
    int chunk = n / 256;
    int base = tid * chunk;
    int cgt = 0, ceq = 0;
    for (int u = 0; u < chunk; ++u) {
        float s = sc[base + u];
        cgt += (s > thr); ceq += (s == thr);
    }
    int packed = (cgt << 12) | ceq;
    int pincl = blockScan256(packed, wsum);
    if (tid == 255) sh_tot = pincl;
    __syncthreads();
    int total_gt = sh_tot >> 12;
    int ties = k - total_gt;
    int pexcl = pincl - packed;
    int gtb = pexcl >> 12, eqb = pexcl & 4095;
    for (int u = 0; u < chunk; ++u) {
        int i = base + u;
        float s = sc[i];
        bool isgt = (s > thr), iseq = (s == thr);
        bool keep = isgt || (iseq && eqb < ties);
        if (keep) {
            int pos = gtb + (eqb < ties ? eqb : ties);
            idx_local[b * NTOT + pos] = i;
            gate[b * NTOT + pos] = tanhf(s);
            orig_next[b * NTOT + pos] = orig_cur[b * NTOT + i];
        }
        gtb += isgt; eqb += iseq;
    }
}

// gather gated rows, recompute stats, write z (f16), set inverse map (XCD-swizzled)
__global__ void __launch_bounds__(64) gather_kernel(
    const float* __restrict__ h, const int* __restrict__ idx_local,
    const float* __restrict__ gate, const int* __restrict__ orig_new,
    float* __restrict__ hout, half_t* __restrict__ zout, int* __restrict__ inv,
    int n_old, int k, int tag) {
    int bid = blockIdx.x;
    int xcd = bid & 7;
    int b = xcd >> 1;
    int rr = ((bid >> 3) << 1) | (xcd & 1);  // [0, k)
    int r = b * k + rr;
    int lane = threadIdx.x;
    int src = idx_local[b * NTOT + rr];
    float gg = gate[b * NTOT + rr];
    f32x4 v = ((const f32x4*)h)[(size_t)(b * n_old + src) * 64 + lane] * gg;
    ((f32x4*)hout)[(size_t)r * 64 + lane] = v;
    float s = v[0] + v[1] + v[2] + v[3];
    float ss = v[0] * v[0] + v[1] * v[1] + v[2] * v[2] + v[3] * v[3];
#pragma unroll
    for (int m = 1; m < 64; m <<= 1) { s += __shfl_xor(s, m); ss += __shfl_xor(ss, m); }
    float mean = s * (1.0f / DD);
    float rs = rsqrtf(ss * (1.0f / DD) - mean * mean + 1e-5f);
    ((halfx4*)zout)[(size_t)r * 64 + lane] = f2h((v - mean) * rs);
    if (lane == 0) inv[b * NTOT + orig_new[b * NTOT + rr]] = (tag << 12) | rr;
}

// ---------------- readout (B*8 blocks): per-column mean/std over 256 rows ----------------
__global__ void __launch_bounds__(256) readout_kernel(
    const float* __restrict__ h, float* __restrict__ feat) {
    __shared__ float red[8][32][2];
    int bid = blockIdx.x;          // B*8
    int b = bid >> 3, dc = (bid & 7) * 32;
    int cl = threadIdx.x & 31, rg = threadIdx.x >> 5;  // 8 row-groups
    const float* hb = h + (size_t)b * 256 * DD + dc + cl;
    float s = 0.f, ss = 0.f;
    for (int i = rg * 32; i < rg * 32 + 32; ++i) {
        float v = hb[(size_t)i * DD];
        s += v; ss += v * v;
    }
    red[rg][cl][0] = s; red[rg][cl][1] = ss;
    __syncthreads();
    if (rg == 0) {
        float ts = 0.f, tss = 0.f;
#pragma unroll
        for (int j = 0; j < 8; ++j) { ts += red[j][cl][0]; tss += red[j][cl][1]; }
        float mean = ts / 256.0f;
        float s2 = tss - 256.0f * mean * mean;
        feat[b * 512 + dc + cl] = mean;
        feat[b * 512 + 256 + dc + cl] = sqrtf(fmaxf(s2, 0.f) / 255.0f) + 1e-6f;
    }
}

__global__ void final_kernel(const float* __restrict__ feat, const float* __restrict__ lw,
                             const float* __restrict__ lb, float* __restrict__ out) {
    int b = blockIdx.x, l = threadIdx.x;  // 128 threads
    float acc = lb[l];
    const float* f = feat + b * 512;
    for (int k = 0; k < 512; ++k) acc += f[k] * lw[k * 128 + l];
    out[b * 128 + l] = acc;
}

extern "C" void kernel_launch(void* const* d_in, const int* in_sizes, int n_in,
                              void* d_out, int out_size, void* d_ws, size_t ws_size,
                              hipStream_t stream) {
    (void)in_sizes; (void)n_in; (void)out_size; (void)ws_size;
    const float* x     = (const float*)d_in[0];
    const float* adj   = (const float*)d_in[1];
    const float* pos   = (const float*)d_in[2];
    const float* in_w  = (const float*)d_in[3];
    const float* in_b  = (const float*)d_in[4];
    const float* pw1   = (const float*)d_in[5];
    const float* pb1   = (const float*)d_in[6];
    const float* pw2   = (const float*)d_in[7];
    const float* pb2   = (const float*)d_in[8];
    const float* bg    = (const float*)d_in[9];
    const float* bb    = (const float*)d_in[10];
    const float* bw1   = (const float*)d_in[11];
    const float* bb1   = (const float*)d_in[12];
    const float* bw2   = (const float*)d_in[13];
    const float* bb2   = (const float*)d_in[14];
    const float* beps  = (const float*)d_in[15];
    const float* poolp = (const float*)d_in[16];
    const float* lw    = (const float*)d_in[17];
    const float* lb    = (const float*)d_in[18];
    float* out = (float*)d_out;

    char* wp = (char*)d_ws;
    auto alloc = [&](size_t bytes) -> void* {
        void* p = (void*)wp;
        wp += (bytes + 255) & ~(size_t)255;
        return p;
    };
    const size_t HBYTES = (size_t)BSZ * NTOT * DD * sizeof(float);  // 8.39 MB
    float*  h    = (float*)alloc(HBYTES);
    float*  bufC = (float*)alloc(HBYTES);          // gather target
    half_t* zA   = (half_t*)alloc(HBYTES / 2);
    half_t* zB   = (half_t*)alloc(HBYTES / 2);
    half_t* Wt   = (half_t*)alloc((size_t)17 * DD * DD * sizeof(half_t));
    float* pstats  = (float*)alloc(8 * sizeof(float));
    float* pinv    = (float*)alloc(4 * sizeof(float));
    float* scores  = (float*)alloc(BSZ * NTOT * sizeof(float));
    float* gate    = (float*)alloc(BSZ * NTOT * sizeof(float));
    int*   origA   = (int*)alloc(BSZ * NTOT * sizeof(int));
    int*   origB   = (int*)alloc(BSZ * NTOT * sizeof(int));
    int*   idxl    = (int*)alloc(BSZ * NTOT * sizeof(int));
    int*   inv     = (int*)alloc(BSZ * NTOT * sizeof(int));
    int*   ldeg0   = (int*)alloc(NTOT * sizeof(int));
    int*   lcol0   = (int*)alloc((size_t)NTOT * 64 * sizeof(int));
    float* feat    = (float*)alloc(BSZ * 512 * sizeof(float));

    // ---- init: 2 dispatches ----
    setup_kernel<<<SB_MAPS, 256, 0, stream>>>(bw1, bw2, pw2, Wt, pos, pstats, poolp, pinv,
                                              adj, ldeg0, lcol0, origA, inv);
    pe_h_kernel<<<NTOT / 16, 256, 0, stream>>>(pos, pstats, pw1, pb1,
                                               Wt + (size_t)16 * DD * DD, pb2,
                                               x, in_w, in_b, h, zA);

    float* hcur = h;
    float* halt = bufC;
    half_t* zin = zA;
    half_t* zout = zB;
    int* orig = origA;
    int* orign = origB;
    int n = NTOT;
    int blk = 0;
    for (int dep = 0; dep < 4; ++dep) {
        for (int s = 0; s < 2; ++s) {
            int rows = BSZ * n;
            const half_t* W1 = Wt + (size_t)blk * DD * DD;
            const half_t* W2 = Wt + (size_t)(8 + blk) * DD * DD;
            const float* B1 = bb1 + blk * DD;
            const float* B2 = bb2 + blk * DD;
            const float* G  = bg + blk * DD;
            const float* BB = bb + blk * DD;
            int sc = (s == 1 && dep < 3) ? 1 : 0;
            if (sc) layer_kernel<1><<<rows / 16, 1024, 0, stream>>>(
                hcur, zin, zout, W1, W2, B1, B2, G, BB, beps, blk,
                ldeg0, lcol0, orig, inv, poolp, pinv, scores, dep, n, dep);
            else    layer_kernel<0><<<rows / 16, 1024, 0, stream>>>(
                hcur, zin, zout, W1, W2, B1, B2, G, BB, beps, blk,
                ldeg0, lcol0, orig, inv, nullptr, nullptr, nullptr, 0, n, dep);
            { half_t* t = zin; zin = zout; zout = t; }
            ++blk;
        }
        if (dep < 3) {
            int k = n / 2;
            topk_kernel<<<BSZ, 256, 0, stream>>>(scores, orig, orign, idxl, gate, n, k);
            { int* t = orig; orig = orign; orign = t; }
            gather_kernel<<<BSZ * k, 64, 0, stream>>>(hcur, idxl, gate, orig, halt, zin, inv,
                                                      n, k, dep + 1);
            { float* t = hcur; hcur = halt; halt = t; }
            n = k;
        }
    }
    // ---- readout + final ----
    readout_kernel<<<BSZ * 8, 256, 0, stream>>>(hcur, feat);
    final_kernel<<<BSZ, 128, 0, stream>>>(feat, lw, lb, out);
}

// Round 16
// 243.672 us; speedup vs baseline: 1.3464x; 1.0120x over previous
//
#include <hip/hip_runtime.h>
#include <hip/hip_bf16.h>

#define NTOT 2048
#define DD 256
#define BSZ 4

typedef _Float16 half_t;
typedef __attribute__((ext_vector_type(8))) _Float16 halfx8;
typedef __attribute__((ext_vector_type(4))) _Float16 halfx4;
typedef __attribute__((ext_vector_type(4))) float f32x4;

__device__ __forceinline__ f32x4 h2f(halfx4 v) {
    f32x4 r;
#pragma unroll
    for (int e = 0; e < 4; ++e) r[e] = (float)v[e];
    return r;
}
__device__ __forceinline__ halfx4 f2h(f32x4 v) {
    halfx4 r;
#pragma unroll
    for (int e = 0; e < 4; ++e) r[e] = (half_t)v[e];
    return r;
}

// ---------------- block reduce (256 threads) ----------------
__device__ __forceinline__ float blockReduceSum256(float v) {
    __shared__ float red[4];
    for (int off = 32; off > 0; off >>= 1) v += __shfl_down(v, off);
    int lane = threadIdx.x & 63, w = threadIdx.x >> 6;
    __syncthreads();
    if (lane == 0) red[w] = v;
    __syncthreads();
    return red[0] + red[1] + red[2] + red[3];
}

// inclusive scan of per-thread int across 256 threads (3 barriers)
__device__ __forceinline__ int blockScan256(int v, int* wsum) {
    int lane = threadIdx.x & 63, w = threadIdx.x >> 6;
#pragma unroll
    for (int off = 1; off < 64; off <<= 1) {
        int t = __shfl_up(v, off);
        if (lane >= off) v += t;
    }
    __syncthreads();                 // protect wsum reuse from previous call
    if (lane == 63) wsum[w] = v;
    __syncthreads();
    int add = 0;
#pragma unroll
    for (int i = 0; i < 4; ++i) add += (i < w) ? wsum[i] : 0;
    return v + add;
}

// ---------------- mega setup: wprep | stats | adj->lcol0 | maps ----------------
#define SB_WPREP 4352
#define SB_STAT  4356
#define SB_A2L   4868
#define SB_MAPS  4900
__global__ void __launch_bounds__(256) setup_kernel(
    const float* __restrict__ bw1, const float* __restrict__ bw2,
    const float* __restrict__ pw2, half_t* __restrict__ Wt,
    const float* __restrict__ pos, float* __restrict__ pstats,
    const float* __restrict__ poolp, float* __restrict__ pinv,
    const float* __restrict__ adj, int* __restrict__ ldeg0, int* __restrict__ lcol0,
    int* __restrict__ orig, int* __restrict__ inv) {
    int bid = blockIdx.x, tid = threadIdx.x;
    if (bid < SB_WPREP) {
        int m = bid >> 8, rem = bid & 255;
        int nb = (rem >> 4) * 16, kb = (rem & 15) * 16;
        const float* W = (m < 8) ? (bw1 + (size_t)m * DD * DD)
                      : (m < 16) ? (bw2 + (size_t)(m - 8) * DD * DD)
                                 : pw2;
        __shared__ float s[16][17];
        int i = tid >> 4, j = tid & 15;
        s[i][j] = W[(size_t)(kb + i) * DD + nb + j];
        __syncthreads();
        Wt[(size_t)m * DD * DD + (size_t)(nb + i) * DD + kb + j] = (half_t)s[j][i];
    } else if (bid < SB_STAT) {
        int which = bid - SB_WPREP;
        if (which == 0) {
            float s[3] = {0.f, 0.f, 0.f};
            for (int i = tid; i < NTOT; i += 256)
                for (int c = 0; c < 3; ++c) s[c] += pos[i * 3 + c];
            float m[3];
            for (int c = 0; c < 3; ++c) m[c] = blockReduceSum256(s[c]) / (float)NTOT;
            float q[3] = {0.f, 0.f, 0.f};
            for (int i = tid; i < NTOT; i += 256)
                for (int c = 0; c < 3; ++c) { float d = pos[i * 3 + c] - m[c]; q[c] += d * d; }
            for (int c = 0; c < 3; ++c) {
                float t = blockReduceSum256(q[c]);
                if (tid == 0) {
                    float var = ((float)BSZ * t) / ((float)BSZ * NTOT - 1.0f);
                    pstats[c] = m[c];
                    pstats[3 + c] = 1.0f / (sqrtf(var) + 1e-8f);
                }
            }
        } else {
            int dep = which - 1;
            float v = poolp[dep * DD + tid];
            float ss = blockReduceSum256(v * v);
            if (tid == 0) pinv[dep] = rsqrtf(ss);
        }
    } else if (bid < SB_A2L) {
        int row = (bid - SB_STAT) * 4 + (tid >> 6);
        int lane = tid & 63;
        int run = 0;
        for (int j0 = 0; j0 < NTOT; j0 += 64) {
            int j = j0 + lane;
            bool pred = adj[(size_t)row * NTOT + j] != 0.f;
            unsigned long long mask = __ballot(pred);
            if (pred) {
                int pos2 = run + __popcll(mask & ((1ull << lane) - 1ull));
                if (pos2 < 64) lcol0[row * 64 + pos2] = j;
            }
            run += __popcll(mask);
        }
        if (lane == 0) ldeg0[row] = run < 64 ? run : 64;
    } else {
        int t = (bid - SB_A2L) * 256 + tid;  // B*NTOT
        int i = t & (NTOT - 1);
        orig[t] = i; inv[t] = i;  // tag 0
    }
}

// ---------------- fused pe + input projection + h/z init (z -> f16) ----------------
__global__ void __launch_bounds__(256) pe_h_kernel(
    const float* __restrict__ pos, const float* __restrict__ pstats,
    const float* __restrict__ pw1, const float* __restrict__ pb1,
    const half_t* __restrict__ Wt16, const float* __restrict__ pb2,
    const float* __restrict__ x, const float* __restrict__ in_w,
    const float* __restrict__ in_b, float* __restrict__ h, half_t* __restrict__ z) {
    __shared__ half_t tb[16][264];
    __shared__ float iw[16][DD];
    __shared__ float xs[16][16];
    __shared__ float part[4][16][2];
    __shared__ float mrs[16][2];
    int tid = threadIdx.x;
    int i0 = blockIdx.x * 16;
    {
        int rl = tid >> 4, cb = (tid & 15) * 16;
        float pn[3];
#pragma unroll
        for (int c = 0; c < 3; ++c)
            pn[c] = (pos[(i0 + rl) * 3 + c] - pstats[c]) * pstats[3 + c];
#pragma unroll
        for (int u = 0; u < 16; ++u) {
            int d = cb + u;
            float a = pb1[d];
            a += pn[0] * pw1[d];
            a += pn[1] * pw1[DD + d];
            a += pn[2] * pw1[2 * DD + d];
            a = a / (1.0f + expf(-a));
            tb[rl][d] = (half_t)a;
        }
        int k = tid >> 4;
#pragma unroll
        for (int u = 0; u < 16; ++u) iw[k][cb + u] = in_w[k * DD + cb + u];
    }
    __syncthreads();
    int w = tid >> 6, l = tid & 63;
    int lo = l & 15, hi = l >> 4;
    int kb = hi * 8;
    float pe_r[4][4];
    {
        f32x4 acc[4] = {};
#pragma unroll
        for (int k0 = 0; k0 < DD; k0 += 32) {
            halfx8 a0 = *(const halfx8*)&tb[lo][kb + k0];
#pragma unroll
            for (int j = 0; j < 4; ++j) {
                halfx8 bj = *(const halfx8*)(Wt16 + (size_t)(w * 64 + j * 16 + lo) * DD + kb + k0);
                acc[j] = __builtin_amdgcn_mfma_f32_16x16x32_f16(a0, bj, acc[j], 0, 0, 0);
            }
        }
#pragma unroll
        for (int j = 0; j < 4; ++j) {
            float bs = pb2[w * 64 + j * 16 + lo];
#pragma unroll
            for (int q = 0; q < 4; ++q) pe_r[j][q] = acc[j][q] + bs;
        }
    }
    float xb[4];
#pragma unroll
    for (int j = 0; j < 4; ++j) xb[j] = in_b[w * 64 + j * 16 + lo];
    for (int b = 0; b < BSZ; ++b) {
        __syncthreads();
        xs[tid >> 4][tid & 15] = x[(size_t)(b * NTOT + i0 + (tid >> 4)) * 16 + (tid & 15)];
        __syncthreads();
        float vh[4][4];
#pragma unroll
        for (int q = 0; q < 4; ++q) {
            int rl = hi * 4 + q;
            float s = 0.f, ss = 0.f;
#pragma unroll
            for (int j = 0; j < 4; ++j) {
                int c = w * 64 + j * 16 + lo;
                float acc = xb[j];
#pragma unroll
                for (int k = 0; k < 16; ++k) acc += xs[rl][k] * iw[k][c];
                float v = acc + pe_r[j][q];
                vh[j][q] = v;
                s += v; ss += v * v;
            }
#pragma unroll
            for (int m = 1; m < 16; m <<= 1) { s += __shfl_xor(s, m); ss += __shfl_xor(ss, m); }
            if (lo == 0) { part[w][rl][0] = s; part[w][rl][1] = ss; }
        }
        __syncthreads();
        if (tid < 16) {
            float s = 0.f, ss = 0.f;
#pragma unroll
            for (int w2 = 0; w2 < 4; ++w2) { s += part[w2][tid][0]; ss += part[w2][tid][1]; }
            float mean = s * (1.0f / DD);
            float var = ss * (1.0f / DD) - mean * mean;
            mrs[tid][0] = mean;
            mrs[tid][1] = rsqrtf(var + 1e-5f);
        }
        __syncthreads();
#pragma unroll
        for (int q = 0; q < 4; ++q) {
            int rl = hi * 4 + q;
            size_t r = (size_t)(b * NTOT + i0 + rl);
            float mean = mrs[rl][0], rs = mrs[rl][1];
#pragma unroll
            for (int j = 0; j < 4; ++j) {
                int c = w * 64 + j * 16 + lo;
                float v = vh[j][q];
                h[r * DD + c] = v;
                z[r * DD + c] = (half_t)((v - mean) * rs);
            }
        }
    }
}

// ---------------- fused layer, ROWS rows/block, ROWS waves (wave = one row) ----------
// wave w owns cols [W*w, W*w+W), W = 256/ROWS. Phase A: 64 thr/row (scalar idx chain).
// ROWS=16: 1024 thr (big tiers); ROWS=8: 512 thr (small tiers, MFMA rows>=8 garbage).
template <int ROWS, int SCORE>
__global__ void __launch_bounds__(ROWS * 64) layer_kernel(
    float* __restrict__ h, const half_t* __restrict__ zin, half_t* __restrict__ zout,
    const half_t* __restrict__ Wt1, const half_t* __restrict__ Wt2,
    const float* __restrict__ b1v, const float* __restrict__ b2v,
    const float* __restrict__ gv, const float* __restrict__ bbv,
    const float* __restrict__ beps, int blk,
    const int* __restrict__ ldeg0, const int* __restrict__ lcol0,
    const int* __restrict__ orig, const int* __restrict__ inv,
    const float* __restrict__ poolp, const float* __restrict__ pinv_all,
    float* __restrict__ scores, int dep, int n, int tag) {
    constexpr int W = 256 / ROWS;   // cols per wave
    constexpr int JL = W / 16;      // MFMA col-frags per wave
    __shared__ half_t tb[16][264];
    __shared__ half_t ub[16][264];
    __shared__ float part[16][16][3];
    __shared__ float mrs[16][2];
    int tid = threadIdx.x;
    int bid = blockIdx.x;
    int xcd = bid & 7;
    int batch = xcd >> 1;
    int within = ((bid >> 3) << 1) | (xcd & 1);
    int rowBase = batch * n + within * ROWS;
    float eps1 = 1.0f + beps[blk];

    // ---- phase A: aggregation -> LDS tb (f16); wave = one row, scalar index chain ----
    {
        int rl = __builtin_amdgcn_readfirstlane(tid >> 6);  // wave id, provably uniform
        int cg = tid & 63;
        int r = rowBase + rl;
        int b = r / n, i = r - b * n;
        const halfx4* zb = (const halfx4*)zin + (size_t)b * n * 64;
        f32x4 acc = h2f(zb[(size_t)i * 64 + cg]) * eps1;
        int cnt = 0;
        if (tag == 0) {
            int deg = ldeg0[i];
            const int* lc = lcol0 + i * 64;
            int p = 0;
            for (; p + 4 <= deg; p += 4) {
                int j0 = lc[p], j1 = lc[p + 1], j2 = lc[p + 2], j3 = lc[p + 3];
                f32x4 v0 = h2f(zb[(size_t)j0 * 64 + cg]);
                f32x4 v1 = h2f(zb[(size_t)j1 * 64 + cg]);
                f32x4 v2 = h2f(zb[(size_t)j2 * 64 + cg]);
                f32x4 v3 = h2f(zb[(size_t)j3 * 64 + cg]);
                acc += (v0 + v1) + (v2 + v3);
            }
            for (; p < deg; ++p) acc += h2f(zb[(size_t)lc[p] * 64 + cg]);
            cnt = deg;
        } else {
            int o = orig[b * NTOT + i];
            int deg = ldeg0[o];
            const int* lc = lcol0 + o * 64;
            const int* invb = inv + b * NTOT;
            int p = 0;
            for (; p + 4 <= deg; p += 4) {
                int v0 = invb[lc[p]], v1 = invb[lc[p + 1]];
                int v2 = invb[lc[p + 2]], v3 = invb[lc[p + 3]];
                if ((v0 >> 12) == tag) { acc += h2f(zb[(size_t)(v0 & 4095) * 64 + cg]); ++cnt; }
                if ((v1 >> 12) == tag) { acc += h2f(zb[(size_t)(v1 & 4095) * 64 + cg]); ++cnt; }
                if ((v2 >> 12) == tag) { acc += h2f(zb[(size_t)(v2 & 4095) * 64 + cg]); ++cnt; }
                if ((v3 >> 12) == tag) { acc += h2f(zb[(size_t)(v3 & 4095) * 64 + cg]); ++cnt; }
            }
            for (; p < deg; ++p) {
                int v = invb[lc[p]];
                if ((v >> 12) == tag) { acc += h2f(zb[(size_t)(v & 4095) * 64 + cg]); ++cnt; }
            }
        }
        float coefb = eps1 + (float)cnt;
        f32x4 gvv = ((const f32x4*)gv)[cg];
        f32x4 bvv = ((const f32x4*)bbv)[cg];
        f32x4 tv = gvv * acc + bvv * coefb;
        *(halfx4*)&tb[rl][cg * 4] = f2h(tv);
    }
    __syncthreads();

    int w = tid >> 6, l = tid & 63;   // w: 0..ROWS-1
    int lo = l & 15, hi = l >> 4;
    int kb = hi * 8;

    // ---- phase B: mm1 + silu -> ub (wave w -> cols [W*w, W*w+W)) ----
    {
        f32x4 acc[JL] = {};
#pragma unroll
        for (int k0 = 0; k0 < DD; k0 += 32) {
            halfx8 a0 = *(const halfx8*)&tb[lo][kb + k0];
#pragma unroll
            for (int j = 0; j < JL; ++j) {
                halfx8 bj = *(const halfx8*)(Wt1 + (size_t)(w * W + j * 16 + lo) * DD + kb + k0);
                acc[j] = __builtin_amdgcn_mfma_f32_16x16x32_f16(a0, bj, acc[j], 0, 0, 0);
            }
        }
        float bs[JL];
#pragma unroll
        for (int j = 0; j < JL; ++j) bs[j] = b1v[w * W + j * 16 + lo];
#pragma unroll
        for (int q = 0; q < 4; ++q)
#pragma unroll
            for (int j = 0; j < JL; ++j) {
                float v = acc[j][q] + bs[j];
                v = v / (1.0f + expf(-v));
                ub[hi * 4 + q][w * W + j * 16 + lo] = (half_t)v;
            }
    }
    __syncthreads();

    // ---- phase C: mm2 + residual + stats (+score) + z ----
    {
        f32x4 acc[JL] = {};
#pragma unroll
        for (int k0 = 0; k0 < DD; k0 += 32) {
            halfx8 a0 = *(const halfx8*)&ub[lo][kb + k0];
#pragma unroll
            for (int j = 0; j < JL; ++j) {
                halfx8 bj = *(const halfx8*)(Wt2 + (size_t)(w * W + j * 16 + lo) * DD + kb + k0);
                acc[j] = __builtin_amdgcn_mfma_f32_16x16x32_f16(a0, bj, acc[j], 0, 0, 0);
            }
        }
        float bs[JL], pv[JL];
#pragma unroll
        for (int j = 0; j < JL; ++j) { bs[j] = b2v[w * W + j * 16 + lo]; pv[j] = 0.f; }
        if (SCORE) {
#pragma unroll
            for (int j = 0; j < JL; ++j) pv[j] = poolp[dep * DD + w * W + j * 16 + lo];
        }
        float vh[JL][4];
#pragma unroll
        for (int q = 0; q < 4; ++q) {
            int rl = hi * 4 + q;
            int r = rowBase + rl;
            float s = 0.f, ss = 0.f, sp = 0.f;
            if (rl < ROWS) {
#pragma unroll
                for (int j = 0; j < JL; ++j) {
                    int c = w * W + j * 16 + lo;
                    float v = h[(size_t)r * DD + c] + acc[j][q] + bs[j];
                    vh[j][q] = v;
                    s += v; ss += v * v;
                    if (SCORE) sp += v * pv[j];
                }
            }
#pragma unroll
            for (int m = 1; m < 16; m <<= 1) {
                s += __shfl_xor(s, m); ss += __shfl_xor(ss, m);
                if (SCORE) sp += __shfl_xor(sp, m);
            }
            if (lo == 0 && rl < ROWS) {
                part[w][rl][0] = s; part[w][rl][1] = ss;
                if (SCORE) part[w][rl][2] = sp;
            }
        }
        __syncthreads();
        if (tid < ROWS) {
            float s = 0.f, ss = 0.f, sp = 0.f;
#pragma unroll
            for (int w2 = 0; w2 < ROWS; ++w2) {
                s += part[w2][tid][0]; ss += part[w2][tid][1];
                if (SCORE) sp += part[w2][tid][2];
            }
            float mean = s * (1.0f / DD);
            float var = ss * (1.0f / DD) - mean * mean;
            mrs[tid][0] = mean;
            mrs[tid][1] = rsqrtf(var + 1e-5f);
            if (SCORE) {
                int r = rowBase + tid;
                int b2 = r / n, ii = r - b2 * n;
                scores[b2 * NTOT + ii] = sp * pinv_all[dep];
            }
        }
        __syncthreads();
#pragma unroll
        for (int q = 0; q < 4; ++q) {
            int rl = hi * 4 + q;
            if (rl < ROWS) {
                int r = rowBase + rl;
                float mean = mrs[rl][0], rs = mrs[rl][1];
#pragma unroll
                for (int j = 0; j < JL; ++j) {
                    int c = w * W + j * 16 + lo;
                    float v = vh[j][q];
                    h[(size_t)r * DD + c] = v;
                    zout[(size_t)r * DD + c] = (half_t)((v - mean) * rs);
                }
            }
        }
    }
}

// ---------------- pooling: 1-pass radix + candidate rank; wave-scan based ----------------
__global__ void topk_kernel(const float* __restrict__ scores, const int* __restrict__ orig_cur,
                            int* __restrict__ orig_next, int* __restrict__ idx_local,
                            float* __restrict__ gate, int n, int k) {
    __shared__ unsigned keys[2048];
    __shared__ int hist[256];
    __shared__ int wsum[4];
    __shared__ int sh_bucket, sh_r, sh_cnt, sh_tot;
    __shared__ unsigned cand[256];
    __shared__ unsigned sh_thr;
    int b = blockIdx.x;
    const float* sc = scores + b * NTOT;
    int tid = threadIdx.x;
    for (int i = tid; i < n; i += 256) {
        unsigned u = __float_as_uint(sc[i]);
        keys[i] = (u & 0x80000000u) ? ~u : (u | 0x80000000u);
    }
    hist[tid] = 0;
    if (tid == 0) sh_cnt = 0;
    __syncthreads();
    for (int i = tid; i < n; i += 256) atomicAdd(&hist[keys[i] >> 24], 1);
    __syncthreads();
    int cnt = hist[tid];
    int incl = blockScan256(cnt, wsum);
    int r = n - k;  // 0-indexed rank ascending
    int excl = incl - cnt;
    if (excl <= r && r < incl) { sh_bucket = tid; sh_r = r - excl; }
    __syncthreads();
    int b1 = sh_bucket, r1 = sh_r;
    int c = hist[b1];
    unsigned thrkey;
    if (c <= 256) {
        for (int i = tid; i < n; i += 256) {
            unsigned key = keys[i];
            if ((key >> 24) == (unsigned)b1) {
                int pos = atomicAdd(&sh_cnt, 1);
                cand[pos] = key;
            }
        }
        __syncthreads();
        if (tid < c) {
            unsigned mine = cand[tid];
            int less = 0, eq = 0;
            for (int j = 0; j < c; ++j) {
                unsigned oth = cand[j];
                less += (oth < mine); eq += (oth == mine);
            }
            if (less <= r1 && r1 < less + eq) sh_thr = mine;
        }
        __syncthreads();
        thrkey = sh_thr;
    } else {
        unsigned prefix = ((unsigned)b1) << 24;
        int rr = r1;
        for (int shift = 16; shift >= 0; shift -= 8) {
            __syncthreads();
            hist[tid] = 0;
            __syncthreads();
            unsigned mask = 0xFFFFFFFFu << (shift + 8);
            for (int i = tid; i < n; i += 256) {
                unsigned key = keys[i];
                if ((key & mask) == (prefix & mask)) atomicAdd(&hist[(key >> shift) & 255], 1);
            }
            __syncthreads();
            int cnt2 = hist[tid];
            int incl2 = blockScan256(cnt2, wsum);
            int excl2 = incl2 - cnt2;
            if (excl2 <= rr && rr < incl2) { sh_bucket = tid; sh_r = rr - excl2; }
            __syncthreads();
            prefix |= ((unsigned)sh_bucket) << shift;
            rr = sh_r;
            __syncthreads();
        }
        thrkey = prefix;
    }
    unsigned uthr = (thrkey & 0x80000000u) ? (thrkey ^ 0x80000000u) : ~thrkey;
    float thr = __uint_as_float(uthr);  // exact k-th largest value
    // tie-aware stable compaction via single packed scan (cgt*4096 + ceq)
    int chunk = n / 256;
    int base = tid * chunk;
    int cgt = 0, ceq = 0;
    for (int u = 0; u < chunk; ++u) {
        float s = sc[base + u];
        cgt += (s > thr); ceq += (s == thr);
    }
    int packed = (cgt << 12) | ceq;
    int pincl = blockScan256(packed, wsum);
    if (tid == 255) sh_tot = pincl;
    __syncthreads();
    int total_gt = sh_tot >> 12;
    int ties = k - total_gt;
    int pexcl = pincl - packed;
    int gtb = pexcl >> 12, eqb = pexcl & 4095;
    for (int u = 0; u < chunk; ++u) {
        int i = base + u;
        float s = sc[i];
        bool isgt = (s > thr), iseq = (s == thr);
        bool keep = isgt || (iseq && eqb < ties);
        if (keep) {
            int pos = gtb + (eqb < ties ? eqb : ties);
            idx_local[b * NTOT + pos] = i;
            gate[b * NTOT + pos] = tanhf(s);
            orig_next[b * NTOT + pos] = orig_cur[b * NTOT + i];
        }
        gtb += isgt; eqb += iseq;
    }
}

// gather gated rows, recompute stats, write z (f16), set inverse map (XCD-swizzled)
__global__ void __launch_bounds__(64) gather_kernel(
    const float* __restrict__ h, const int* __restrict__ idx_local,
    const float* __restrict__ gate, const int* __restrict__ orig_new,
    float* __restrict__ hout, half_t* __restrict__ zout, int* __restrict__ inv,
    int n_old, int k, int tag) {
    int bid = blockIdx.x;
    int xcd = bid & 7;
    int b = xcd >> 1;
    int rr = ((bid >> 3) << 1) | (xcd & 1);  // [0, k)
    int r = b * k + rr;
    int lane = threadIdx.x;
    int src = idx_local[b * NTOT + rr];
    float gg = gate[b * NTOT + rr];
    f32x4 v = ((const f32x4*)h)[(size_t)(b * n_old + src) * 64 + lane] * gg;
    ((f32x4*)hout)[(size_t)r * 64 + lane] = v;
    float s = v[0] + v[1] + v[2] + v[3];
    float ss = v[0] * v[0] + v[1] * v[1] + v[2] * v[2] + v[3] * v[3];
#pragma unroll
    for (int m = 1; m < 64; m <<= 1) { s += __shfl_xor(s, m); ss += __shfl_xor(ss, m); }
    float mean = s * (1.0f / DD);
    float rs = rsqrtf(ss * (1.0f / DD) - mean * mean + 1e-5f);
    ((halfx4*)zout)[(size_t)r * 64 + lane] = f2h((v - mean) * rs);
    if (lane == 0) inv[b * NTOT + orig_new[b * NTOT + rr]] = (tag << 12) | rr;
}

// ---------------- readout (B*8 blocks): per-column mean/std over 256 rows ----------------
__global__ void __launch_bounds__(256) readout_kernel(
    const float* __restrict__ h, float* __restrict__ feat) {
    __shared__ float red[8][32][2];
    int bid = blockIdx.x;          // B*8
    int b = bid >> 3, dc = (bid & 7) * 32;
    int cl = threadIdx.x & 31, rg = threadIdx.x >> 5;  // 8 row-groups
    const float* hb = h + (size_t)b * 256 * DD + dc + cl;
    float s = 0.f, ss = 0.f;
    for (int i = rg * 32; i < rg * 32 + 32; ++i) {
        float v = hb[(size_t)i * DD];
        s += v; ss += v * v;
    }
    red[rg][cl][0] = s; red[rg][cl][1] = ss;
    __syncthreads();
    if (rg == 0) {
        float ts = 0.f, tss = 0.f;
#pragma unroll
        for (int j = 0; j < 8; ++j) { ts += red[j][cl][0]; tss += red[j][cl][1]; }
        float mean = ts / 256.0f;
        float s2 = tss - 256.0f * mean * mean;
        feat[b * 512 + dc + cl] = mean;
        feat[b * 512 + 256 + dc + cl] = sqrtf(fmaxf(s2, 0.f) / 255.0f) + 1e-6f;
    }
}

__global__ void final_kernel(const float* __restrict__ feat, const float* __restrict__ lw,
                             const float* __restrict__ lb, float* __restrict__ out) {
    int b = blockIdx.x, l = threadIdx.x;  // 128 threads
    float acc = lb[l];
    const float* f = feat + b * 512;
    for (int k = 0; k < 512; ++k) acc += f[k] * lw[k * 128 + l];
    out[b * 128 + l] = acc;
}

extern "C" void kernel_launch(void* const* d_in, const int* in_sizes, int n_in,
                              void* d_out, int out_size, void* d_ws, size_t ws_size,
                              hipStream_t stream) {
    (void)in_sizes; (void)n_in; (void)out_size; (void)ws_size;
    const float* x     = (const float*)d_in[0];
    const float* adj   = (const float*)d_in[1];
    const float* pos   = (const float*)d_in[2];
    const float* in_w  = (const float*)d_in[3];
    const float* in_b  = (const float*)d_in[4];
    const float* pw1   = (const float*)d_in[5];
    const float* pb1   = (const float*)d_in[6];
    const float* pw2   = (const float*)d_in[7];
    const float* pb2   = (const float*)d_in[8];
    const float* bg    = (const float*)d_in[9];
    const float* bb    = (const float*)d_in[10];
    const float* bw1   = (const float*)d_in[11];
    const float* bb1   = (const float*)d_in[12];
    const float* bw2   = (const float*)d_in[13];
    const float* bb2   = (const float*)d_in[14];
    const float* beps  = (const float*)d_in[15];
    const float* poolp = (const float*)d_in[16];
    const float* lw    = (const float*)d_in[17];
    const float* lb    = (const float*)d_in[18];
    float* out = (float*)d_out;

    char* wp = (char*)d_ws;
    auto alloc = [&](size_t bytes) -> void* {
        void* p = (void*)wp;
        wp += (bytes + 255) & ~(size_t)255;
        return p;
    };
    const size_t HBYTES = (size_t)BSZ * NTOT * DD * sizeof(float);  // 8.39 MB
    float*  h    = (float*)alloc(HBYTES);
    float*  bufC = (float*)alloc(HBYTES);          // gather target
    half_t* zA   = (half_t*)alloc(HBYTES / 2);
    half_t* zB   = (half_t*)alloc(HBYTES / 2);
    half_t* Wt   = (half_t*)alloc((size_t)17 * DD * DD * sizeof(half_t));
    float* pstats  = (float*)alloc(8 * sizeof(float));
    float* pinv    = (float*)alloc(4 * sizeof(float));
    float* scores  = (float*)alloc(BSZ * NTOT * sizeof(float));
    float* gate    = (float*)alloc(BSZ * NTOT * sizeof(float));
    int*   origA   = (int*)alloc(BSZ * NTOT * sizeof(int));
    int*   origB   = (int*)alloc(BSZ * NTOT * sizeof(int));
    int*   idxl    = (int*)alloc(BSZ * NTOT * sizeof(int));
    int*   inv     = (int*)alloc(BSZ * NTOT * sizeof(int));
    int*   ldeg0   = (int*)alloc(NTOT * sizeof(int));
    int*   lcol0   = (int*)alloc((size_t)NTOT * 64 * sizeof(int));
    float* feat    = (float*)alloc(BSZ * 512 * sizeof(float));

    // ---- init: 2 dispatches ----
    setup_kernel<<<SB_MAPS, 256, 0, stream>>>(bw1, bw2, pw2, Wt, pos, pstats, poolp, pinv,
                                              adj, ldeg0, lcol0, origA, inv);
    pe_h_kernel<<<NTOT / 16, 256, 0, stream>>>(pos, pstats, pw1, pb1,
                                               Wt + (size_t)16 * DD * DD, pb2,
                                               x, in_w, in_b, h, zA);

    float* hcur = h;
    float* halt = bufC;
    half_t* zin = zA;
    half_t* zout = zB;
    int* orig = origA;
    int* orign = origB;
    int n = NTOT;
    int blk = 0;
    for (int dep = 0; dep < 4; ++dep) {
        for (int s = 0; s < 2; ++s) {
            int rows = BSZ * n;
            const half_t* W1 = Wt + (size_t)blk * DD * DD;
            const half_t* W2 = Wt + (size_t)(8 + blk) * DD * DD;
            const float* B1 = bb1 + blk * DD;
            const float* B2 = bb2 + blk * DD;
            const float* G  = bg + blk * DD;
            const float* BB = bb + blk * DD;
            int sc = (s == 1 && dep < 3) ? 1 : 0;
            if (dep < 2) {
                if (sc) layer_kernel<16, 1><<<rows / 16, 1024, 0, stream>>>(
                    hcur, zin, zout, W1, W2, B1, B2, G, BB, beps, blk,
                    ldeg0, lcol0, orig, inv, poolp, pinv, scores, dep, n, dep);
                else    layer_kernel<16, 0><<<rows / 16, 1024, 0, stream>>>(
                    hcur, zin, zout, W1, W2, B1, B2, G, BB, beps, blk,
                    ldeg0, lcol0, orig, inv, nullptr, nullptr, nullptr, 0, n, dep);
            } else {
                if (sc) layer_kernel<8, 1><<<rows / 8, 512, 0, stream>>>(
                    hcur, zin, zout, W1, W2, B1, B2, G, BB, beps, blk,
                    ldeg0, lcol0, orig, inv, poolp, pinv, scores, dep, n, dep);
                else    layer_kernel<8, 0><<<rows / 8, 512, 0, stream>>>(
                    hcur, zin, zout, W1, W2, B1, B2, G, BB, beps, blk,
                    ldeg0, lcol0, orig, inv, nullptr, nullptr, nullptr, 0, n, dep);
            }
            { half_t* t = zin; zin = zout; zout = t; }
            ++blk;
        }
        if (dep < 3) {
            int k = n / 2;
            topk_kernel<<<BSZ, 256, 0, stream>>>(scores, orig, orign, idxl, gate, n, k);
            { int* t = orig; orig = orign; orign = t; }
            gather_kernel<<<BSZ * k, 64, 0, stream>>>(hcur, idxl, gate, orig, halt, zin, inv,
                                                      n, k, dep + 1);
            { float* t = hcur; hcur = halt; halt = t; }
            n = k;
        }
    }
    // ---- readout + final ----
    readout_kernel<<<BSZ * 8, 256, 0, stream>>>(hcur, feat);
    final_kernel<<<BSZ, 128, 0, stream>>>(feat, lw, lb, out);
}